// Round 3
// baseline (646.511 us; speedup 1.0000x reference)
//
#include <hip/hip_runtime.h>

#define NN 2048
#define NE 32768
#define DIM 256
#define NH 4

typedef unsigned short u16;
typedef __attribute__((ext_vector_type(4))) unsigned short u16x4;
typedef __attribute__((ext_vector_type(8))) short bf16x8;
typedef __attribute__((ext_vector_type(4))) float f32x4;

typedef __attribute__((address_space(1))) const unsigned int g_as1;
typedef __attribute__((address_space(3))) unsigned int l_as3;

__device__ __forceinline__ void gload16(const u16* g, u16* l) {
  __builtin_amdgcn_global_load_lds((g_as1*)g, (l_as3*)l, 16, 0, 0);
}

__device__ __forceinline__ u16 f2bf(float f) {
  unsigned u = __float_as_uint(f);
  unsigned r = u + 0x7FFFu + ((u >> 16) & 1u);
  return (u16)(r >> 16);
}

__device__ __forceinline__ float dmask_eval(const float* __restrict__ C3,
    const float* __restrict__ W1, const float* __restrict__ b1,
    const float* __restrict__ W2, const float* __restrict__ b2,
    int n, int m, int h)
{
  float dx = C3[3*n+0] - C3[3*m+0];
  float dy = C3[3*n+1] - C3[3*m+1];
  float dz = C3[3*n+2] - C3[3*m+2];
  float sq = dx*dx + dy*dy + dz*dz;
  float dist = sq > 0.f ? sqrtf(sq) : 0.f;
  float o = b2[h];
  #pragma unroll
  for (int j = 0; j < 3; ++j) {
    float hd = b1[j] + dx*W1[0*3+j] + dy*W1[1*3+j] + dz*W1[2*3+j] + dist*W1[3*3+j];
    hd = fmaxf(hd, 0.f);
    o += hd * W2[j*4+h];
  }
  return o;
}

// ---------------- bf16 MFMA GEMM ------------------------------------------------
// C[m][n] = epi(scale * sum_k A[m][k]*Bt[n][k] + bias[n])
struct GB { const u16* A; const int* idx; long ld; long aoffz; };

// EPI: 0 = f32 out; 1 = relu -> bf16; 2 = sigmoid -> f32; 3 = +dmask -> f32;
//      4 = headsplit bf16; 5 = bf16 out; 6 = head-permuted f32 (valP layout)
template<int BNF, int EPI>
__global__ __launch_bounds__(256) void gemm_bf(
    GB ga, const u16* __restrict__ Bt, long bld, long boffz,
    const float* __restrict__ bias, void* __restrict__ Cp, long ldc, long coffz,
    int K, float scale,
    const float* __restrict__ C3, const float* __restrict__ gW1, const float* __restrict__ gb1,
    const float* __restrict__ gW2, const float* __restrict__ gb2)
{
  __shared__ u16 As[128 * 64];
  __shared__ u16 Bs[32 * BNF * 64];

  const int tid = threadIdx.x;
  const int wid = tid >> 6, lane = tid & 63;
  const int bz = blockIdx.z;
  const int m0 = blockIdx.y * 128;
  const int n0 = blockIdx.x * (32 * BNF);
  const int wr = wid >> 1, wc = wid & 1;
  const int l15 = lane & 15, l4 = lane >> 4;

  const u16* asrc[4];
  #pragma unroll
  for (int c = 0; c < 4; ++c) {
    int rl = c*32 + wid*8 + (lane >> 3);
    int row = ga.idx ? ga.idx[m0 + rl] : (m0 + rl);
    int c16s = (lane & 7) ^ (rl & 7);
    asrc[c] = ga.A + ga.aoffz * bz + (long)row * ga.ld + c16s * 8;
  }
  const u16* bsrc[BNF];
  #pragma unroll
  for (int c = 0; c < BNF; ++c) {
    int rl = c*32 + wid*8 + (lane >> 3);
    int c16s = (lane & 7) ^ (rl & 7);
    bsrc[c] = Bt + boffz * bz + (long)(n0 + rl) * bld + c16s * 8;
  }

  f32x4 acc[4][BNF] = {};

  for (int k0 = 0; k0 < K; k0 += 64) {
    #pragma unroll
    for (int c = 0; c < 4; ++c)
      gload16(asrc[c] + k0, &As[(c*32 + wid*8) * 64]);
    #pragma unroll
    for (int c = 0; c < BNF; ++c)
      gload16(bsrc[c] + k0, &Bs[(c*32 + wid*8) * 64]);
    __syncthreads();

    #pragma unroll
    for (int kk = 0; kk < 2; ++kk) {
      bf16x8 af[4], bfr[BNF];
      #pragma unroll
      for (int i = 0; i < 4; ++i) {
        int r = wr*64 + i*16 + l15;
        af[i] = *(const bf16x8*)&As[r*64 + (((kk*4 + l4) ^ (r & 7)) * 8)];
      }
      #pragma unroll
      for (int j = 0; j < BNF; ++j) {
        int r = wc*(16*BNF) + j*16 + l15;
        bfr[j] = *(const bf16x8*)&Bs[r*64 + (((kk*4 + l4) ^ (r & 7)) * 8)];
      }
      #pragma unroll
      for (int i = 0; i < 4; ++i)
        #pragma unroll
        for (int j = 0; j < BNF; ++j)
          acc[i][j] = __builtin_amdgcn_mfma_f32_16x16x32_bf16(af[i], bfr[j], acc[i][j], 0, 0, 0);
    }
    __syncthreads();
  }

  #pragma unroll
  for (int j = 0; j < BNF; ++j) {
    const int col = n0 + wc*(16*BNF) + j*16 + l15;
    const float bb = bias ? bias[col] : 0.f;
    #pragma unroll
    for (int i = 0; i < 4; ++i) {
      #pragma unroll
      for (int r = 0; r < 4; ++r) {
        const int m = m0 + wr*64 + i*16 + l4*4 + r;
        float v = acc[i][j][r] * scale + bb;
        if constexpr (EPI == 1) v = fmaxf(v, 0.f);
        if constexpr (EPI == 2) v = 1.f / (1.f + expf(-v));
        if constexpr (EPI == 3) v += dmask_eval(C3, gW1, gb1, gW2, gb2, m, col, bz);
        if constexpr (EPI == 0 || EPI == 2 || EPI == 3)
          ((float*)Cp)[coffz*bz + (long)m*ldc + col] = v;
        else if constexpr (EPI == 4)
          ((u16*)Cp)[((long)(col & 3) * NE + m) * ldc + (col >> 2) + coffz] = f2bf(v);
        else if constexpr (EPI == 6)
          ((float*)Cp)[(long)m*256 + (col & 3)*64 + (col >> 2)] = v;
        else
          ((u16*)Cp)[coffz*bz + (long)m*ldc + col] = f2bf(v);
      }
    }
  }
}

// ---------------- dedicated ne-MLP layer-1 GEMM: fused 4-segment gather ---------
// A row e = [node_bf[src[e]], edge_bf[e], edge_bf[rev[e]] or 0, node_bf[dst[e]]]
__global__ __launch_bounds__(256) void gemm_ne(
    const u16* __restrict__ nbf, const u16* __restrict__ ebf, const u16* __restrict__ zbuf,
    const int* __restrict__ ei, const int* __restrict__ rev,
    const u16* __restrict__ Bt, const float* __restrict__ bias, u16* __restrict__ C)
{
  __shared__ u16 As[128 * 64];
  __shared__ u16 Bs[128 * 64];
  const int tid = threadIdx.x, wid = tid >> 6, lane = tid & 63;
  const int m0 = blockIdx.y * 128, n0 = blockIdx.x * 128;
  const int wr = wid >> 1, wc = wid & 1, l15 = lane & 15, l4 = lane >> 4;

  const u16* bsrc[4];
  #pragma unroll
  for (int c = 0; c < 4; ++c) {
    int rl = c*32 + wid*8 + (lane >> 3);
    int c16s = (lane & 7) ^ (rl & 7);
    bsrc[c] = Bt + (long)(n0 + rl) * 1024 + c16s * 8;
  }

  f32x4 acc[4][4] = {};

  #pragma unroll
  for (int seg = 0; seg < 4; ++seg) {
    const u16* asrc[4];
    #pragma unroll
    for (int c = 0; c < 4; ++c) {
      int rl = c*32 + wid*8 + (lane >> 3);
      int m = m0 + rl;
      int c16s = (lane & 7) ^ (rl & 7);
      const u16* base; long row;
      if (seg == 0)      { base = nbf; row = ei[m]; }
      else if (seg == 1) { base = ebf; row = m; }
      else if (seg == 2) { int r = rev[m]; base = (r >= 0) ? ebf : zbuf; row = (r >= 0) ? r : 0; }
      else               { base = nbf; row = ei[NE + m]; }
      asrc[c] = base + row * 256 + c16s * 8;
    }
    #pragma unroll
    for (int kt = 0; kt < 4; ++kt) {
      #pragma unroll
      for (int c = 0; c < 4; ++c)
        gload16(asrc[c] + kt*64, &As[(c*32 + wid*8) * 64]);
      #pragma unroll
      for (int c = 0; c < 4; ++c)
        gload16(bsrc[c] + seg*256 + kt*64, &Bs[(c*32 + wid*8) * 64]);
      __syncthreads();
      #pragma unroll
      for (int kk = 0; kk < 2; ++kk) {
        bf16x8 af[4], bfr[4];
        #pragma unroll
        for (int i = 0; i < 4; ++i) {
          int r = wr*64 + i*16 + l15;
          af[i] = *(const bf16x8*)&As[r*64 + (((kk*4 + l4) ^ (r & 7)) * 8)];
        }
        #pragma unroll
        for (int j = 0; j < 4; ++j) {
          int r = wc*64 + j*16 + l15;
          bfr[j] = *(const bf16x8*)&Bs[r*64 + (((kk*4 + l4) ^ (r & 7)) * 8)];
        }
        #pragma unroll
        for (int i = 0; i < 4; ++i)
          #pragma unroll
          for (int j = 0; j < 4; ++j)
            acc[i][j] = __builtin_amdgcn_mfma_f32_16x16x32_bf16(af[i], bfr[j], acc[i][j], 0, 0, 0);
      }
      __syncthreads();
    }
  }

  #pragma unroll
  for (int j = 0; j < 4; ++j) {
    const int col = n0 + wc*64 + j*16 + l15;
    const float bb = bias[col];
    #pragma unroll
    for (int i = 0; i < 4; ++i) {
      #pragma unroll
      for (int r = 0; r < 4; ++r) {
        const int m = m0 + wr*64 + i*16 + l4*4 + r;
        C[(long)m*512 + col] = f2bf(fmaxf(acc[i][j][r] + bb, 0.f));
      }
    }
  }
}

// ---------------- pack / convert kernels ----------------------------------------
__global__ void conv4_k(const float* __restrict__ s, u16* __restrict__ d, long n4) {
  long i = (long)blockIdx.x * 256 + threadIdx.x;
  if (i >= n4) return;
  float4 v = ((const float4*)s)[i];
  u16x4 o = { f2bf(v.x), f2bf(v.y), f2bf(v.z), f2bf(v.w) };
  ((u16x4*)d)[i] = o;
}

__global__ __launch_bounds__(256) void transw_k(const float* __restrict__ W,
                                                u16* __restrict__ Wt, int K, int N) {
  __shared__ float t[32][33];
  int bk = blockIdx.x * 32, bn = blockIdx.y * 32;
  int tx = threadIdx.x & 31, ty = threadIdx.x >> 5;
  #pragma unroll
  for (int i = ty; i < 32; i += 8) t[i][tx] = W[(long)(bk + i) * N + bn + tx];
  __syncthreads();
  #pragma unroll
  for (int i = ty; i < 32; i += 8) Wt[(long)(bn + i) * K + bk + tx] = f2bf(t[tx][i]);
}

__global__ __launch_bounds__(256) void seg_sum_k(const float* __restrict__ ef,
    const int* __restrict__ ei, float* sub, float* obj, float* cs, float* cd) {
  int e = blockIdx.x * 4 + (threadIdx.x >> 6);
  int lane = threadIdx.x & 63;
  int s = ei[e], d = ei[NE + e];
  const float* row = ef + (long)e * DIM;
  #pragma unroll
  for (int c = 0; c < 4; ++c) {
    float v = row[lane + c*64];
    atomicAdd(&sub[(long)s*DIM + lane + c*64], v);
    atomicAdd(&obj[(long)d*DIM + lane + c*64], v);
  }
  if (lane == 0) { atomicAdd(&cs[s], 1.f); atomicAdd(&cd[d], 1.f); }
}

__global__ void pack_tw_k(const float* __restrict__ sub, const float* __restrict__ obj,
    const float* __restrict__ cs, const float* __restrict__ cd, u16* __restrict__ twA) {
  int n = blockIdx.x, t = threadIdx.x;  // 128 threads
  int seg = t >> 6, c = (t & 63) * 4;
  float sc = seg ? 1.f / fmaxf(cd[n], 1.f) : 1.f / fmaxf(cs[n], 1.f);
  float4 v = *(const float4*)((seg ? obj : sub) + (long)n * DIM + c);
  u16x4 o = { f2bf(v.x*sc), f2bf(v.y*sc), f2bf(v.z*sc), f2bf(v.w*sc) };
  *(u16x4*)&twA[(long)n*512 + seg*256 + c] = o;
}

__global__ void pack_pr_k(const float* __restrict__ nf, const float* __restrict__ agg,
                          u16* __restrict__ prA) {
  int n = blockIdx.x, t = threadIdx.x;  // 128 threads
  int seg = t >> 6, c = (t & 63) * 4;
  float4 v = *(const float4*)((seg ? agg : nf) + (long)n * DIM + c);
  u16x4 o = { f2bf(v.x), f2bf(v.y), f2bf(v.z), f2bf(v.w) };
  *(u16x4*)&prA[(long)n*512 + seg*256 + c] = o;
}

__global__ __launch_bounds__(256) void softmax_k(const float* __restrict__ S,
                                                 u16* __restrict__ P) {
  long base = (long)blockIdx.x * NN;
  int t = threadIdx.x;
  float v[8];
  float mx = -1e30f;
  #pragma unroll
  for (int i = 0; i < 8; ++i) { v[i] = S[base + t + i*256]; mx = fmaxf(mx, v[i]); }
  #pragma unroll
  for (int off = 32; off; off >>= 1) mx = fmaxf(mx, __shfl_xor(mx, off));
  __shared__ float r1[4], r2[4];
  if ((t & 63) == 0) r1[t >> 6] = mx;
  __syncthreads();
  mx = fmaxf(fmaxf(r1[0], r1[1]), fmaxf(r1[2], r1[3]));
  float sum = 0.f;
  #pragma unroll
  for (int i = 0; i < 8; ++i) { v[i] = expf(v[i] - mx); sum += v[i]; }
  #pragma unroll
  for (int off = 32; off; off >>= 1) sum += __shfl_xor(sum, off);
  if ((t & 63) == 0) r2[t >> 6] = sum;
  __syncthreads();
  sum = r2[0] + r2[1] + r2[2] + r2[3];
  float inv = 1.f / sum;
  #pragma unroll
  for (int i = 0; i < 8; ++i) P[base + t + i*256] = f2bf(v[i] * inv);
}

__global__ void node_out_k(const float* mh, const float* ea, float* out) {
  long i = (long)blockIdx.x * 256 + threadIdx.x;
  out[i] = fmaxf(mh[i], 0.f) * ea[i];
}

__global__ void scat_k(const int* ei, int* tbl) {
  int e = blockIdx.x * 256 + threadIdx.x;
  atomicMax(&tbl[(long)ei[e] * NN + ei[NE + e]], e + 1);
}

__global__ void rev_k(const int* ei, const int* tbl, int* rev) {
  int e = blockIdx.x * 256 + threadIdx.x;
  rev[e] = tbl[(long)ei[NE + e] * NN + ei[e]] - 1;
}

// ---------------- CSR build + msg/agg (atomic-free segment max) ------------------
__global__ __launch_bounds__(256) void scan_k(const float* __restrict__ cs,
    int* __restrict__ start, int* __restrict__ cursor) {
  __shared__ int part[256];
  int t = threadIdx.x;
  int loc[8]; int s = 0;
  #pragma unroll
  for (int i = 0; i < 8; ++i) { int v = (int)cs[t*8 + i]; loc[i] = s; s += v; }
  part[t] = s;
  __syncthreads();
  if (t == 0) { int a = 0; for (int i = 0; i < 256; ++i) { int v = part[i]; part[i] = a; a += v; } }
  __syncthreads();
  int base = part[t];
  #pragma unroll
  for (int i = 0; i < 8; ++i) { start[t*8+i] = base + loc[i]; cursor[t*8+i] = base + loc[i]; }
  if (t == 255) start[2048] = base + s;
}

__global__ void scatter_k(const int* __restrict__ ei, int* __restrict__ cursor,
                          int* __restrict__ eids) {
  int e = blockIdx.x * 256 + threadIdx.x;
  int pos = atomicAdd(&cursor[ei[e]], 1);
  eids[pos] = e;
}

// per (e): softmax over o (64 lanes of each wave; h = wave id), times valP -> msgP
__global__ __launch_bounds__(256) void msg2_k(const float* __restrict__ Sb,
    const float* __restrict__ valP, float* __restrict__ msgP) {
  int e = blockIdx.x;
  int t = threadIdx.x;
  int h = t >> 6;
  float s = Sb[((long)h * NE + e) * 64 + (t & 63)];
  float mx = s;
  #pragma unroll
  for (int off = 32; off; off >>= 1) mx = fmaxf(mx, __shfl_xor(mx, off));
  float p = expf(s - mx), sum = p;
  #pragma unroll
  for (int off = 32; off; off >>= 1) sum += __shfl_xor(sum, off);
  msgP[(long)e*256 + t] = (p / sum) * valP[(long)e*256 + t];
}

// per node: max over its out-edges; t indexes [h][o]; output channel c = o*4+h
__global__ __launch_bounds__(256) void agg_k(const int* __restrict__ start,
    const int* __restrict__ eids, const float* __restrict__ msgP, float* __restrict__ aggf) {
  int n = blockIdx.x, t = threadIdx.x;
  int b = start[n], e_ = start[n+1];
  float mx = -1e30f;
  for (int i = b; i < e_; ++i) {
    int e = eids[i];
    mx = fmaxf(mx, msgP[(long)e*256 + t]);
  }
  int c = (t & 63) * 4 + (t >> 6);
  aggf[(long)n*256 + c] = (e_ > b) ? mx : 0.f;
}

// ---------------- host side ------------------------------------------------------
static GB gb(const u16* A, const int* idx, long ld, long aoffz) {
  GB g; g.A = A; g.idx = idx; g.ld = ld; g.aoffz = aoffz; return g;
}

extern "C" void kernel_launch(void* const* d_in, const int* in_sizes, int n_in,
                              void* d_out, int out_size, void* d_ws, size_t ws_size,
                              hipStream_t stream) {
  (void)in_sizes; (void)n_in; (void)out_size; (void)ws_size;

  const float* node_f = (const float*)d_in[0];
  const float* edge_f = (const float*)d_in[1];
  const float* coords = (const float*)d_in[2];
  const int*   ei     = (const int*)d_in[3];
  const float* Wq = (const float*)d_in[5];  const float* bq = (const float*)d_in[6];
  const float* Wk = (const float*)d_in[7];  const float* bk = (const float*)d_in[8];
  const float* Wv = (const float*)d_in[9];  const float* bv = (const float*)d_in[10];
  const float* Wo = (const float*)d_in[11]; const float* bo = (const float*)d_in[12];
  const float* gd_W1 = (const float*)d_in[13]; const float* gd_b1 = (const float*)d_in[14];
  const float* gd_W2 = (const float*)d_in[15]; const float* gd_b2 = (const float*)d_in[16];
  const float* tw_W1 = (const float*)d_in[17]; const float* tw_b1 = (const float*)d_in[18];
  const float* tw_W2 = (const float*)d_in[19]; const float* tw_b2 = (const float*)d_in[20];
  const float* ne_W1 = (const float*)d_in[21]; const float* ne_b1 = (const float*)d_in[22];
  const float* ne_W2 = (const float*)d_in[23]; const float* ne_b2 = (const float*)d_in[24];
  const float* att_W1 = (const float*)d_in[25]; const float* att_b1 = (const float*)d_in[26];
  const float* att_W2 = (const float*)d_in[27]; const float* att_b2 = (const float*)d_in[28];
  const float* pe_W = (const float*)d_in[29]; const float* pe_b = (const float*)d_in[30];
  const float* pq_W = (const float*)d_in[31]; const float* pq_b = (const float*)d_in[32];
  const float* pv_W = (const float*)d_in[33]; const float* pv_b = (const float*)d_in[34];
  const float* pr_W1 = (const float*)d_in[35]; const float* pr_b1 = (const float*)d_in[36];
  const float* pr_W2 = (const float*)d_in[37]; const float* pr_b2 = (const float*)d_in[38];

  char* WB = (char*)d_ws;
  float* out = (float*)d_out;
  float* out_node = out;
  float* out_edge = out + (long)NN*DIM;
  float* out_xx   = out + (long)NN*DIM + (long)NE*DIM;

  // -------- workspace: big time-union'd regions --------
  const long sz_R1 = 4L*NN*NN*4;   // 67.1 MB : S f32  ->  valP f32 (33.5) + msgP f32 (33.5)
  const long sz_R2 = 4L*NN*NN*2;   // 33.5 MB : P_bf -> nehid bf16
  const long sz_R3 = 4L*NE*128*2;  // 33.5 MB : tbl int (16.8) + edge_bf (16.8) -> h1 bf16
  const long sz_R4 = 4L*NE*128*2;  // 33.5 MB : qeA bf16 -> Sb f32
  const long R1 = 0, R2 = R1 + sz_R1, R3 = R2 + sz_R2, R4 = R3 + sz_R3;

  float* S      = (float*)(WB + R1);
  float* valP   = (float*)(WB + R1);
  float* msgP   = (float*)(WB + R1 + sz_R1/2);
  u16*   Pbf    = (u16*)(WB + R2);
  u16*   nehid  = (u16*)(WB + R2);
  int*   tbl    = (int*)(WB + R3);
  u16*   h1     = (u16*)(WB + R3);
  u16*   edge_bf= (u16*)(WB + R3 + (long)NN*NN*4);
  u16*   qeA    = (u16*)(WB + R4);
  float* Sb     = (float*)(WB + R4);

  long cur = R4 + sz_R4;
  auto alloc = [&](long bytes) { long o = cur; cur += (bytes + 255) & ~255L; return o; };

  long o_sub = alloc(2L*NN*DIM*4);          // sub+obj -> later q_bf,k_bf | vT,attn_bf
  float* sub = (float*)(WB + o_sub);
  float* obj = sub + (long)NN*DIM;
  u16* q_bf    = (u16*)sub;
  u16* k_bf    = q_bf + (long)NN*DIM;
  u16* vT      = (u16*)obj;
  u16* attn_bf = vT + (long)NN*DIM;

  long o_cs  = alloc(2L*NN*4);
  float* cs = (float*)(WB + o_cs); float* cd = cs + NN;
  long o_vb  = alloc((long)NN*DIM*4);       // vbuf -> later mhsa
  float* vbuf = (float*)(WB + o_vb);
  float* mhsa = vbuf;
  long o_ea  = alloc((long)NN*DIM*4);  float* eatt = (float*)(WB + o_ea);
  long o_ag  = alloc((long)NN*DIM*4);  float* aggf = (float*)(WB + o_ag);
  long o_rv  = alloc((long)NE*4);      int* rev = (int*)(WB + o_rv);
  long o_st  = alloc((NN+1)*4);        int* startp = (int*)(WB + o_st);
  long o_cu  = alloc(NN*4);            int* cursor = (int*)(WB + o_cu);
  long o_eid = alloc((long)NE*4);      int* eids = (int*)(WB + o_eid);
  long o_zb  = alloc(1024);            u16* zbuf = (u16*)(WB + o_zb);
  long o_nbf = alloc((long)NN*DIM*2);  u16* node_bf = (u16*)(WB + o_nbf);
  long o_twA = alloc((long)NN*512*2);  u16* twA = (u16*)(WB + o_twA);
  long o_twh = alloc((long)NN*DIM*2);  u16* twh = (u16*)(WB + o_twh);
  long o_prA = alloc((long)NN*512*2);  u16* prA = (u16*)(WB + o_prA);
  long o_prh = alloc((long)NN*512*2);  u16* prh = (u16*)(WB + o_prh);

  u16* Wq_t  = (u16*)(WB + alloc(DIM*DIM*2));
  u16* Wk_t  = (u16*)(WB + alloc(DIM*DIM*2));
  u16* Wv_t  = (u16*)(WB + alloc(DIM*DIM*2));
  u16* Wo_t  = (u16*)(WB + alloc(DIM*DIM*2));
  u16* tw1_t = (u16*)(WB + alloc(DIM*512*2));
  u16* tw2_t = (u16*)(WB + alloc(DIM*DIM*2));
  u16* ne1_t = (u16*)(WB + alloc(512L*1024*2));
  u16* ne2_t = (u16*)(WB + alloc(DIM*512*2));
  u16* pe_t  = (u16*)(WB + alloc(DIM*DIM*2));
  u16* pq_t  = (u16*)(WB + alloc(DIM*DIM*2));
  u16* pv_t  = (u16*)(WB + alloc(DIM*DIM*2));
  u16* pr1_t = (u16*)(WB + alloc(512L*512*2));
  u16* pr2_t = (u16*)(WB + alloc(DIM*512*2));
  u16* a1_bf = (u16*)(WB + alloc(128*128*2));
  u16* a2_bf = (u16*)(WB + alloc(64*128*2));

  // -------- init --------
  hipMemsetAsync(sub, 0, 2L*NN*DIM*4, stream);
  hipMemsetAsync(cs, 0, 2L*NN*4, stream);
  hipMemsetAsync(tbl, 0, (long)NN*NN*4, stream);
  hipMemsetAsync(zbuf, 0, 1024, stream);

  // -------- packs / weight converts --------
  seg_sum_k<<<NE/4, 256, 0, stream>>>(edge_f, ei, sub, obj, cs, cd);
  conv4_k<<<(NN*DIM/4+255)/256, 256, 0, stream>>>(node_f, node_bf, NN*DIM/4);
  conv4_k<<<(NE*DIM/4+255)/256, 256, 0, stream>>>(edge_f, edge_bf, (long)NE*DIM/4);
  conv4_k<<<(128*128/4+255)/256, 256, 0, stream>>>(att_W1, a1_bf, 128*128/4);
  conv4_k<<<(64*128/4+255)/256, 256, 0, stream>>>(att_W2, a2_bf, 64*128/4);
  transw_k<<<dim3(8,8),   256, 0, stream>>>(Wq, Wq_t, DIM, DIM);
  transw_k<<<dim3(8,8),   256, 0, stream>>>(Wk, Wk_t, DIM, DIM);
  transw_k<<<dim3(8,8),   256, 0, stream>>>(Wv, Wv_t, DIM, DIM);
  transw_k<<<dim3(8,8),   256, 0, stream>>>(Wo, Wo_t, DIM, DIM);
  transw_k<<<dim3(16,8),  256, 0, stream>>>(tw_W1, tw1_t, 512, DIM);
  transw_k<<<dim3(8,8),   256, 0, stream>>>(tw_W2, tw2_t, DIM, DIM);
  transw_k<<<dim3(32,16), 256, 0, stream>>>(ne_W1, ne1_t, 1024, 512);
  transw_k<<<dim3(16,8),  256, 0, stream>>>(ne_W2, ne2_t, 512, DIM);
  transw_k<<<dim3(8,8),   256, 0, stream>>>(pe_W, pe_t, DIM, DIM);
  transw_k<<<dim3(8,8),   256, 0, stream>>>(pq_W, pq_t, DIM, DIM);
  transw_k<<<dim3(8,8),   256, 0, stream>>>(pv_W, pv_t, DIM, DIM);
  transw_k<<<dim3(16,16), 256, 0, stream>>>(pr_W1, pr1_t, 512, 512);
  transw_k<<<dim3(16,8),  256, 0, stream>>>(pr_W2, pr2_t, 512, DIM);

  // -------- CSR build (for segment-max) --------
  scan_k<<<1, 256, 0, stream>>>(cs, startp, cursor);
  scatter_k<<<NE/256, 256, 0, stream>>>(ei, cursor, eids);

  // -------- twin edge-mean gate --------
  pack_tw_k<<<NN, 128, 0, stream>>>(sub, obj, cs, cd, twA);
  gemm_bf<4,1><<<dim3(2,16,1), 256, 0, stream>>>(gb(twA, nullptr, 512, 0), tw1_t, 512, 0,
      tw_b1, twh, DIM, 0, 512, 1.f, nullptr, nullptr, nullptr, nullptr, nullptr);
  gemm_bf<4,2><<<dim3(2,16,1), 256, 0, stream>>>(gb(twh, nullptr, DIM, 0), tw2_t, DIM, 0,
      tw_b2, eatt, DIM, 0, DIM, 1.f, nullptr, nullptr, nullptr, nullptr, nullptr);

  // -------- MHSA --------
  gemm_bf<4,5><<<dim3(2,16,1), 256, 0, stream>>>(gb(node_bf, nullptr, DIM, 0), Wq_t, DIM, 0,
      bq, q_bf, DIM, 0, DIM, 1.f, nullptr, nullptr, nullptr, nullptr, nullptr);
  gemm_bf<4,5><<<dim3(2,16,1), 256, 0, stream>>>(gb(node_bf, nullptr, DIM, 0), Wk_t, DIM, 0,
      bk, k_bf, DIM, 0, DIM, 1.f, nullptr, nullptr, nullptr, nullptr, nullptr);
  gemm_bf<4,0><<<dim3(2,16,1), 256, 0, stream>>>(gb(node_bf, nullptr, DIM, 0), Wv_t, DIM, 0,
      bv, vbuf, DIM, 0, DIM, 1.f, nullptr, nullptr, nullptr, nullptr, nullptr);
  transw_k<<<dim3(64,8), 256, 0, stream>>>(vbuf, vT, NN, DIM);   // vT [256][2048] bf16

  gemm_bf<4,3><<<dim3(16,16,4), 256, 0, stream>>>(gb(q_bf, nullptr, DIM, 64), k_bf, DIM, 64,
      nullptr, S, NN, (long)NN*NN, 64, 0.125f, coords, gd_W1, gd_b1, gd_W2, gd_b2);
  softmax_k<<<NN*NH, 256, 0, stream>>>(S, Pbf);
  gemm_bf<2,5><<<dim3(1,16,4), 256, 0, stream>>>(gb(Pbf, nullptr, NN, (long)NN*NN), vT, NN, 64L*NN,
      nullptr, attn_bf, DIM, 64, NN, 1.f, nullptr, nullptr, nullptr, nullptr, nullptr);
  gemm_bf<4,0><<<dim3(2,16,1), 256, 0, stream>>>(gb(attn_bf, nullptr, DIM, 0), Wo_t, DIM, 0,
      bo, mhsa, DIM, 0, DIM, 1.f, nullptr, nullptr, nullptr, nullptr, nullptr);
  node_out_k<<<NN, 256, 0, stream>>>(mhsa, eatt, out_node);

  // -------- reverse-edge lookup + edge MLP (fused gather) --------
  scat_k<<<NE/256, 256, 0, stream>>>(ei, tbl);
  rev_k<<<NE/256, 256, 0, stream>>>(ei, tbl, rev);
  gemm_ne<<<dim3(4,256,1), 256, 0, stream>>>(node_bf, edge_bf, zbuf, ei, rev,
      ne1_t, ne_b1, nehid);                                            // R2 (Pbf dead)
  gemm_bf<4,0><<<dim3(2,256,1), 256, 0, stream>>>(gb(nehid, nullptr, 512, 0), ne2_t, 512, 0,
      ne_b2, out_edge, DIM, 0, 512, 1.f, nullptr, nullptr, nullptr, nullptr, nullptr);

  // -------- per-edge attention --------
  gemm_bf<4,6><<<dim3(2,256,1), 256, 0, stream>>>(gb(node_bf, ei + NE, DIM, 0), pv_t, DIM, 0,
      pv_b, valP, DIM, 0, DIM, 1.f, nullptr, nullptr, nullptr, nullptr, nullptr);     // R1 (S dead)
  gemm_bf<4,4><<<dim3(2,256,1), 256, 0, stream>>>(gb(node_bf, ei, DIM, 0), pq_t, DIM, 0,
      pq_b, qeA, 128, 0, DIM, 1.f, nullptr, nullptr, nullptr, nullptr, nullptr);      // cols 0-63
  gemm_bf<4,4><<<dim3(2,256,1), 256, 0, stream>>>(gb(edge_bf, nullptr, DIM, 0), pe_t, DIM, 0,
      pe_b, qeA, 128, 64, DIM, 1.f, nullptr, nullptr, nullptr, nullptr, nullptr);     // cols 64-127
  gemm_bf<4,1><<<dim3(1,1024,1), 256, 0, stream>>>(gb(qeA, nullptr, 128, 0), a1_bf, 128, 0,
      att_b1, h1, 128, 0, 128, 1.f, nullptr, nullptr, nullptr, nullptr, nullptr);     // R3 (tbl,edge_bf dead)
  gemm_bf<2,0><<<dim3(1,1024,1), 256, 0, stream>>>(gb(h1, nullptr, 128, 0), a2_bf, 128, 0,
      att_b2, Sb, 64, 0, 128, 1.f, nullptr, nullptr, nullptr, nullptr, nullptr);      // R4 (qeA dead)

  msg2_k<<<NE, 256, 0, stream>>>(Sb, valP, msgP);
  agg_k<<<NN, 256, 0, stream>>>(startp, eids, msgP, aggf);

  // -------- final node MLP --------
  pack_pr_k<<<NN, 128, 0, stream>>>(node_f, aggf, prA);
  gemm_bf<4,1><<<dim3(4,16,1), 256, 0, stream>>>(gb(prA, nullptr, 512, 0), pr1_t, 512, 0,
      pr_b1, prh, 512, 0, 512, 1.f, nullptr, nullptr, nullptr, nullptr, nullptr);
  gemm_bf<4,0><<<dim3(2,16,1), 256, 0, stream>>>(gb(prh, nullptr, 512, 0), pr2_t, 512, 0,
      pr_b2, out_xx, DIM, 0, 512, 1.f, nullptr, nullptr, nullptr, nullptr, nullptr);
}

// Round 4
// 574.811 us; speedup vs baseline: 1.1247x; 1.1247x over previous
//
#include <hip/hip_runtime.h>

#define NN 2048
#define NE 32768
#define DIM 256
#define NH 4

typedef unsigned short u16;
typedef __attribute__((ext_vector_type(4))) unsigned short u16x4;
typedef __attribute__((ext_vector_type(8))) short bf16x8;
typedef __attribute__((ext_vector_type(4))) float f32x4;

typedef __attribute__((address_space(1))) const unsigned int g_as1;
typedef __attribute__((address_space(3))) unsigned int l_as3;

__device__ __forceinline__ void gload16(const u16* g, u16* l) {
  __builtin_amdgcn_global_load_lds((g_as1*)g, (l_as3*)l, 16, 0, 0);
}

__device__ __forceinline__ u16 f2bf(float f) {
  unsigned u = __float_as_uint(f);
  unsigned r = u + 0x7FFFu + ((u >> 16) & 1u);
  return (u16)(r >> 16);
}
__device__ __forceinline__ float bf2f(u16 b) {
  return __uint_as_float(((unsigned)b) << 16);
}

// ---------------- bf16 MFMA GEMM ------------------------------------------------
// C[m][n] = epi(scale * sum_k A[m][k]*Bt[n][k] + bias[n])
struct GB { const u16* A; const int* idx; long ld; long aoffz; };

// EPI: 0 = f32 out; 1 = relu -> bf16; 2 = sigmoid -> f32; 3 = +dmask -> bf16;
//      4 = headsplit bf16; 5 = bf16 out; 6 = head-permuted f32 (valP layout)
template<int BNF, int EPI>
__global__ __launch_bounds__(256) void gemm_bf(
    GB ga, const u16* __restrict__ Bt, long bld, long boffz,
    const float* __restrict__ bias, void* __restrict__ Cp, long ldc, long coffz,
    int K, float scale, const float4* __restrict__ pk,
    const float* __restrict__ gW1, const float* __restrict__ gb1,
    const float* __restrict__ gW2, const float* __restrict__ gb2)
{
  __shared__ u16 As[128 * 64];
  __shared__ u16 Bs[32 * BNF * 64];

  const int tid = threadIdx.x;
  const int wid = tid >> 6, lane = tid & 63;
  const int bz = blockIdx.z;
  const int m0 = blockIdx.y * 128;
  const int n0 = blockIdx.x * (32 * BNF);
  const int wr = wid >> 1, wc = wid & 1;
  const int l15 = lane & 15, l4 = lane >> 4;

  const u16* asrc[4];
  #pragma unroll
  for (int c = 0; c < 4; ++c) {
    int rl = c*32 + wid*8 + (lane >> 3);
    int row = ga.idx ? ga.idx[m0 + rl] : (m0 + rl);
    int c16s = (lane & 7) ^ (rl & 7);
    asrc[c] = ga.A + ga.aoffz * bz + (long)row * ga.ld + c16s * 8;
  }
  const u16* bsrc[BNF];
  #pragma unroll
  for (int c = 0; c < BNF; ++c) {
    int rl = c*32 + wid*8 + (lane >> 3);
    int c16s = (lane & 7) ^ (rl & 7);
    bsrc[c] = Bt + boffz * bz + (long)(n0 + rl) * bld + c16s * 8;
  }

  f32x4 acc[4][BNF] = {};

  for (int k0 = 0; k0 < K; k0 += 64) {
    #pragma unroll
    for (int c = 0; c < 4; ++c)
      gload16(asrc[c] + k0, &As[(c*32 + wid*8) * 64]);
    #pragma unroll
    for (int c = 0; c < BNF; ++c)
      gload16(bsrc[c] + k0, &Bs[(c*32 + wid*8) * 64]);
    __syncthreads();

    #pragma unroll
    for (int kk = 0; kk < 2; ++kk) {
      bf16x8 af[4], bfr[BNF];
      #pragma unroll
      for (int i = 0; i < 4; ++i) {
        int r = wr*64 + i*16 + l15;
        af[i] = *(const bf16x8*)&As[r*64 + (((kk*4 + l4) ^ (r & 7)) * 8)];
      }
      #pragma unroll
      for (int j = 0; j < BNF; ++j) {
        int r = wc*(16*BNF) + j*16 + l15;
        bfr[j] = *(const bf16x8*)&Bs[r*64 + (((kk*4 + l4) ^ (r & 7)) * 8)];
      }
      #pragma unroll
      for (int i = 0; i < 4; ++i)
        #pragma unroll
        for (int j = 0; j < BNF; ++j)
          acc[i][j] = __builtin_amdgcn_mfma_f32_16x16x32_bf16(af[i], bfr[j], acc[i][j], 0, 0, 0);
    }
    __syncthreads();
  }

  if constexpr (EPI == 3) {
    // dmask epilogue via per-node geometry pack: pk[n*2]={c,s}, pk[n*2+1]={a0,a1,a2,_}
    const float b1v0 = gb1[0], b1v1 = gb1[1], b1v2 = gb1[2];
    const float w30 = gW1[9], w31 = gW1[10], w32 = gW1[11];
    const float w20 = gW2[0*4+bz], w21 = gW2[1*4+bz], w22 = gW2[2*4+bz];
    const float b2h = gb2[bz];
    float4 cp0[BNF], cp1[BNF];
    int colv[BNF];
    #pragma unroll
    for (int j = 0; j < BNF; ++j) {
      int col = n0 + wc*(16*BNF) + j*16 + l15;
      colv[j] = col;
      cp0[j] = pk[col*2]; cp1[j] = pk[col*2+1];
    }
    #pragma unroll
    for (int i = 0; i < 4; ++i) {
      #pragma unroll
      for (int r = 0; r < 4; ++r) {
        const int m = m0 + wr*64 + i*16 + l4*4 + r;
        float4 rp0 = pk[m*2], rp1 = pk[m*2+1];
        #pragma unroll
        for (int j = 0; j < BNF; ++j) {
          float dot = rp0.x*cp0[j].x + rp0.y*cp0[j].y + rp0.z*cp0[j].z;
          float sq = rp0.w + cp0[j].w - 2.f*dot;
          float dist = sq > 0.f ? sqrtf(sq) : 0.f;
          float h0 = fmaxf(b1v0 + rp1.x - cp1[j].x + dist*w30, 0.f);
          float h1_ = fmaxf(b1v1 + rp1.y - cp1[j].y + dist*w31, 0.f);
          float h2 = fmaxf(b1v2 + rp1.z - cp1[j].z + dist*w32, 0.f);
          float v = acc[i][j][r]*scale + b2h + h0*w20 + h1_*w21 + h2*w22;
          ((u16*)Cp)[coffz*bz + (long)m*ldc + colv[j]] = f2bf(v);
        }
      }
    }
  } else {
    #pragma unroll
    for (int j = 0; j < BNF; ++j) {
      const int col = n0 + wc*(16*BNF) + j*16 + l15;
      const float bb = bias ? bias[col] : 0.f;
      #pragma unroll
      for (int i = 0; i < 4; ++i) {
        #pragma unroll
        for (int r = 0; r < 4; ++r) {
          const int m = m0 + wr*64 + i*16 + l4*4 + r;
          float v = acc[i][j][r] * scale + bb;
          if constexpr (EPI == 1) v = fmaxf(v, 0.f);
          if constexpr (EPI == 2) v = 1.f / (1.f + expf(-v));
          if constexpr (EPI == 0 || EPI == 2)
            ((float*)Cp)[coffz*bz + (long)m*ldc + col] = v;
          else if constexpr (EPI == 4)
            ((u16*)Cp)[((long)(col & 3) * NE + m) * ldc + (col >> 2) + coffz] = f2bf(v);
          else if constexpr (EPI == 6)
            ((float*)Cp)[(long)m*256 + (col & 3)*64 + (col >> 2)] = v;
          else
            ((u16*)Cp)[coffz*bz + (long)m*ldc + col] = f2bf(v);
        }
      }
    }
  }
}

// ---------------- dedicated ne-MLP layer-1 GEMM: fused 4-segment gather ---------
__global__ __launch_bounds__(256) void gemm_ne(
    const u16* __restrict__ nbf, const u16* __restrict__ ebf, const u16* __restrict__ zbuf,
    const int* __restrict__ ei, const int* __restrict__ rev,
    const u16* __restrict__ Bt, const float* __restrict__ bias, u16* __restrict__ C)
{
  __shared__ u16 As[128 * 64];
  __shared__ u16 Bs[128 * 64];
  const int tid = threadIdx.x, wid = tid >> 6, lane = tid & 63;
  const int m0 = blockIdx.y * 128, n0 = blockIdx.x * 128;
  const int wr = wid >> 1, wc = wid & 1, l15 = lane & 15, l4 = lane >> 4;

  const u16* bsrc[4];
  #pragma unroll
  for (int c = 0; c < 4; ++c) {
    int rl = c*32 + wid*8 + (lane >> 3);
    int c16s = (lane & 7) ^ (rl & 7);
    bsrc[c] = Bt + (long)(n0 + rl) * 1024 + c16s * 8;
  }

  f32x4 acc[4][4] = {};

  #pragma unroll
  for (int seg = 0; seg < 4; ++seg) {
    const u16* asrc[4];
    #pragma unroll
    for (int c = 0; c < 4; ++c) {
      int rl = c*32 + wid*8 + (lane >> 3);
      int m = m0 + rl;
      int c16s = (lane & 7) ^ (rl & 7);
      const u16* base; long row;
      if (seg == 0)      { base = nbf; row = ei[m]; }
      else if (seg == 1) { base = ebf; row = m; }
      else if (seg == 2) { int r = rev[m]; base = (r >= 0) ? ebf : zbuf; row = (r >= 0) ? r : 0; }
      else               { base = nbf; row = ei[NE + m]; }
      asrc[c] = base + row * 256 + c16s * 8;
    }
    #pragma unroll
    for (int kt = 0; kt < 4; ++kt) {
      #pragma unroll
      for (int c = 0; c < 4; ++c)
        gload16(asrc[c] + kt*64, &As[(c*32 + wid*8) * 64]);
      #pragma unroll
      for (int c = 0; c < 4; ++c)
        gload16(bsrc[c] + seg*256 + kt*64, &Bs[(c*32 + wid*8) * 64]);
      __syncthreads();
      #pragma unroll
      for (int kk = 0; kk < 2; ++kk) {
        bf16x8 af[4], bfr[4];
        #pragma unroll
        for (int i = 0; i < 4; ++i) {
          int r = wr*64 + i*16 + l15;
          af[i] = *(const bf16x8*)&As[r*64 + (((kk*4 + l4) ^ (r & 7)) * 8)];
        }
        #pragma unroll
        for (int j = 0; j < 4; ++j) {
          int r = wc*64 + j*16 + l15;
          bfr[j] = *(const bf16x8*)&Bs[r*64 + (((kk*4 + l4) ^ (r & 7)) * 8)];
        }
        #pragma unroll
        for (int i = 0; i < 4; ++i)
          #pragma unroll
          for (int j = 0; j < 4; ++j)
            acc[i][j] = __builtin_amdgcn_mfma_f32_16x16x32_bf16(af[i], bfr[j], acc[i][j], 0, 0, 0);
      }
      __syncthreads();
    }
  }

  #pragma unroll
  for (int j = 0; j < 4; ++j) {
    const int col = n0 + wc*64 + j*16 + l15;
    const float bb = bias[col];
    #pragma unroll
    for (int i = 0; i < 4; ++i) {
      #pragma unroll
      for (int r = 0; r < 4; ++r) {
        const int m = m0 + wr*64 + i*16 + l4*4 + r;
        C[(long)m*512 + col] = f2bf(fmaxf(acc[i][j][r] + bb, 0.f));
      }
    }
  }
}

// ---------------- merged weight-prep mega-kernel --------------------------------
struct PrepEnt { const float* src; void* dst; int K; int N; int ntiles; int op; };
struct PrepDesc { PrepEnt e[24]; int n; };

__global__ __launch_bounds__(256) void wprep_k(PrepDesc d) {
  __shared__ float t[32][33];
  int b = blockIdx.x;
  int ei = 0;
  while (ei < d.n && b >= d.e[ei].ntiles) { b -= d.e[ei].ntiles; ++ei; }
  if (ei >= d.n) return;
  PrepEnt E = d.e[ei];
  int tid = threadIdx.x;
  if (E.op == 0) {                 // f32 [K][N] -> bf16 [N][K] transpose
    int kt = E.K >> 5;
    int bk = (b % kt) * 32, bn = (b / kt) * 32;
    int tx = tid & 31, ty = tid >> 5;
    #pragma unroll
    for (int i = ty; i < 32; i += 8) t[i][tx] = E.src[(long)(bk + i) * E.N + bn + tx];
    __syncthreads();
    u16* dst = (u16*)E.dst;
    #pragma unroll
    for (int i = ty; i < 32; i += 8) dst[(long)(bn + i) * E.K + bk + tx] = f2bf(t[tx][i]);
  } else if (E.op == 1) {          // f32 -> bf16 copy (float4 granules)
    long i = (long)b * 256 + tid;
    long n4 = ((long)E.K * E.N) >> 2;
    if (i < n4) {
      float4 v = ((const float4*)E.src)[i];
      u16x4 o = { f2bf(v.x), f2bf(v.y), f2bf(v.z), f2bf(v.w) };
      ((u16x4*)E.dst)[i] = o;
    }
  } else {                          // f32 copy (bias concat)
    int i = b * 256 + tid;
    if (i < E.N) ((float*)E.dst)[i] = E.src[i];
  }
}

// per-node geometry pack: geo[n*8] = {cx,cy,cz, |c|^2, a0,a1,a2, 0}
__global__ void geo_k(const float* __restrict__ C3, const float* __restrict__ gW1,
                      float* __restrict__ geo) {
  int n = blockIdx.x * 256 + threadIdx.x;
  if (n >= NN) return;
  float cx = C3[3*n], cy = C3[3*n+1], cz = C3[3*n+2];
  float s = cx*cx + cy*cy + cz*cz;
  float a0 = cx*gW1[0] + cy*gW1[3] + cz*gW1[6];
  float a1 = cx*gW1[1] + cy*gW1[4] + cz*gW1[7];
  float a2 = cx*gW1[2] + cy*gW1[5] + cz*gW1[8];
  float4* g = (float4*)(geo + (long)n*8);
  g[0] = make_float4(cx, cy, cz, s);
  g[1] = make_float4(a0, a1, a2, 0.f);
}

// bf16 transpose: src [NN][768] col-slice +512 -> dst [256][NN]
__global__ __launch_bounds__(256) void transb_k(const u16* __restrict__ src,
                                                u16* __restrict__ dst) {
  __shared__ u16 t[32][34];
  int bm = blockIdx.x * 32, bc = blockIdx.y * 32;
  int tx = threadIdx.x & 31, ty = threadIdx.x >> 5;
  #pragma unroll
  for (int i = ty; i < 32; i += 8) t[i][tx] = src[(long)(bm+i)*768 + 512 + bc + tx];
  __syncthreads();
  #pragma unroll
  for (int i = ty; i < 32; i += 8) dst[(long)(bc+i)*NN + bm + tx] = t[tx][i];
}

__global__ __launch_bounds__(256) void seg_sum_k(const float* __restrict__ ef,
    const int* __restrict__ ei, float* sub, float* obj, float* cs, float* cd) {
  int e = blockIdx.x * 4 + (threadIdx.x >> 6);
  int lane = threadIdx.x & 63;
  int s = ei[e], d = ei[NE + e];
  const float* row = ef + (long)e * DIM;
  #pragma unroll
  for (int c = 0; c < 4; ++c) {
    float v = row[lane + c*64];
    atomicAdd(&sub[(long)s*DIM + lane + c*64], v);
    atomicAdd(&obj[(long)d*DIM + lane + c*64], v);
  }
  if (lane == 0) { atomicAdd(&cs[s], 1.f); atomicAdd(&cd[d], 1.f); }
}

__global__ void pack_tw_k(const float* __restrict__ sub, const float* __restrict__ obj,
    const float* __restrict__ cs, const float* __restrict__ cd, u16* __restrict__ twA) {
  int n = blockIdx.x, t = threadIdx.x;  // 128 threads
  int seg = t >> 6, c = (t & 63) * 4;
  float sc = seg ? 1.f / fmaxf(cd[n], 1.f) : 1.f / fmaxf(cs[n], 1.f);
  float4 v = *(const float4*)((seg ? obj : sub) + (long)n * DIM + c);
  u16x4 o = { f2bf(v.x*sc), f2bf(v.y*sc), f2bf(v.z*sc), f2bf(v.w*sc) };
  *(u16x4*)&twA[(long)n*512 + seg*256 + c] = o;
}

__global__ void pack_pr_k(const float* __restrict__ nf, const float* __restrict__ agg,
                          u16* __restrict__ prA) {
  int n = blockIdx.x, t = threadIdx.x;  // 128 threads
  int seg = t >> 6, c = (t & 63) * 4;
  float4 v = *(const float4*)((seg ? agg : nf) + (long)n * DIM + c);
  u16x4 o = { f2bf(v.x), f2bf(v.y), f2bf(v.z), f2bf(v.w) };
  *(u16x4*)&prA[(long)n*512 + seg*256 + c] = o;
}

__global__ __launch_bounds__(256) void softmax_k(const u16* __restrict__ S,
                                                 u16* __restrict__ P) {
  long base = (long)blockIdx.x * NN;
  int t = threadIdx.x;
  u16x4 a0 = *(const u16x4*)&S[base + t*8];
  u16x4 a1 = *(const u16x4*)&S[base + t*8 + 4];
  float v[8];
  #pragma unroll
  for (int i = 0; i < 4; ++i) { v[i] = bf2f(a0[i]); v[4+i] = bf2f(a1[i]); }
  float mx = -1e30f;
  #pragma unroll
  for (int i = 0; i < 8; ++i) mx = fmaxf(mx, v[i]);
  #pragma unroll
  for (int off = 32; off; off >>= 1) mx = fmaxf(mx, __shfl_xor(mx, off));
  __shared__ float r1[4], r2[4];
  if ((t & 63) == 0) r1[t >> 6] = mx;
  __syncthreads();
  mx = fmaxf(fmaxf(r1[0], r1[1]), fmaxf(r1[2], r1[3]));
  float sum = 0.f;
  #pragma unroll
  for (int i = 0; i < 8; ++i) { v[i] = expf(v[i] - mx); sum += v[i]; }
  #pragma unroll
  for (int off = 32; off; off >>= 1) sum += __shfl_xor(sum, off);
  if ((t & 63) == 0) r2[t >> 6] = sum;
  __syncthreads();
  sum = r2[0] + r2[1] + r2[2] + r2[3];
  float inv = 1.f / sum;
  u16x4 o0, o1;
  #pragma unroll
  for (int i = 0; i < 4; ++i) { o0[i] = f2bf(v[i] * inv); o1[i] = f2bf(v[4+i] * inv); }
  *(u16x4*)&P[base + t*8] = o0;
  *(u16x4*)&P[base + t*8 + 4] = o1;
}

__global__ void node_out_k(const float* mh, const float* ea, float* out) {
  long i = (long)blockIdx.x * 256 + threadIdx.x;
  out[i] = fmaxf(mh[i], 0.f) * ea[i];
}

__global__ void scat_k(const int* ei, int* tbl) {
  int e = blockIdx.x * 256 + threadIdx.x;
  atomicMax(&tbl[(long)ei[e] * NN + ei[NE + e]], e + 1);
}

__global__ void rev_k(const int* ei, const int* tbl, int* rev) {
  int e = blockIdx.x * 256 + threadIdx.x;
  rev[e] = tbl[(long)ei[NE + e] * NN + ei[e]] - 1;
}

// ---------------- CSR build + msg/agg (atomic-free segment max) ------------------
__global__ __launch_bounds__(256) void scan_k(const float* __restrict__ cs,
    int* __restrict__ start, int* __restrict__ cursor) {
  __shared__ int part[256];
  int t = threadIdx.x;
  int loc[8]; int s = 0;
  #pragma unroll
  for (int i = 0; i < 8; ++i) { int v = (int)cs[t*8 + i]; loc[i] = s; s += v; }
  part[t] = s;
  __syncthreads();
  if (t == 0) { int a = 0; for (int i = 0; i < 256; ++i) { int v = part[i]; part[i] = a; a += v; } }
  __syncthreads();
  int base = part[t];
  #pragma unroll
  for (int i = 0; i < 8; ++i) { start[t*8+i] = base + loc[i]; cursor[t*8+i] = base + loc[i]; }
  if (t == 255) start[2048] = base + s;
}

__global__ void scatter_k(const int* __restrict__ ei, int* __restrict__ cursor,
                          int* __restrict__ eids) {
  int e = blockIdx.x * 256 + threadIdx.x;
  int pos = atomicAdd(&cursor[ei[e]], 1);
  eids[pos] = e;
}

__global__ __launch_bounds__(256) void msg2_k(const float* __restrict__ Sb,
    const float* __restrict__ valP, float* __restrict__ msgP) {
  int e = blockIdx.x;
  int t = threadIdx.x;
  int h = t >> 6;
  float s = Sb[((long)h * NE + e) * 64 + (t & 63)];
  float mx = s;
  #pragma unroll
  for (int off = 32; off; off >>= 1) mx = fmaxf(mx, __shfl_xor(mx, off));
  float p = expf(s - mx), sum = p;
  #pragma unroll
  for (int off = 32; off; off >>= 1) sum += __shfl_xor(sum, off);
  msgP[(long)e*256 + t] = (p / sum) * valP[(long)e*256 + t];
}

__global__ __launch_bounds__(256) void agg_k(const int* __restrict__ start,
    const int* __restrict__ eids, const float* __restrict__ msgP, float* __restrict__ aggf) {
  int n = blockIdx.x, t = threadIdx.x;
  int b = start[n], e_ = start[n+1];
  float mx = -1e30f;
  for (int i = b; i < e_; ++i) {
    int e = eids[i];
    mx = fmaxf(mx, msgP[(long)e*256 + t]);
  }
  int c = (t & 63) * 4 + (t >> 6);
  aggf[(long)n*256 + c] = (e_ > b) ? mx : 0.f;
}

// ---------------- host side ------------------------------------------------------
static GB gb(const u16* A, const int* idx, long ld, long aoffz) {
  GB g; g.A = A; g.idx = idx; g.ld = ld; g.aoffz = aoffz; return g;
}

extern "C" void kernel_launch(void* const* d_in, const int* in_sizes, int n_in,
                              void* d_out, int out_size, void* d_ws, size_t ws_size,
                              hipStream_t stream) {
  (void)in_sizes; (void)n_in; (void)out_size; (void)ws_size;

  const float* node_f = (const float*)d_in[0];
  const float* edge_f = (const float*)d_in[1];
  const float* coords = (const float*)d_in[2];
  const int*   ei     = (const int*)d_in[3];
  const float* Wq = (const float*)d_in[5];  const float* bq = (const float*)d_in[6];
  const float* Wk = (const float*)d_in[7];  const float* bk = (const float*)d_in[8];
  const float* Wv = (const float*)d_in[9];  const float* bv = (const float*)d_in[10];
  const float* Wo = (const float*)d_in[11]; const float* bo = (const float*)d_in[12];
  const float* gd_W1 = (const float*)d_in[13]; const float* gd_b1 = (const float*)d_in[14];
  const float* gd_W2 = (const float*)d_in[15]; const float* gd_b2 = (const float*)d_in[16];
  const float* tw_W1 = (const float*)d_in[17]; const float* tw_b1 = (const float*)d_in[18];
  const float* tw_W2 = (const float*)d_in[19]; const float* tw_b2 = (const float*)d_in[20];
  const float* ne_W1 = (const float*)d_in[21]; const float* ne_b1 = (const float*)d_in[22];
  const float* ne_W2 = (const float*)d_in[23]; const float* ne_b2 = (const float*)d_in[24];
  const float* att_W1 = (const float*)d_in[25]; const float* att_b1 = (const float*)d_in[26];
  const float* att_W2 = (const float*)d_in[27]; const float* att_b2 = (const float*)d_in[28];
  const float* pe_W = (const float*)d_in[29]; const float* pe_b = (const float*)d_in[30];
  const float* pq_W = (const float*)d_in[31]; const float* pq_b = (const float*)d_in[32];
  const float* pv_W = (const float*)d_in[33]; const float* pv_b = (const float*)d_in[34];
  const float* pr_W1 = (const float*)d_in[35]; const float* pr_b1 = (const float*)d_in[36];
  const float* pr_W2 = (const float*)d_in[37]; const float* pr_b2 = (const float*)d_in[38];

  char* WB = (char*)d_ws;
  float* out = (float*)d_out;
  float* out_node = out;
  float* out_edge = out + (long)NN*DIM;
  float* out_xx   = out + (long)NN*DIM + (long)NE*DIM;

  // -------- workspace: big time-union'd regions --------
  const long sz_R1 = 4L*NN*NN*4;   // 67.1 MB : S u16 (33.5) -> valP f32 (33.5) + msgP f32 (33.5)
  const long sz_R2 = 4L*NN*NN*2;   // 33.5 MB : P_bf -> nehid bf16
  const long sz_R3 = 4L*NE*128*2;  // 33.5 MB : tbl int (16.8) + edge_bf (16.8); tbl -> h1 bf16
  const long sz_R4 = 4L*NE*128*2;  // 33.5 MB : qeA bf16 -> Sb f32
  const long R1 = 0, R2 = R1 + sz_R1, R3 = R2 + sz_R2, R4 = R3 + sz_R3;

  u16*   S      = (u16*)(WB + R1);
  float* valP   = (float*)(WB + R1);
  float* msgP   = (float*)(WB + R1 + sz_R1/2);
  u16*   Pbf    = (u16*)(WB + R2);
  u16*   nehid  = (u16*)(WB + R2);
  int*   tbl    = (int*)(WB + R3);
  u16*   h1     = (u16*)(WB + R3);
  u16*   edge_bf= (u16*)(WB + R3 + (long)NN*NN*4);
  u16*   qeA    = (u16*)(WB + R4);
  float* Sb     = (float*)(WB + R4);

  long cur = R4 + sz_R4;
  auto alloc = [&](long bytes) { long o = cur; cur += (bytes + 255) & ~255L; return o; };

  long o_sub = alloc(2L*NN*DIM*4);          // sub+obj -> later qkv_bf | vT,attn_bf
  float* sub = (float*)(WB + o_sub);
  float* obj = sub + (long)NN*DIM;
  u16* qkv_bf  = (u16*)sub;                 // [2048][768]
  u16* vT      = (u16*)obj;                 // [256][2048]
  u16* attn_bf = vT + (long)NN*DIM;

  long o_cs  = alloc(2L*NN*4);
  float* cs = (float*)(WB + o_cs); float* cd = cs + NN;
  long o_mh  = alloc((long)NN*DIM*4);  float* mhsa = (float*)(WB + o_mh);
  long o_ea  = alloc((long)NN*DIM*4);  float* eatt = (float*)(WB + o_ea);
  long o_ag  = alloc((long)NN*DIM*4);  float* aggf = (float*)(WB + o_ag);
  long o_rv  = alloc((long)NE*4);      int* rev = (int*)(WB + o_rv);
  long o_st  = alloc((NN+1)*4);        int* startp = (int*)(WB + o_st);
  long o_cu  = alloc(NN*4);            int* cursor = (int*)(WB + o_cu);
  long o_eid = alloc((long)NE*4);      int* eids = (int*)(WB + o_eid);
  long o_zb  = alloc(1024);            u16* zbuf = (u16*)(WB + o_zb);
  long o_geo = alloc((long)NN*8*4);    float* geo = (float*)(WB + o_geo);
  long o_nbf = alloc((long)NN*DIM*2);  u16* node_bf = (u16*)(WB + o_nbf);
  long o_twA = alloc((long)NN*512*2);  u16* twA = (u16*)(WB + o_twA);
  long o_twh = alloc((long)NN*DIM*2);  u16* twh = (u16*)(WB + o_twh);
  long o_prA = alloc((long)NN*512*2);  u16* prA = (u16*)(WB + o_prA);
  long o_prh = alloc((long)NN*512*2);  u16* prh = (u16*)(WB + o_prh);

  u16* qkv_t = (u16*)(WB + alloc(3L*DIM*DIM*2));   // Wq_t | Wk_t | Wv_t contiguous
  u16* Wo_t  = (u16*)(WB + alloc(DIM*DIM*2));
  u16* tw1_t = (u16*)(WB + alloc(DIM*512*2));
  u16* tw2_t = (u16*)(WB + alloc(DIM*DIM*2));
  u16* ne1_t = (u16*)(WB + alloc(512L*1024*2));
  u16* ne2_t = (u16*)(WB + alloc(DIM*512*2));
  u16* pe_t  = (u16*)(WB + alloc(DIM*DIM*2));
  u16* pq_t  = (u16*)(WB + alloc(DIM*DIM*2));
  u16* pv_t  = (u16*)(WB + alloc(DIM*DIM*2));
  u16* pr1_t = (u16*)(WB + alloc(512L*512*2));
  u16* pr2_t = (u16*)(WB + alloc(DIM*512*2));
  u16* a1_bf = (u16*)(WB + alloc(128*128*2));
  u16* a2_bf = (u16*)(WB + alloc(64*128*2));
  float* qkvb = (float*)(WB + alloc(768*4));

  // -------- init --------
  hipMemsetAsync(sub, 0, 2L*NN*DIM*4, stream);
  hipMemsetAsync(cs, 0, 2L*NN*4, stream);
  hipMemsetAsync(tbl, 0, (long)NN*NN*4, stream);
  hipMemsetAsync(zbuf, 0, 1024, stream);

  // -------- merged weight prep (one launch) --------
  PrepDesc pd{}; int ne_ = 0; int tot = 0;
  auto addT = [&](const float* s, u16* d, int K, int N) {
    pd.e[ne_] = { s, d, K, N, (K/32)*(N/32), 0 }; tot += pd.e[ne_].ntiles; ++ne_;
  };
  auto addC = [&](const float* s, u16* d, long elems) {
    int nt = (int)((elems/4 + 255) / 256);
    pd.e[ne_] = { s, d, 1, (int)elems, nt, 1 }; tot += nt; ++ne_;
  };
  auto addB = [&](const float* s, float* d, int n) {
    pd.e[ne_] = { s, d, 1, n, (n + 255)/256, 2 }; tot += pd.e[ne_].ntiles; ++ne_;
  };
  addT(Wq, qkv_t,               DIM, DIM);
  addT(Wk, qkv_t + DIM*DIM,     DIM, DIM);
  addT(Wv, qkv_t + 2*DIM*DIM,   DIM, DIM);
  addT(Wo, Wo_t, DIM, DIM);
  addT(tw_W1, tw1_t, 512, DIM);
  addT(tw_W2, tw2_t, DIM, DIM);
  addT(ne_W1, ne1_t, 1024, 512);
  addT(ne_W2, ne2_t, 512, DIM);
  addT(pe_W, pe_t, DIM, DIM);
  addT(pq_W, pq_t, DIM, DIM);
  addT(pv_W, pv_t, DIM, DIM);
  addT(pr_W1, pr1_t, 512, 512);
  addT(pr_W2, pr2_t, 512, DIM);
  addC(att_W1, a1_bf, 128*128);
  addC(att_W2, a2_bf, 64*128);
  addC(node_f, node_bf, (long)NN*DIM);
  addC(edge_f, edge_bf, (long)NE*DIM);
  addB(bq, qkvb, 256); addB(bk, qkvb + 256, 256); addB(bv, qkvb + 512, 256);
  pd.n = ne_;
  wprep_k<<<tot, 256, 0, stream>>>(pd);
  geo_k<<<NN/256, 256, 0, stream>>>(coords, gd_W1, geo);

  // -------- twin edge-mean gate --------
  seg_sum_k<<<NE/4, 256, 0, stream>>>(edge_f, ei, sub, obj, cs, cd);
  scan_k<<<1, 256, 0, stream>>>(cs, startp, cursor);
  scatter_k<<<NE/256, 256, 0, stream>>>(ei, cursor, eids);
  pack_tw_k<<<NN, 128, 0, stream>>>(sub, obj, cs, cd, twA);
  gemm_bf<4,1><<<dim3(2,16,1), 256, 0, stream>>>(gb(twA, nullptr, 512, 0), tw1_t, 512, 0,
      tw_b1, twh, DIM, 0, 512, 1.f, nullptr, nullptr, nullptr, nullptr, nullptr);
  gemm_bf<4,2><<<dim3(2,16,1), 256, 0, stream>>>(gb(twh, nullptr, DIM, 0), tw2_t, DIM, 0,
      tw_b2, eatt, DIM, 0, DIM, 1.f, nullptr, nullptr, nullptr, nullptr, nullptr);

  // -------- MHSA --------
  gemm_bf<4,5><<<dim3(6,16,1), 256, 0, stream>>>(gb(node_bf, nullptr, DIM, 0), qkv_t, DIM, 0,
      qkvb, qkv_bf, 768, 0, DIM, 1.f, nullptr, nullptr, nullptr, nullptr, nullptr);
  transb_k<<<dim3(64,8), 256, 0, stream>>>(qkv_bf, vT);

  gemm_bf<4,3><<<dim3(16,16,4), 256, 0, stream>>>(gb(qkv_bf, nullptr, 768, 64), qkv_bf + 256, 768, 64,
      nullptr, S, NN, (long)NN*NN, 64, 0.125f, (const float4*)geo, gd_W1, gd_b1, gd_W2, gd_b2);
  softmax_k<<<NN*NH, 256, 0, stream>>>(S, Pbf);
  gemm_bf<2,5><<<dim3(1,16,4), 256, 0, stream>>>(gb(Pbf, nullptr, NN, (long)NN*NN), vT, NN, 64L*NN,
      nullptr, attn_bf, DIM, 64, NN, 1.f, nullptr, nullptr, nullptr, nullptr, nullptr);
  gemm_bf<4,0><<<dim3(2,16,1), 256, 0, stream>>>(gb(attn_bf, nullptr, DIM, 0), Wo_t, DIM, 0,
      bo, mhsa, DIM, 0, DIM, 1.f, nullptr, nullptr, nullptr, nullptr, nullptr);
  node_out_k<<<NN, 256, 0, stream>>>(mhsa, eatt, out_node);

  // -------- reverse-edge lookup + edge MLP (fused gather) --------
  scat_k<<<NE/256, 256, 0, stream>>>(ei, tbl);
  rev_k<<<NE/256, 256, 0, stream>>>(ei, tbl, rev);
  gemm_ne<<<dim3(4,256,1), 256, 0, stream>>>(node_bf, edge_bf, zbuf, ei, rev,
      ne1_t, ne_b1, nehid);
  gemm_bf<4,0><<<dim3(2,256,1), 256, 0, stream>>>(gb(nehid, nullptr, 512, 0), ne2_t, 512, 0,
      ne_b2, out_edge, DIM, 0, 512, 1.f, nullptr, nullptr, nullptr, nullptr, nullptr);

  // -------- per-edge attention --------
  gemm_bf<4,6><<<dim3(2,256,1), 256, 0, stream>>>(gb(node_bf, ei + NE, DIM, 0), pv_t, DIM, 0,
      pv_b, valP, DIM, 0, DIM, 1.f, nullptr, nullptr, nullptr, nullptr, nullptr);
  gemm_bf<4,4><<<dim3(2,256,1), 256, 0, stream>>>(gb(node_bf, ei, DIM, 0), pq_t, DIM, 0,
      pq_b, qeA, 128, 0, DIM, 1.f, nullptr, nullptr, nullptr, nullptr, nullptr);
  gemm_bf<4,4><<<dim3(2,256,1), 256, 0, stream>>>(gb(edge_bf, nullptr, DIM, 0), pe_t, DIM, 0,
      pe_b, qeA, 128, 64, DIM, 1.f, nullptr, nullptr, nullptr, nullptr, nullptr);
  gemm_bf<4,1><<<dim3(1,1024,1), 256, 0, stream>>>(gb(qeA, nullptr, 128, 0), a1_bf, 128, 0,
      att_b1, h1, 128, 0, 128, 1.f, nullptr, nullptr, nullptr, nullptr, nullptr);
  gemm_bf<2,0><<<dim3(1,1024,1), 256, 0, stream>>>(gb(h1, nullptr, 128, 0), a2_bf, 128, 0,
      att_b2, Sb, 64, 0, 128, 1.f, nullptr, nullptr, nullptr, nullptr, nullptr);

  msg2_k<<<NE, 256, 0, stream>>>(Sb, valP, msgP);
  agg_k<<<NN, 256, 0, stream>>>(startp, eids, msgP, aggf);

  // -------- final node MLP --------
  pack_pr_k<<<NN, 128, 0, stream>>>(node_f, aggf, prA);
  gemm_bf<4,1><<<dim3(4,16,1), 256, 0, stream>>>(gb(prA, nullptr, 512, 0), pr1_t, 512, 0,
      pr_b1, prh, 512, 0, 512, 1.f, nullptr, nullptr, nullptr, nullptr, nullptr);
  gemm_bf<4,0><<<dim3(2,16,1), 256, 0, stream>>>(gb(prh, nullptr, 512, 0), pr2_t, 512, 0,
      pr_b2, out_xx, DIM, 0, 512, 1.f, nullptr, nullptr, nullptr, nullptr, nullptr);
}

// Round 5
// 556.561 us; speedup vs baseline: 1.1616x; 1.0328x over previous
//
#include <hip/hip_runtime.h>

#define NN 2048
#define NE 32768
#define DIM 256
#define NH 4

typedef unsigned short u16;
typedef __attribute__((ext_vector_type(4))) unsigned short u16x4;
typedef __attribute__((ext_vector_type(8))) short bf16x8;
typedef __attribute__((ext_vector_type(4))) float f32x4;

typedef __attribute__((address_space(1))) const unsigned int g_as1;
typedef __attribute__((address_space(3))) unsigned int l_as3;

__device__ __forceinline__ void gload16(const u16* g, u16* l) {
  __builtin_amdgcn_global_load_lds((g_as1*)g, (l_as3*)l, 16, 0, 0);
}

__device__ __forceinline__ u16 f2bf(float f) {
  unsigned u = __float_as_uint(f);
  unsigned r = u + 0x7FFFu + ((u >> 16) & 1u);
  return (u16)(r >> 16);
}
__device__ __forceinline__ float bf2f(u16 b) {
  return __uint_as_float(((unsigned)b) << 16);
}

// ---------------- bf16 MFMA GEMM ------------------------------------------------
// C[m][n] = epi(scale * sum_k A[m][k]*Bt[n][k] + bias[n])
struct GB { const u16* A; const int* idx; long ld; long aoffz; };

// EPI: 0 = f32 out; 1 = relu -> bf16; 2 = sigmoid -> f32;
//      4 = headsplit bf16; 5 = bf16 out; 6 = head-permuted f32 (valP layout)
template<int BNF, int EPI>
__global__ __launch_bounds__(256) void gemm_bf(
    GB ga, const u16* __restrict__ Bt, long bld, long boffz,
    const float* __restrict__ bias, void* __restrict__ Cp, long ldc, long coffz,
    int K, float scale)
{
  __shared__ u16 As[128 * 64];
  __shared__ u16 Bs[32 * BNF * 64];

  const int tid = threadIdx.x;
  const int wid = tid >> 6, lane = tid & 63;
  const int bz = blockIdx.z;
  const int m0 = blockIdx.y * 128;
  const int n0 = blockIdx.x * (32 * BNF);
  const int wr = wid >> 1, wc = wid & 1;
  const int l15 = lane & 15, l4 = lane >> 4;

  const u16* asrc[4];
  #pragma unroll
  for (int c = 0; c < 4; ++c) {
    int rl = c*32 + wid*8 + (lane >> 3);
    int row = ga.idx ? ga.idx[m0 + rl] : (m0 + rl);
    int c16s = (lane & 7) ^ (rl & 7);
    asrc[c] = ga.A + ga.aoffz * bz + (long)row * ga.ld + c16s * 8;
  }
  const u16* bsrc[BNF];
  #pragma unroll
  for (int c = 0; c < BNF; ++c) {
    int rl = c*32 + wid*8 + (lane >> 3);
    int c16s = (lane & 7) ^ (rl & 7);
    bsrc[c] = Bt + boffz * bz + (long)(n0 + rl) * bld + c16s * 8;
  }

  f32x4 acc[4][BNF] = {};

  for (int k0 = 0; k0 < K; k0 += 64) {
    #pragma unroll
    for (int c = 0; c < 4; ++c)
      gload16(asrc[c] + k0, &As[(c*32 + wid*8) * 64]);
    #pragma unroll
    for (int c = 0; c < BNF; ++c)
      gload16(bsrc[c] + k0, &Bs[(c*32 + wid*8) * 64]);
    __syncthreads();

    #pragma unroll
    for (int kk = 0; kk < 2; ++kk) {
      bf16x8 af[4], bfr[BNF];
      #pragma unroll
      for (int i = 0; i < 4; ++i) {
        int r = wr*64 + i*16 + l15;
        af[i] = *(const bf16x8*)&As[r*64 + (((kk*4 + l4) ^ (r & 7)) * 8)];
      }
      #pragma unroll
      for (int j = 0; j < BNF; ++j) {
        int r = wc*(16*BNF) + j*16 + l15;
        bfr[j] = *(const bf16x8*)&Bs[r*64 + (((kk*4 + l4) ^ (r & 7)) * 8)];
      }
      #pragma unroll
      for (int i = 0; i < 4; ++i)
        #pragma unroll
        for (int j = 0; j < BNF; ++j)
          acc[i][j] = __builtin_amdgcn_mfma_f32_16x16x32_bf16(af[i], bfr[j], acc[i][j], 0, 0, 0);
    }
    __syncthreads();
  }

  #pragma unroll
  for (int j = 0; j < BNF; ++j) {
    const int col = n0 + wc*(16*BNF) + j*16 + l15;
    const float bb = bias ? bias[col] : 0.f;
    #pragma unroll
    for (int i = 0; i < 4; ++i) {
      #pragma unroll
      for (int r = 0; r < 4; ++r) {
        const int m = m0 + wr*64 + i*16 + l4*4 + r;
        float v = acc[i][j][r] * scale + bb;
        if constexpr (EPI == 1) v = fmaxf(v, 0.f);
        if constexpr (EPI == 2) v = 1.f / (1.f + expf(-v));
        if constexpr (EPI == 0 || EPI == 2)
          ((float*)Cp)[coffz*bz + (long)m*ldc + col] = v;
        else if constexpr (EPI == 4)
          ((u16*)Cp)[((long)(col & 3) * NE + m) * ldc + (col >> 2) + coffz] = f2bf(v);
        else if constexpr (EPI == 6)
          ((float*)Cp)[(long)m*256 + (col & 3)*64 + (col >> 2)] = v;
        else
          ((u16*)Cp)[coffz*bz + (long)m*ldc + col] = f2bf(v);
      }
    }
  }
}

// ---------------- fused flash MHSA: QK^T + dmask + online softmax + PV ----------
// grid: 128 blocks = 32 q-row-tiles (64 rows) x 4 heads; 4 waves, each owns 16 rows
__global__ __launch_bounds__(256) void flash_k(
    const u16* __restrict__ qkv,   // [NN][768] bf16  (q|k|v)
    const u16* __restrict__ vT,    // [256][NN] bf16  (v transposed)
    const float4* __restrict__ pk, // geo pack: pk[n*2]={c,|c|^2}, pk[n*2+1]={a0,a1,a2,0}
    const float* __restrict__ gW1, const float* __restrict__ gb1,
    const float* __restrict__ gW2, const float* __restrict__ gb2,
    u16* __restrict__ attn)        // [NN][256] bf16
{
  __shared__ u16 Qls[64*64];
  __shared__ u16 Kls[128*64];
  __shared__ u16 Vls[2][64*64];
  __shared__ u16 Pls[4][16*128];

  const int tid = threadIdx.x, wid = tid >> 6, lane = tid & 63;
  const int h  = blockIdx.x & 3;
  const int m0 = (blockIdx.x >> 2) * 64;
  const int l15 = lane & 15, l4 = lane >> 4;
  const int rl8 = wid*8 + (lane >> 3);   // staging row slot (0..31)
  const int c8  = lane & 7;

  // ---- stage Q (64x64) and load per-wave Q fragments ----
  #pragma unroll
  for (int c = 0; c < 2; ++c) {
    int r = c*32 + rl8;
    gload16(qkv + (long)(m0 + r)*768 + h*64 + ((c8 ^ (r & 7))*8), &Qls[(c*32 + wid*8)*64]);
  }
  __syncthreads();
  bf16x8 qf[2];
  {
    int r = wid*16 + l15;
    qf[0] = *(const bf16x8*)&Qls[r*64 + (((0*4 + l4) ^ (r & 7))*8)];
    qf[1] = *(const bf16x8*)&Qls[r*64 + (((1*4 + l4) ^ (r & 7))*8)];
  }

  // ---- per-row geometry + dmask constants ----
  const float b10 = gb1[0], b11 = gb1[1], b12 = gb1[2];
  const float w30 = gW1[9], w31 = gW1[10], w32 = gW1[11];
  const float w20 = gW2[0*4+h], w21 = gW2[1*4+h], w22 = gW2[2*4+h];
  const float b2h = gb2[h];
  float4 rp0[4], rp1[4];
  #pragma unroll
  for (int r = 0; r < 4; ++r) {
    int qrow = m0 + wid*16 + l4*4 + r;
    rp0[r] = pk[qrow*2]; rp1[r] = pk[qrow*2 + 1];
  }

  float mrun[4] = {-1e30f, -1e30f, -1e30f, -1e30f};
  float lrun[4] = {};
  f32x4 pa[4] = {};

  for (int t = 0; t < 16; ++t) {
    const int n0 = t * 128;
    // ---- stage K tile (128x64) and V tile (2 halves of 64x64) ----
    #pragma unroll
    for (int c = 0; c < 4; ++c) {
      int r = c*32 + rl8;
      gload16(qkv + (long)(n0 + r)*768 + 256 + h*64 + ((c8 ^ (r & 7))*8),
              &Kls[(c*32 + wid*8)*64]);
    }
    #pragma unroll
    for (int hh = 0; hh < 2; ++hh)
      #pragma unroll
      for (int c = 0; c < 2; ++c) {
        int r = c*32 + rl8;
        gload16(vT + (long)(h*64 + r)*NN + n0 + hh*64 + ((c8 ^ (r & 7))*8),
                &Vls[hh][(c*32 + wid*8)*64]);
      }
    __syncthreads();

    // ---- S = Q K^T (per wave: 16 rows x 128 cols) ----
    f32x4 sa[8] = {};
    #pragma unroll
    for (int kk = 0; kk < 2; ++kk) {
      #pragma unroll
      for (int j = 0; j < 8; ++j) {
        int r = j*16 + l15;
        bf16x8 bf = *(const bf16x8*)&Kls[r*64 + (((kk*4 + l4) ^ (r & 7))*8)];
        sa[j] = __builtin_amdgcn_mfma_f32_16x16x32_bf16(qf[kk], bf, sa[j], 0, 0, 0);
      }
    }

    // ---- + dmask, row max ----
    float rowmx[4] = {-1e30f, -1e30f, -1e30f, -1e30f};
    #pragma unroll
    for (int j = 0; j < 8; ++j) {
      int n = n0 + j*16 + l15;
      float4 cp0 = pk[n*2], cp1 = pk[n*2 + 1];
      #pragma unroll
      for (int r = 0; r < 4; ++r) {
        float dot = rp0[r].x*cp0.x + rp0[r].y*cp0.y + rp0[r].z*cp0.z;
        float sq = rp0[r].w + cp0.w - 2.f*dot;
        float dist = sq > 0.f ? sqrtf(sq) : 0.f;
        float h0 = fmaxf(b10 + rp1[r].x - cp1.x + dist*w30, 0.f);
        float h1 = fmaxf(b11 + rp1[r].y - cp1.y + dist*w31, 0.f);
        float h2 = fmaxf(b12 + rp1[r].z - cp1.z + dist*w32, 0.f);
        float s = sa[j][r]*0.125f + b2h + h0*w20 + h1*w21 + h2*w22;
        sa[j][r] = s;
        rowmx[r] = fmaxf(rowmx[r], s);
      }
    }
    #pragma unroll
    for (int w = 1; w < 16; w <<= 1)
      #pragma unroll
      for (int r = 0; r < 4; ++r)
        rowmx[r] = fmaxf(rowmx[r], __shfl_xor(rowmx[r], w));

    // ---- online softmax ----
    float fac[4], rs[4] = {};
    #pragma unroll
    for (int r = 0; r < 4; ++r) {
      float mnew = fmaxf(mrun[r], rowmx[r]);
      fac[r] = __expf(mrun[r] - mnew);
      mrun[r] = mnew;
    }
    #pragma unroll
    for (int j = 0; j < 8; ++j)
      #pragma unroll
      for (int r = 0; r < 4; ++r) {
        float p = __expf(sa[j][r] - mrun[r]);
        sa[j][r] = p;
        rs[r] += p;
      }
    #pragma unroll
    for (int w = 1; w < 16; w <<= 1)
      #pragma unroll
      for (int r = 0; r < 4; ++r)
        rs[r] += __shfl_xor(rs[r], w);
    #pragma unroll
    for (int r = 0; r < 4; ++r) lrun[r] = lrun[r]*fac[r] + rs[r];
    #pragma unroll
    for (int j2 = 0; j2 < 4; ++j2)
      #pragma unroll
      for (int r = 0; r < 4; ++r)
        pa[j2][r] *= fac[r];

    // ---- P -> LDS (bf16, XOR-swizzled), then PV MFMA ----
    #pragma unroll
    for (int j = 0; j < 8; ++j)
      #pragma unroll
      for (int r = 0; r < 4; ++r) {
        int qr = l4*4 + r, n = j*16 + l15;
        Pls[wid][qr*128 + (((n >> 3) ^ (qr & 7))*8) + (n & 7)] = f2bf(sa[j][r]);
      }
    #pragma unroll
    for (int ks = 0; ks < 4; ++ks) {
      bf16x8 paf = *(const bf16x8*)&Pls[wid][l15*128 + (((ks*4 + l4) ^ (l15 & 7))*8)];
      #pragma unroll
      for (int j2 = 0; j2 < 4; ++j2) {
        int r = j2*16 + l15;
        bf16x8 vf = *(const bf16x8*)&Vls[ks >> 1][r*64 + ((((ks & 1)*4 + l4) ^ (r & 7))*8)];
        pa[j2] = __builtin_amdgcn_mfma_f32_16x16x32_bf16(paf, vf, pa[j2], 0, 0, 0);
      }
    }
    __syncthreads();
  }

  // ---- normalize + write ----
  #pragma unroll
  for (int j2 = 0; j2 < 4; ++j2)
    #pragma unroll
    for (int r = 0; r < 4; ++r) {
      int m = m0 + wid*16 + l4*4 + r;
      attn[(long)m*256 + h*64 + j2*16 + l15] = f2bf(pa[j2][r] / lrun[r]);
    }
}

// ---------------- dedicated ne-MLP layer-1 GEMM: fused 4-segment gather ---------
__global__ __launch_bounds__(256) void gemm_ne(
    const u16* __restrict__ nbf, const u16* __restrict__ ebf, const u16* __restrict__ zbuf,
    const int* __restrict__ ei, const int* __restrict__ rev,
    const u16* __restrict__ Bt, const float* __restrict__ bias, u16* __restrict__ C)
{
  __shared__ u16 As[128 * 64];
  __shared__ u16 Bs[128 * 64];
  const int tid = threadIdx.x, wid = tid >> 6, lane = tid & 63;
  const int m0 = blockIdx.y * 128, n0 = blockIdx.x * 128;
  const int wr = wid >> 1, wc = wid & 1, l15 = lane & 15, l4 = lane >> 4;

  const u16* bsrc[4];
  #pragma unroll
  for (int c = 0; c < 4; ++c) {
    int rl = c*32 + wid*8 + (lane >> 3);
    int c16s = (lane & 7) ^ (rl & 7);
    bsrc[c] = Bt + (long)(n0 + rl) * 1024 + c16s * 8;
  }

  f32x4 acc[4][4] = {};

  #pragma unroll
  for (int seg = 0; seg < 4; ++seg) {
    const u16* asrc[4];
    #pragma unroll
    for (int c = 0; c < 4; ++c) {
      int rl = c*32 + wid*8 + (lane >> 3);
      int m = m0 + rl;
      int c16s = (lane & 7) ^ (rl & 7);
      const u16* base; long row;
      if (seg == 0)      { base = nbf; row = ei[m]; }
      else if (seg == 1) { base = ebf; row = m; }
      else if (seg == 2) { int r = rev[m]; base = (r >= 0) ? ebf : zbuf; row = (r >= 0) ? r : 0; }
      else               { base = nbf; row = ei[NE + m]; }
      asrc[c] = base + row * 256 + c16s * 8;
    }
    #pragma unroll
    for (int kt = 0; kt < 4; ++kt) {
      #pragma unroll
      for (int c = 0; c < 4; ++c)
        gload16(asrc[c] + kt*64, &As[(c*32 + wid*8) * 64]);
      #pragma unroll
      for (int c = 0; c < 4; ++c)
        gload16(bsrc[c] + seg*256 + kt*64, &Bs[(c*32 + wid*8) * 64]);
      __syncthreads();
      #pragma unroll
      for (int kk = 0; kk < 2; ++kk) {
        bf16x8 af[4], bfr[4];
        #pragma unroll
        for (int i = 0; i < 4; ++i) {
          int r = wr*64 + i*16 + l15;
          af[i] = *(const bf16x8*)&As[r*64 + (((kk*4 + l4) ^ (r & 7)) * 8)];
        }
        #pragma unroll
        for (int j = 0; j < 4; ++j) {
          int r = wc*64 + j*16 + l15;
          bfr[j] = *(const bf16x8*)&Bs[r*64 + (((kk*4 + l4) ^ (r & 7)) * 8)];
        }
        #pragma unroll
        for (int i = 0; i < 4; ++i)
          #pragma unroll
          for (int j = 0; j < 4; ++j)
            acc[i][j] = __builtin_amdgcn_mfma_f32_16x16x32_bf16(af[i], bfr[j], acc[i][j], 0, 0, 0);
      }
      __syncthreads();
    }
  }

  #pragma unroll
  for (int j = 0; j < 4; ++j) {
    const int col = n0 + wc*64 + j*16 + l15;
    const float bb = bias[col];
    #pragma unroll
    for (int i = 0; i < 4; ++i) {
      #pragma unroll
      for (int r = 0; r < 4; ++r) {
        const int m = m0 + wr*64 + i*16 + l4*4 + r;
        C[(long)m*512 + col] = f2bf(fmaxf(acc[i][j][r] + bb, 0.f));
      }
    }
  }
}

// ---------------- merged weight-prep mega-kernel --------------------------------
struct PrepEnt { const float* src; void* dst; int K; int N; int ntiles; int op; };
struct PrepDesc { PrepEnt e[24]; int n; };

__global__ __launch_bounds__(256) void wprep_k(PrepDesc d) {
  __shared__ float t[32][33];
  int b = blockIdx.x;
  int ei = 0;
  while (ei < d.n && b >= d.e[ei].ntiles) { b -= d.e[ei].ntiles; ++ei; }
  if (ei >= d.n) return;
  PrepEnt E = d.e[ei];
  int tid = threadIdx.x;
  if (E.op == 0) {                 // f32 [K][N] -> bf16 [N][K] transpose
    int kt = E.K >> 5;
    int bk = (b % kt) * 32, bn = (b / kt) * 32;
    int tx = tid & 31, ty = tid >> 5;
    #pragma unroll
    for (int i = ty; i < 32; i += 8) t[i][tx] = E.src[(long)(bk + i) * E.N + bn + tx];
    __syncthreads();
    u16* dst = (u16*)E.dst;
    #pragma unroll
    for (int i = ty; i < 32; i += 8) dst[(long)(bn + i) * E.K + bk + tx] = f2bf(t[tx][i]);
  } else if (E.op == 1) {          // f32 -> bf16 copy (float4 granules)
    long i = (long)b * 256 + tid;
    long n4 = ((long)E.K * E.N) >> 2;
    if (i < n4) {
      float4 v = ((const float4*)E.src)[i];
      u16x4 o = { f2bf(v.x), f2bf(v.y), f2bf(v.z), f2bf(v.w) };
      ((u16x4*)E.dst)[i] = o;
    }
  } else {                          // f32 copy (bias concat)
    int i = b * 256 + tid;
    if (i < E.N) ((float*)E.dst)[i] = E.src[i];
  }
}

// per-node geometry pack: geo[n*8] = {cx,cy,cz, |c|^2, a0,a1,a2, 0}
__global__ void geo_k(const float* __restrict__ C3, const float* __restrict__ gW1,
                      float* __restrict__ geo) {
  int n = blockIdx.x * 256 + threadIdx.x;
  if (n >= NN) return;
  float cx = C3[3*n], cy = C3[3*n+1], cz = C3[3*n+2];
  float s = cx*cx + cy*cy + cz*cz;
  float a0 = cx*gW1[0] + cy*gW1[3] + cz*gW1[6];
  float a1 = cx*gW1[1] + cy*gW1[4] + cz*gW1[7];
  float a2 = cx*gW1[2] + cy*gW1[5] + cz*gW1[8];
  float4* g = (float4*)(geo + (long)n*8);
  g[0] = make_float4(cx, cy, cz, s);
  g[1] = make_float4(a0, a1, a2, 0.f);
}

// bf16 transpose: src [NN][768] col-slice +512 -> dst [256][NN]
__global__ __launch_bounds__(256) void transb_k(const u16* __restrict__ src,
                                                u16* __restrict__ dst) {
  __shared__ u16 t[32][34];
  int bm = blockIdx.x * 32, bc = blockIdx.y * 32;
  int tx = threadIdx.x & 31, ty = threadIdx.x >> 5;
  #pragma unroll
  for (int i = ty; i < 32; i += 8) t[i][tx] = src[(long)(bm+i)*768 + 512 + bc + tx];
  __syncthreads();
  #pragma unroll
  for (int i = ty; i < 32; i += 8) dst[(long)(bc+i)*NN + bm + tx] = t[tx][i];
}

__global__ __launch_bounds__(256) void seg_sum_k(const float* __restrict__ ef,
    const int* __restrict__ ei, float* sub, float* obj, float* cs, float* cd) {
  int e = blockIdx.x * 4 + (threadIdx.x >> 6);
  int lane = threadIdx.x & 63;
  int s = ei[e], d = ei[NE + e];
  const float* row = ef + (long)e * DIM;
  #pragma unroll
  for (int c = 0; c < 4; ++c) {
    float v = row[lane + c*64];
    atomicAdd(&sub[(long)s*DIM + lane + c*64], v);
    atomicAdd(&obj[(long)d*DIM + lane + c*64], v);
  }
  if (lane == 0) { atomicAdd(&cs[s], 1.f); atomicAdd(&cd[d], 1.f); }
}

__global__ void pack_tw_k(const float* __restrict__ sub, const float* __restrict__ obj,
    const float* __restrict__ cs, const float* __restrict__ cd, u16* __restrict__ twA) {
  int n = blockIdx.x, t = threadIdx.x;  // 128 threads
  int seg = t >> 6, c = (t & 63) * 4;
  float sc = seg ? 1.f / fmaxf(cd[n], 1.f) : 1.f / fmaxf(cs[n], 1.f);
  float4 v = *(const float4*)((seg ? obj : sub) + (long)n * DIM + c);
  u16x4 o = { f2bf(v.x*sc), f2bf(v.y*sc), f2bf(v.z*sc), f2bf(v.w*sc) };
  *(u16x4*)&twA[(long)n*512 + seg*256 + c] = o;
}

__global__ void pack_pr_k(const float* __restrict__ nf, const float* __restrict__ agg,
                          u16* __restrict__ prA) {
  int n = blockIdx.x, t = threadIdx.x;  // 128 threads
  int seg = t >> 6, c = (t & 63) * 4;
  float4 v = *(const float4*)((seg ? agg : nf) + (long)n * DIM + c);
  u16x4 o = { f2bf(v.x), f2bf(v.y), f2bf(v.z), f2bf(v.w) };
  *(u16x4*)&prA[(long)n*512 + seg*256 + c] = o;
}

__global__ void node_out_k(const float* mh, const float* ea, float* out) {
  long i = (long)blockIdx.x * 256 + threadIdx.x;
  out[i] = fmaxf(mh[i], 0.f) * ea[i];
}

__global__ void scat_k(const int* ei, int* tbl) {
  int e = blockIdx.x * 256 + threadIdx.x;
  atomicMax(&tbl[(long)ei[e] * NN + ei[NE + e]], e + 1);
}

__global__ void rev_k(const int* ei, const int* tbl, int* rev) {
  int e = blockIdx.x * 256 + threadIdx.x;
  rev[e] = tbl[(long)ei[NE + e] * NN + ei[e]] - 1;
}

// ---------------- CSR build + msg/agg (atomic-free segment max) ------------------
__global__ __launch_bounds__(256) void scan_k(const float* __restrict__ cs,
    int* __restrict__ start, int* __restrict__ cursor) {
  __shared__ int part[256];
  int t = threadIdx.x;
  int loc[8]; int s = 0;
  #pragma unroll
  for (int i = 0; i < 8; ++i) { int v = (int)cs[t*8 + i]; loc[i] = s; s += v; }
  part[t] = s;
  __syncthreads();
  if (t == 0) { int a = 0; for (int i = 0; i < 256; ++i) { int v = part[i]; part[i] = a; a += v; } }
  __syncthreads();
  int base = part[t];
  #pragma unroll
  for (int i = 0; i < 8; ++i) { start[t*8+i] = base + loc[i]; cursor[t*8+i] = base + loc[i]; }
  if (t == 255) start[2048] = base + s;
}

__global__ void scatter_k(const int* __restrict__ ei, int* __restrict__ cursor,
                          int* __restrict__ eids) {
  int e = blockIdx.x * 256 + threadIdx.x;
  int pos = atomicAdd(&cursor[ei[e]], 1);
  eids[pos] = e;
}

__global__ __launch_bounds__(256) void msg2_k(const float* __restrict__ Sb,
    const float* __restrict__ valP, float* __restrict__ msgP) {
  int e = blockIdx.x;
  int t = threadIdx.x;
  int h = t >> 6;
  float s = Sb[((long)h * NE + e) * 64 + (t & 63)];
  float mx = s;
  #pragma unroll
  for (int off = 32; off; off >>= 1) mx = fmaxf(mx, __shfl_xor(mx, off));
  float p = expf(s - mx), sum = p;
  #pragma unroll
  for (int off = 32; off; off >>= 1) sum += __shfl_xor(sum, off);
  msgP[(long)e*256 + t] = (p / sum) * valP[(long)e*256 + t];
}

__global__ __launch_bounds__(256) void agg_k(const int* __restrict__ start,
    const int* __restrict__ eids, const float* __restrict__ msgP, float* __restrict__ aggf) {
  int n = blockIdx.x, t = threadIdx.x;
  int b = start[n], e_ = start[n+1];
  float mx = -1e30f;
  for (int i = b; i < e_; ++i) {
    int e = eids[i];
    mx = fmaxf(mx, msgP[(long)e*256 + t]);
  }
  int c = (t & 63) * 4 + (t >> 6);
  aggf[(long)n*256 + c] = (e_ > b) ? mx : 0.f;
}

// ---------------- host side ------------------------------------------------------
static GB gb(const u16* A, const int* idx, long ld, long aoffz) {
  GB g; g.A = A; g.idx = idx; g.ld = ld; g.aoffz = aoffz; return g;
}

extern "C" void kernel_launch(void* const* d_in, const int* in_sizes, int n_in,
                              void* d_out, int out_size, void* d_ws, size_t ws_size,
                              hipStream_t stream) {
  (void)in_sizes; (void)n_in; (void)out_size; (void)ws_size;

  const float* node_f = (const float*)d_in[0];
  const float* edge_f = (const float*)d_in[1];
  const float* coords = (const float*)d_in[2];
  const int*   ei     = (const int*)d_in[3];
  const float* Wq = (const float*)d_in[5];  const float* bq = (const float*)d_in[6];
  const float* Wk = (const float*)d_in[7];  const float* bk = (const float*)d_in[8];
  const float* Wv = (const float*)d_in[9];  const float* bv = (const float*)d_in[10];
  const float* Wo = (const float*)d_in[11]; const float* bo = (const float*)d_in[12];
  const float* gd_W1 = (const float*)d_in[13]; const float* gd_b1 = (const float*)d_in[14];
  const float* gd_W2 = (const float*)d_in[15]; const float* gd_b2 = (const float*)d_in[16];
  const float* tw_W1 = (const float*)d_in[17]; const float* tw_b1 = (const float*)d_in[18];
  const float* tw_W2 = (const float*)d_in[19]; const float* tw_b2 = (const float*)d_in[20];
  const float* ne_W1 = (const float*)d_in[21]; const float* ne_b1 = (const float*)d_in[22];
  const float* ne_W2 = (const float*)d_in[23]; const float* ne_b2 = (const float*)d_in[24];
  const float* att_W1 = (const float*)d_in[25]; const float* att_b1 = (const float*)d_in[26];
  const float* att_W2 = (const float*)d_in[27]; const float* att_b2 = (const float*)d_in[28];
  const float* pe_W = (const float*)d_in[29]; const float* pe_b = (const float*)d_in[30];
  const float* pq_W = (const float*)d_in[31]; const float* pq_b = (const float*)d_in[32];
  const float* pv_W = (const float*)d_in[33]; const float* pv_b = (const float*)d_in[34];
  const float* pr_W1 = (const float*)d_in[35]; const float* pr_b1 = (const float*)d_in[36];
  const float* pr_W2 = (const float*)d_in[37]; const float* pr_b2 = (const float*)d_in[38];

  char* WB = (char*)d_ws;
  float* out = (float*)d_out;
  float* out_node = out;
  float* out_edge = out + (long)NN*DIM;
  float* out_xx   = out + (long)NN*DIM + (long)NE*DIM;

  // -------- workspace: big time-union'd regions --------
  const long sz_R1 = 4L*NN*NN*4;   // valP f32 (33.5 MB) + msgP f32 (33.5 MB)
  const long sz_R2 = 4L*NN*NN*2;   // nehid bf16
  const long sz_R3 = 4L*NE*128*2;  // tbl int (16.8) + edge_bf (16.8); tbl -> h1 bf16
  const long sz_R4 = 4L*NE*128*2;  // qeA bf16 -> Sb f32
  const long R1 = 0, R2 = R1 + sz_R1, R3 = R2 + sz_R2, R4 = R3 + sz_R3;

  float* valP   = (float*)(WB + R1);
  float* msgP   = (float*)(WB + R1 + sz_R1/2);
  u16*   nehid  = (u16*)(WB + R2);
  int*   tbl    = (int*)(WB + R3);
  u16*   h1     = (u16*)(WB + R3);
  u16*   edge_bf= (u16*)(WB + R3 + (long)NN*NN*4);
  u16*   qeA    = (u16*)(WB + R4);
  float* Sb     = (float*)(WB + R4);

  long cur = R4 + sz_R4;
  auto alloc = [&](long bytes) { long o = cur; cur += (bytes + 255) & ~255L; return o; };

  long o_sub = alloc(2L*NN*DIM*4);          // sub+obj -> later qkv_bf | vT,attn_bf
  float* sub = (float*)(WB + o_sub);
  float* obj = sub + (long)NN*DIM;
  u16* qkv_bf  = (u16*)sub;                 // [2048][768]
  u16* vT      = (u16*)obj;                 // [256][2048]
  u16* attn_bf = vT + (long)NN*DIM;

  long o_cs  = alloc(2L*NN*4);
  float* cs = (float*)(WB + o_cs); float* cd = cs + NN;
  long o_mh  = alloc((long)NN*DIM*4);  float* mhsa = (float*)(WB + o_mh);
  long o_ea  = alloc((long)NN*DIM*4);  float* eatt = (float*)(WB + o_ea);
  long o_ag  = alloc((long)NN*DIM*4);  float* aggf = (float*)(WB + o_ag);
  long o_rv  = alloc((long)NE*4);      int* rev = (int*)(WB + o_rv);
  long o_st  = alloc((NN+1)*4);        int* startp = (int*)(WB + o_st);
  long o_cu  = alloc(NN*4);            int* cursor = (int*)(WB + o_cu);
  long o_eid = alloc((long)NE*4);      int* eids = (int*)(WB + o_eid);
  long o_zb  = alloc(1024);            u16* zbuf = (u16*)(WB + o_zb);
  long o_geo = alloc((long)NN*8*4);    float* geo = (float*)(WB + o_geo);
  long o_nbf = alloc((long)NN*DIM*2);  u16* node_bf = (u16*)(WB + o_nbf);
  long o_twA = alloc((long)NN*512*2);  u16* twA = (u16*)(WB + o_twA);
  long o_twh = alloc((long)NN*DIM*2);  u16* twh = (u16*)(WB + o_twh);
  long o_prA = alloc((long)NN*512*2);  u16* prA = (u16*)(WB + o_prA);
  long o_prh = alloc((long)NN*512*2);  u16* prh = (u16*)(WB + o_prh);

  u16* qkv_t = (u16*)(WB + alloc(3L*DIM*DIM*2));   // Wq_t | Wk_t | Wv_t contiguous
  u16* Wo_t  = (u16*)(WB + alloc(DIM*DIM*2));
  u16* tw1_t = (u16*)(WB + alloc(DIM*512*2));
  u16* tw2_t = (u16*)(WB + alloc(DIM*DIM*2));
  u16* ne1_t = (u16*)(WB + alloc(512L*1024*2));
  u16* ne2_t = (u16*)(WB + alloc(DIM*512*2));
  u16* pe_t  = (u16*)(WB + alloc(DIM*DIM*2));
  u16* pq_t  = (u16*)(WB + alloc(DIM*DIM*2));
  u16* pv_t  = (u16*)(WB + alloc(DIM*DIM*2));
  u16* pr1_t = (u16*)(WB + alloc(512L*512*2));
  u16* pr2_t = (u16*)(WB + alloc(DIM*512*2));
  u16* a1_bf = (u16*)(WB + alloc(128*128*2));
  u16* a2_bf = (u16*)(WB + alloc(64*128*2));
  float* qkvb = (float*)(WB + alloc(768*4));

  // -------- init --------
  hipMemsetAsync(sub, 0, 2L*NN*DIM*4, stream);
  hipMemsetAsync(cs, 0, 2L*NN*4, stream);
  hipMemsetAsync(tbl, 0, (long)NN*NN*4, stream);
  hipMemsetAsync(zbuf, 0, 1024, stream);

  // -------- merged weight prep (one launch) --------
  PrepDesc pd{}; int ne_ = 0; int tot = 0;
  auto addT = [&](const float* s, u16* d, int K, int N) {
    pd.e[ne_] = { s, d, K, N, (K/32)*(N/32), 0 }; tot += pd.e[ne_].ntiles; ++ne_;
  };
  auto addC = [&](const float* s, u16* d, long elems) {
    int nt = (int)((elems/4 + 255) / 256);
    pd.e[ne_] = { s, d, 1, (int)elems, nt, 1 }; tot += nt; ++ne_;
  };
  auto addB = [&](const float* s, float* d, int n) {
    pd.e[ne_] = { s, d, 1, n, (n + 255)/256, 2 }; tot += pd.e[ne_].ntiles; ++ne_;
  };
  addT(Wq, qkv_t,               DIM, DIM);
  addT(Wk, qkv_t + DIM*DIM,     DIM, DIM);
  addT(Wv, qkv_t + 2*DIM*DIM,   DIM, DIM);
  addT(Wo, Wo_t, DIM, DIM);
  addT(tw_W1, tw1_t, 512, DIM);
  addT(tw_W2, tw2_t, DIM, DIM);
  addT(ne_W1, ne1_t, 1024, 512);
  addT(ne_W2, ne2_t, 512, DIM);
  addT(pe_W, pe_t, DIM, DIM);
  addT(pq_W, pq_t, DIM, DIM);
  addT(pv_W, pv_t, DIM, DIM);
  addT(pr_W1, pr1_t, 512, 512);
  addT(pr_W2, pr2_t, 512, DIM);
  addC(att_W1, a1_bf, 128*128);
  addC(att_W2, a2_bf, 64*128);
  addC(node_f, node_bf, (long)NN*DIM);
  addC(edge_f, edge_bf, (long)NE*DIM);
  addB(bq, qkvb, 256); addB(bk, qkvb + 256, 256); addB(bv, qkvb + 512, 256);
  pd.n = ne_;
  wprep_k<<<tot, 256, 0, stream>>>(pd);
  geo_k<<<NN/256, 256, 0, stream>>>(coords, gd_W1, geo);

  // -------- twin edge-mean gate + CSR --------
  seg_sum_k<<<NE/4, 256, 0, stream>>>(edge_f, ei, sub, obj, cs, cd);
  scan_k<<<1, 256, 0, stream>>>(cs, startp, cursor);
  scatter_k<<<NE/256, 256, 0, stream>>>(ei, cursor, eids);
  pack_tw_k<<<NN, 128, 0, stream>>>(sub, obj, cs, cd, twA);
  gemm_bf<4,1><<<dim3(2,16,1), 256, 0, stream>>>(gb(twA, nullptr, 512, 0), tw1_t, 512, 0,
      tw_b1, twh, DIM, 0, 512, 1.f);
  gemm_bf<4,2><<<dim3(2,16,1), 256, 0, stream>>>(gb(twh, nullptr, DIM, 0), tw2_t, DIM, 0,
      tw_b2, eatt, DIM, 0, DIM, 1.f);

  // -------- MHSA (flash-fused) --------
  gemm_bf<4,5><<<dim3(6,16,1), 256, 0, stream>>>(gb(node_bf, nullptr, DIM, 0), qkv_t, DIM, 0,
      qkvb, qkv_bf, 768, 0, DIM, 1.f);
  transb_k<<<dim3(64,8), 256, 0, stream>>>(qkv_bf, vT);
  flash_k<<<128, 256, 0, stream>>>(qkv_bf, vT, (const float4*)geo,
      gd_W1, gd_b1, gd_W2, gd_b2, attn_bf);
  gemm_bf<4,0><<<dim3(2,16,1), 256, 0, stream>>>(gb(attn_bf, nullptr, DIM, 0), Wo_t, DIM, 0,
      bo, mhsa, DIM, 0, DIM, 1.f);
  node_out_k<<<NN, 256, 0, stream>>>(mhsa, eatt, out_node);

  // -------- reverse-edge lookup + edge MLP (fused gather) --------
  scat_k<<<NE/256, 256, 0, stream>>>(ei, tbl);
  rev_k<<<NE/256, 256, 0, stream>>>(ei, tbl, rev);
  gemm_ne<<<dim3(4,256,1), 256, 0, stream>>>(node_bf, edge_bf, zbuf, ei, rev,
      ne1_t, ne_b1, nehid);
  gemm_bf<4,0><<<dim3(2,256,1), 256, 0, stream>>>(gb(nehid, nullptr, 512, 0), ne2_t, 512, 0,
      ne_b2, out_edge, DIM, 0, 512, 1.f);

  // -------- per-edge attention --------
  gemm_bf<4,6><<<dim3(2,256,1), 256, 0, stream>>>(gb(node_bf, ei + NE, DIM, 0), pv_t, DIM, 0,
      pv_b, valP, DIM, 0, DIM, 1.f);
  gemm_bf<4,4><<<dim3(2,256,1), 256, 0, stream>>>(gb(node_bf, ei, DIM, 0), pq_t, DIM, 0,
      pq_b, qeA, 128, 0, DIM, 1.f);
  gemm_bf<4,4><<<dim3(2,256,1), 256, 0, stream>>>(gb(edge_bf, nullptr, DIM, 0), pe_t, DIM, 0,
      pe_b, qeA, 128, 64, DIM, 1.f);
  gemm_bf<4,1><<<dim3(1,1024,1), 256, 0, stream>>>(gb(qeA, nullptr, 128, 0), a1_bf, 128, 0,
      att_b1, h1, 128, 0, 128, 1.f);
  gemm_bf<2,0><<<dim3(1,1024,1), 256, 0, stream>>>(gb(h1, nullptr, 128, 0), a2_bf, 128, 0,
      att_b2, Sb, 64, 0, 128, 1.f);

  msg2_k<<<NE, 256, 0, stream>>>(Sb, valP, msgP);
  agg_k<<<NN, 256, 0, stream>>>(startp, eids, msgP, aggf);

  // -------- final node MLP --------
  pack_pr_k<<<NN, 128, 0, stream>>>(node_f, aggf, prA);
  gemm_bf<4,1><<<dim3(4,16,1), 256, 0, stream>>>(gb(prA, nullptr, 512, 0), pr1_t, 512, 0,
      pr_b1, prh, 512, 0, 512, 1.f);
  gemm_bf<4,0><<<dim3(2,16,1), 256, 0, stream>>>(gb(prh, nullptr, 512, 0), pr2_t, 512, 0,
      pr_b2, out_xx, DIM, 0, 512, 1.f);
}

// Round 6
// 488.884 us; speedup vs baseline: 1.3224x; 1.1384x over previous
//
#include <hip/hip_runtime.h>

#define NN 2048
#define NE 32768
#define DIM 256
#define NH 4

typedef unsigned short u16;
typedef __attribute__((ext_vector_type(4))) unsigned short u16x4;
typedef __attribute__((ext_vector_type(8))) short bf16x8;
typedef __attribute__((ext_vector_type(4))) float f32x4;

typedef __attribute__((address_space(1))) const unsigned int g_as1;
typedef __attribute__((address_space(3))) unsigned int l_as3;

__device__ __forceinline__ void gload16(const u16* g, u16* l) {
  __builtin_amdgcn_global_load_lds((g_as1*)g, (l_as3*)l, 16, 0, 0);
}

__device__ __forceinline__ u16 f2bf(float f) {
  unsigned u = __float_as_uint(f);
  unsigned r = u + 0x7FFFu + ((u >> 16) & 1u);
  return (u16)(r >> 16);
}
__device__ __forceinline__ float bf2f(u16 b) {
  return __uint_as_float(((unsigned)b) << 16);
}

// ---------------- bf16 MFMA GEMM ------------------------------------------------
// C[m][n] = epi(scale * sum_k A[m][k]*Bt[n][k] + bias[n])
struct GB { const u16* A; const int* idx; long ld; long aoffz; };

// EPI: 0 = f32 out; 1 = relu -> bf16; 2 = sigmoid -> f32;
//      4 = headsplit bf16; 5 = bf16 out; 6 = head-permuted f32 (valP layout)
template<int BNF, int EPI>
__global__ __launch_bounds__(256) void gemm_bf(
    GB ga, const u16* __restrict__ Bt, long bld, long boffz,
    const float* __restrict__ bias, void* __restrict__ Cp, long ldc, long coffz,
    int K, float scale)
{
  __shared__ u16 As[128 * 64];
  __shared__ u16 Bs[32 * BNF * 64];

  const int tid = threadIdx.x;
  const int wid = tid >> 6, lane = tid & 63;
  const int bz = blockIdx.z;
  const int m0 = blockIdx.y * 128;
  const int n0 = blockIdx.x * (32 * BNF);
  const int wr = wid >> 1, wc = wid & 1;
  const int l15 = lane & 15, l4 = lane >> 4;

  const u16* asrc[4];
  #pragma unroll
  for (int c = 0; c < 4; ++c) {
    int rl = c*32 + wid*8 + (lane >> 3);
    int row = ga.idx ? ga.idx[m0 + rl] : (m0 + rl);
    int c16s = (lane & 7) ^ (rl & 7);
    asrc[c] = ga.A + ga.aoffz * bz + (long)row * ga.ld + c16s * 8;
  }
  const u16* bsrc[BNF];
  #pragma unroll
  for (int c = 0; c < BNF; ++c) {
    int rl = c*32 + wid*8 + (lane >> 3);
    int c16s = (lane & 7) ^ (rl & 7);
    bsrc[c] = Bt + boffz * bz + (long)(n0 + rl) * bld + c16s * 8;
  }

  f32x4 acc[4][BNF] = {};

  for (int k0 = 0; k0 < K; k0 += 64) {
    #pragma unroll
    for (int c = 0; c < 4; ++c)
      gload16(asrc[c] + k0, &As[(c*32 + wid*8) * 64]);
    #pragma unroll
    for (int c = 0; c < BNF; ++c)
      gload16(bsrc[c] + k0, &Bs[(c*32 + wid*8) * 64]);
    __syncthreads();

    #pragma unroll
    for (int kk = 0; kk < 2; ++kk) {
      bf16x8 af[4], bfr[BNF];
      #pragma unroll
      for (int i = 0; i < 4; ++i) {
        int r = wr*64 + i*16 + l15;
        af[i] = *(const bf16x8*)&As[r*64 + (((kk*4 + l4) ^ (r & 7)) * 8)];
      }
      #pragma unroll
      for (int j = 0; j < BNF; ++j) {
        int r = wc*(16*BNF) + j*16 + l15;
        bfr[j] = *(const bf16x8*)&Bs[r*64 + (((kk*4 + l4) ^ (r & 7)) * 8)];
      }
      #pragma unroll
      for (int i = 0; i < 4; ++i)
        #pragma unroll
        for (int j = 0; j < BNF; ++j)
          acc[i][j] = __builtin_amdgcn_mfma_f32_16x16x32_bf16(af[i], bfr[j], acc[i][j], 0, 0, 0);
    }
    __syncthreads();
  }

  #pragma unroll
  for (int j = 0; j < BNF; ++j) {
    const int col = n0 + wc*(16*BNF) + j*16 + l15;
    const float bb = bias ? bias[col] : 0.f;
    #pragma unroll
    for (int i = 0; i < 4; ++i) {
      #pragma unroll
      for (int r = 0; r < 4; ++r) {
        const int m = m0 + wr*64 + i*16 + l4*4 + r;
        float v = acc[i][j][r] * scale + bb;
        if constexpr (EPI == 1) v = fmaxf(v, 0.f);
        if constexpr (EPI == 2) v = 1.f / (1.f + expf(-v));
        if constexpr (EPI == 0 || EPI == 2)
          ((float*)Cp)[coffz*bz + (long)m*ldc + col] = v;
        else if constexpr (EPI == 4)
          ((u16*)Cp)[((long)(col & 3) * NE + m) * ldc + (col >> 2) + coffz] = f2bf(v);
        else if constexpr (EPI == 6)
          ((float*)Cp)[(long)m*256 + (col & 3)*64 + (col >> 2)] = v;
        else
          ((u16*)Cp)[coffz*bz + (long)m*ldc + col] = f2bf(v);
      }
    }
  }
}

// ---------------- fused flash MHSA with KV-split ---------------------------------
// grid: (128, 4) = (32 q-tiles x 4 heads, 4 KV partitions of 512)
// writes unnormalized O-partials (f32) + per-row (m,l); comb_k merges.
__global__ __launch_bounds__(256) void flash_k(
    const u16* __restrict__ qkv,   // [NN][768] bf16  (q|k|v)
    const u16* __restrict__ vT,    // [256][NN] bf16  (v transposed)
    const float4* __restrict__ pk, // geo pack: pk[n*2]={c,|c|^2}, pk[n*2+1]={a0,a1,a2,0}
    const float* __restrict__ gW1, const float* __restrict__ gb1,
    const float* __restrict__ gW2, const float* __restrict__ gb2,
    float* __restrict__ Op,        // [4][NN][256] f32 partial O
    float2* __restrict__ ml)       // [4][NN][4] (m,l)
{
  __shared__ u16 Qls[64*64];
  __shared__ u16 Kls[128*64];
  __shared__ u16 Vls[2][64*64];
  __shared__ u16 Pls[4][16*128];

  const int tid = threadIdx.x, wid = tid >> 6, lane = tid & 63;
  const int h  = blockIdx.x & 3;
  const int m0 = (blockIdx.x >> 2) * 64;
  const int part = blockIdx.y;
  const int l15 = lane & 15, l4 = lane >> 4;
  const int rl8 = wid*8 + (lane >> 3);   // staging row slot (0..31)
  const int c8  = lane & 7;

  // ---- stage Q (64x64) and load per-wave Q fragments ----
  #pragma unroll
  for (int c = 0; c < 2; ++c) {
    int r = c*32 + rl8;
    gload16(qkv + (long)(m0 + r)*768 + h*64 + ((c8 ^ (r & 7))*8), &Qls[(c*32 + wid*8)*64]);
  }
  __syncthreads();
  bf16x8 qf[2];
  {
    int r = wid*16 + l15;
    qf[0] = *(const bf16x8*)&Qls[r*64 + (((0*4 + l4) ^ (r & 7))*8)];
    qf[1] = *(const bf16x8*)&Qls[r*64 + (((1*4 + l4) ^ (r & 7))*8)];
  }

  // ---- per-row geometry + dmask constants ----
  const float b10 = gb1[0], b11 = gb1[1], b12 = gb1[2];
  const float w30 = gW1[9], w31 = gW1[10], w32 = gW1[11];
  const float w20 = gW2[0*4+h], w21 = gW2[1*4+h], w22 = gW2[2*4+h];
  const float b2h = gb2[h];
  float4 rp0[4], rp1[4];
  #pragma unroll
  for (int r = 0; r < 4; ++r) {
    int qrow = m0 + wid*16 + l4*4 + r;
    rp0[r] = pk[qrow*2]; rp1[r] = pk[qrow*2 + 1];
  }

  float mrun[4] = {-1e30f, -1e30f, -1e30f, -1e30f};
  float lrun[4] = {};
  f32x4 pa[4] = {};

  for (int t = 0; t < 4; ++t) {
    const int n0 = part*512 + t*128;
    // ---- stage K tile (128x64) and V tile (2 halves of 64x64) ----
    #pragma unroll
    for (int c = 0; c < 4; ++c) {
      int r = c*32 + rl8;
      gload16(qkv + (long)(n0 + r)*768 + 256 + h*64 + ((c8 ^ (r & 7))*8),
              &Kls[(c*32 + wid*8)*64]);
    }
    #pragma unroll
    for (int hh = 0; hh < 2; ++hh)
      #pragma unroll
      for (int c = 0; c < 2; ++c) {
        int r = c*32 + rl8;
        gload16(vT + (long)(h*64 + r)*NN + n0 + hh*64 + ((c8 ^ (r & 7))*8),
                &Vls[hh][(c*32 + wid*8)*64]);
      }
    __syncthreads();

    // ---- S = Q K^T (per wave: 16 rows x 128 cols) ----
    f32x4 sa[8] = {};
    #pragma unroll
    for (int kk = 0; kk < 2; ++kk) {
      #pragma unroll
      for (int j = 0; j < 8; ++j) {
        int r = j*16 + l15;
        bf16x8 bf = *(const bf16x8*)&Kls[r*64 + (((kk*4 + l4) ^ (r & 7))*8)];
        sa[j] = __builtin_amdgcn_mfma_f32_16x16x32_bf16(qf[kk], bf, sa[j], 0, 0, 0);
      }
    }

    // ---- + dmask, row max ----
    float rowmx[4] = {-1e30f, -1e30f, -1e30f, -1e30f};
    #pragma unroll
    for (int j = 0; j < 8; ++j) {
      int n = n0 + j*16 + l15;
      float4 cp0 = pk[n*2], cp1 = pk[n*2 + 1];
      #pragma unroll
      for (int r = 0; r < 4; ++r) {
        float dot = rp0[r].x*cp0.x + rp0[r].y*cp0.y + rp0[r].z*cp0.z;
        float sq = rp0[r].w + cp0.w - 2.f*dot;
        float dist = sq > 0.f ? sq * __frsqrt_rn(sq) : 0.f;
        float h0 = fmaxf(b10 + rp1[r].x - cp1.x + dist*w30, 0.f);
        float h1 = fmaxf(b11 + rp1[r].y - cp1.y + dist*w31, 0.f);
        float h2 = fmaxf(b12 + rp1[r].z - cp1.z + dist*w32, 0.f);
        float s = sa[j][r]*0.125f + b2h + h0*w20 + h1*w21 + h2*w22;
        sa[j][r] = s;
        rowmx[r] = fmaxf(rowmx[r], s);
      }
    }
    #pragma unroll
    for (int w = 1; w < 16; w <<= 1)
      #pragma unroll
      for (int r = 0; r < 4; ++r)
        rowmx[r] = fmaxf(rowmx[r], __shfl_xor(rowmx[r], w));

    // ---- online softmax ----
    float fac[4], rs[4] = {};
    #pragma unroll
    for (int r = 0; r < 4; ++r) {
      float mnew = fmaxf(mrun[r], rowmx[r]);
      fac[r] = __expf(mrun[r] - mnew);
      mrun[r] = mnew;
    }
    #pragma unroll
    for (int j = 0; j < 8; ++j)
      #pragma unroll
      for (int r = 0; r < 4; ++r) {
        float p = __expf(sa[j][r] - mrun[r]);
        sa[j][r] = p;
        rs[r] += p;
      }
    #pragma unroll
    for (int w = 1; w < 16; w <<= 1)
      #pragma unroll
      for (int r = 0; r < 4; ++r)
        rs[r] += __shfl_xor(rs[r], w);
    #pragma unroll
    for (int r = 0; r < 4; ++r) lrun[r] = lrun[r]*fac[r] + rs[r];
    #pragma unroll
    for (int j2 = 0; j2 < 4; ++j2)
      #pragma unroll
      for (int r = 0; r < 4; ++r)
        pa[j2][r] *= fac[r];

    // ---- P -> LDS (bf16, XOR-swizzled), then PV MFMA ----
    #pragma unroll
    for (int j = 0; j < 8; ++j)
      #pragma unroll
      for (int r = 0; r < 4; ++r) {
        int qr = l4*4 + r, n = j*16 + l15;
        Pls[wid][qr*128 + (((n >> 3) ^ (qr & 7))*8) + (n & 7)] = f2bf(sa[j][r]);
      }
    #pragma unroll
    for (int ks = 0; ks < 4; ++ks) {
      bf16x8 paf = *(const bf16x8*)&Pls[wid][l15*128 + (((ks*4 + l4) ^ (l15 & 7))*8)];
      #pragma unroll
      for (int j2 = 0; j2 < 4; ++j2) {
        int r = j2*16 + l15;
        bf16x8 vf = *(const bf16x8*)&Vls[ks >> 1][r*64 + ((((ks & 1)*4 + l4) ^ (r & 7))*8)];
        pa[j2] = __builtin_amdgcn_mfma_f32_16x16x32_bf16(paf, vf, pa[j2], 0, 0, 0);
      }
    }
    __syncthreads();
  }

  // ---- write partials ----
  #pragma unroll
  for (int j2 = 0; j2 < 4; ++j2)
    #pragma unroll
    for (int r = 0; r < 4; ++r) {
      int m = m0 + wid*16 + l4*4 + r;
      Op[((long)part*NN + m)*256 + h*64 + j2*16 + l15] = pa[j2][r];
    }
  if (l15 == 0) {
    #pragma unroll
    for (int r = 0; r < 4; ++r) {
      int m = m0 + wid*16 + l4*4 + r;
      ml[((long)part*NN + m)*4 + h] = make_float2(mrun[r], lrun[r]);
    }
  }
}

// combine 4 KV-partition partials -> attn bf16
__global__ __launch_bounds__(256) void comb_k(const float* __restrict__ Op,
    const float2* __restrict__ ml, u16* __restrict__ attn) {
  int n = blockIdx.x, t = threadIdx.x, h = t >> 6;
  float m[4], l[4];
  #pragma unroll
  for (int p = 0; p < 4; ++p) { float2 v = ml[((long)p*NN + n)*4 + h]; m[p] = v.x; l[p] = v.y; }
  float M = fmaxf(fmaxf(m[0], m[1]), fmaxf(m[2], m[3]));
  float L = 0.f, o = 0.f;
  #pragma unroll
  for (int p = 0; p < 4; ++p) {
    float w = __expf(m[p] - M);
    L += w * l[p];
    o += w * Op[((long)p*NN + n)*256 + t];
  }
  attn[(long)n*256 + t] = f2bf(o / L);
}

// ---------------- dedicated ne-MLP layer-1 GEMM: fused 4-segment gather ---------
__global__ __launch_bounds__(256) void gemm_ne(
    const u16* __restrict__ nbf, const u16* __restrict__ ebf, const u16* __restrict__ zbuf,
    const int* __restrict__ ei, const int* __restrict__ rev,
    const u16* __restrict__ Bt, const float* __restrict__ bias, u16* __restrict__ C)
{
  __shared__ u16 As[128 * 64];
  __shared__ u16 Bs[128 * 64];
  const int tid = threadIdx.x, wid = tid >> 6, lane = tid & 63;
  const int m0 = blockIdx.y * 128, n0 = blockIdx.x * 128;
  const int wr = wid >> 1, wc = wid & 1, l15 = lane & 15, l4 = lane >> 4;

  const u16* bsrc[4];
  #pragma unroll
  for (int c = 0; c < 4; ++c) {
    int rl = c*32 + wid*8 + (lane >> 3);
    int c16s = (lane & 7) ^ (rl & 7);
    bsrc[c] = Bt + (long)(n0 + rl) * 1024 + c16s * 8;
  }

  f32x4 acc[4][4] = {};

  #pragma unroll
  for (int seg = 0; seg < 4; ++seg) {
    const u16* asrc[4];
    #pragma unroll
    for (int c = 0; c < 4; ++c) {
      int rl = c*32 + wid*8 + (lane >> 3);
      int m = m0 + rl;
      int c16s = (lane & 7) ^ (rl & 7);
      const u16* base; long row;
      if (seg == 0)      { base = nbf; row = ei[m]; }
      else if (seg == 1) { base = ebf; row = m; }
      else if (seg == 2) { int r = rev[m]; base = (r >= 0) ? ebf : zbuf; row = (r >= 0) ? r : 0; }
      else               { base = nbf; row = ei[NE + m]; }
      asrc[c] = base + row * 256 + c16s * 8;
    }
    #pragma unroll
    for (int kt = 0; kt < 4; ++kt) {
      #pragma unroll
      for (int c = 0; c < 4; ++c)
        gload16(asrc[c] + kt*64, &As[(c*32 + wid*8) * 64]);
      #pragma unroll
      for (int c = 0; c < 4; ++c)
        gload16(bsrc[c] + seg*256 + kt*64, &Bs[(c*32 + wid*8) * 64]);
      __syncthreads();
      #pragma unroll
      for (int kk = 0; kk < 2; ++kk) {
        bf16x8 af[4], bfr[4];
        #pragma unroll
        for (int i = 0; i < 4; ++i) {
          int r = wr*64 + i*16 + l15;
          af[i] = *(const bf16x8*)&As[r*64 + (((kk*4 + l4) ^ (r & 7)) * 8)];
        }
        #pragma unroll
        for (int j = 0; j < 4; ++j) {
          int r = wc*64 + j*16 + l15;
          bfr[j] = *(const bf16x8*)&Bs[r*64 + (((kk*4 + l4) ^ (r & 7)) * 8)];
        }
        #pragma unroll
        for (int i = 0; i < 4; ++i)
          #pragma unroll
          for (int j = 0; j < 4; ++j)
            acc[i][j] = __builtin_amdgcn_mfma_f32_16x16x32_bf16(af[i], bfr[j], acc[i][j], 0, 0, 0);
      }
      __syncthreads();
    }
  }

  #pragma unroll
  for (int j = 0; j < 4; ++j) {
    const int col = n0 + wc*64 + j*16 + l15;
    const float bb = bias[col];
    #pragma unroll
    for (int i = 0; i < 4; ++i) {
      #pragma unroll
      for (int r = 0; r < 4; ++r) {
        const int m = m0 + wr*64 + i*16 + l4*4 + r;
        C[(long)m*512 + col] = f2bf(fmaxf(acc[i][j][r] + bb, 0.f));
      }
    }
  }
}

// ---------------- merged weight-prep mega-kernel --------------------------------
struct PrepEnt { const float* src; void* dst; int K; int N; int ntiles; int op; };
struct PrepDesc { PrepEnt e[24]; int n; };

__global__ __launch_bounds__(256) void wprep_k(PrepDesc d) {
  __shared__ float t[32][33];
  int b = blockIdx.x;
  int ei = 0;
  while (ei < d.n && b >= d.e[ei].ntiles) { b -= d.e[ei].ntiles; ++ei; }
  if (ei >= d.n) return;
  PrepEnt E = d.e[ei];
  int tid = threadIdx.x;
  if (E.op == 0) {                 // f32 [K][N] -> bf16 [N][K] transpose
    int kt = E.K >> 5;
    int bk = (b % kt) * 32, bn = (b / kt) * 32;
    int tx = tid & 31, ty = tid >> 5;
    #pragma unroll
    for (int i = ty; i < 32; i += 8) t[i][tx] = E.src[(long)(bk + i) * E.N + bn + tx];
    __syncthreads();
    u16* dst = (u16*)E.dst;
    #pragma unroll
    for (int i = ty; i < 32; i += 8) dst[(long)(bn + i) * E.K + bk + tx] = f2bf(t[tx][i]);
  } else if (E.op == 1) {          // f32 -> bf16 copy (float4 granules)
    long i = (long)b * 256 + tid;
    long n4 = ((long)E.K * E.N) >> 2;
    if (i < n4) {
      float4 v = ((const float4*)E.src)[i];
      u16x4 o = { f2bf(v.x), f2bf(v.y), f2bf(v.z), f2bf(v.w) };
      ((u16x4*)E.dst)[i] = o;
    }
  } else {                          // f32 copy (bias concat)
    int i = b * 256 + tid;
    if (i < E.N) ((float*)E.dst)[i] = E.src[i];
  }
}

// per-node geometry pack: geo[n*8] = {cx,cy,cz, |c|^2, a0,a1,a2, 0}
__global__ void geo_k(const float* __restrict__ C3, const float* __restrict__ gW1,
                      float* __restrict__ geo) {
  int n = blockIdx.x * 256 + threadIdx.x;
  if (n >= NN) return;
  float cx = C3[3*n], cy = C3[3*n+1], cz = C3[3*n+2];
  float s = cx*cx + cy*cy + cz*cz;
  float a0 = cx*gW1[0] + cy*gW1[3] + cz*gW1[6];
  float a1 = cx*gW1[1] + cy*gW1[4] + cz*gW1[7];
  float a2 = cx*gW1[2] + cy*gW1[5] + cz*gW1[8];
  float4* g = (float4*)(geo + (long)n*8);
  g[0] = make_float4(cx, cy, cz, s);
  g[1] = make_float4(a0, a1, a2, 0.f);
}

// bf16 transpose: src [NN][768] col-slice +512 -> dst [256][NN]
__global__ __launch_bounds__(256) void transb_k(const u16* __restrict__ src,
                                                u16* __restrict__ dst) {
  __shared__ u16 t[32][34];
  int bm = blockIdx.x * 32, bc = blockIdx.y * 32;
  int tx = threadIdx.x & 31, ty = threadIdx.x >> 5;
  #pragma unroll
  for (int i = ty; i < 32; i += 8) t[i][tx] = src[(long)(bm+i)*768 + 512 + bc + tx];
  __syncthreads();
  #pragma unroll
  for (int i = ty; i < 32; i += 8) dst[(long)(bc+i)*NN + bm + tx] = t[tx][i];
}

__global__ __launch_bounds__(256) void seg_sum_k(const float* __restrict__ ef,
    const int* __restrict__ ei, float* sub, float* obj, float* cs, float* cd) {
  int e = blockIdx.x * 4 + (threadIdx.x >> 6);
  int lane = threadIdx.x & 63;
  int s = ei[e], d = ei[NE + e];
  const float* row = ef + (long)e * DIM;
  #pragma unroll
  for (int c = 0; c < 4; ++c) {
    float v = row[lane + c*64];
    atomicAdd(&sub[(long)s*DIM + lane + c*64], v);
    atomicAdd(&obj[(long)d*DIM + lane + c*64], v);
  }
  if (lane == 0) { atomicAdd(&cs[s], 1.f); atomicAdd(&cd[d], 1.f); }
}

__global__ void pack_tw_k(const float* __restrict__ sub, const float* __restrict__ obj,
    const float* __restrict__ cs, const float* __restrict__ cd, u16* __restrict__ twA) {
  int n = blockIdx.x, t = threadIdx.x;  // 128 threads
  int seg = t >> 6, c = (t & 63) * 4;
  float sc = seg ? 1.f / fmaxf(cd[n], 1.f) : 1.f / fmaxf(cs[n], 1.f);
  float4 v = *(const float4*)((seg ? obj : sub) + (long)n * DIM + c);
  u16x4 o = { f2bf(v.x*sc), f2bf(v.y*sc), f2bf(v.z*sc), f2bf(v.w*sc) };
  *(u16x4*)&twA[(long)n*512 + seg*256 + c] = o;
}

__global__ void pack_pr_k(const float* __restrict__ nf, const float* __restrict__ agg,
                          u16* __restrict__ prA) {
  int n = blockIdx.x, t = threadIdx.x;  // 128 threads
  int seg = t >> 6, c = (t & 63) * 4;
  float4 v = *(const float4*)((seg ? agg : nf) + (long)n * DIM + c);
  u16x4 o = { f2bf(v.x), f2bf(v.y), f2bf(v.z), f2bf(v.w) };
  *(u16x4*)&prA[(long)n*512 + seg*256 + c] = o;
}

__global__ void node_out_k(const float* mh, const float* ea, float* out) {
  long i = (long)blockIdx.x * 256 + threadIdx.x;
  out[i] = fmaxf(mh[i], 0.f) * ea[i];
}

__global__ void scat_k(const int* ei, int* tbl) {
  int e = blockIdx.x * 256 + threadIdx.x;
  atomicMax(&tbl[(long)ei[e] * NN + ei[NE + e]], e + 1);
}

__global__ void rev_k(const int* ei, const int* tbl, int* rev) {
  int e = blockIdx.x * 256 + threadIdx.x;
  rev[e] = tbl[(long)ei[NE + e] * NN + ei[e]] - 1;
}

// ---------------- CSR build + msg/agg (atomic-free segment max) ------------------
__global__ __launch_bounds__(256) void scan_k(const float* __restrict__ cs,
    int* __restrict__ start, int* __restrict__ cursor) {
  __shared__ int part[256];
  int t = threadIdx.x;
  int loc[8]; int s = 0;
  #pragma unroll
  for (int i = 0; i < 8; ++i) { int v = (int)cs[t*8 + i]; loc[i] = s; s += v; }
  part[t] = s;
  __syncthreads();
  if (t == 0) { int a = 0; for (int i = 0; i < 256; ++i) { int v = part[i]; part[i] = a; a += v; } }
  __syncthreads();
  int base = part[t];
  #pragma unroll
  for (int i = 0; i < 8; ++i) { start[t*8+i] = base + loc[i]; cursor[t*8+i] = base + loc[i]; }
  if (t == 255) start[2048] = base + s;
}

__global__ void scatter_k(const int* __restrict__ ei, int* __restrict__ cursor,
                          int* __restrict__ eids) {
  int e = blockIdx.x * 256 + threadIdx.x;
  int pos = atomicAdd(&cursor[ei[e]], 1);
  eids[pos] = e;
}

__global__ __launch_bounds__(256) void msg2_k(const float* __restrict__ Sb,
    const float* __restrict__ valP, float* __restrict__ msgP) {
  int e = blockIdx.x;
  int t = threadIdx.x;
  int h = t >> 6;
  float s = Sb[((long)h * NE + e) * 64 + (t & 63)];
  float mx = s;
  #pragma unroll
  for (int off = 32; off; off >>= 1) mx = fmaxf(mx, __shfl_xor(mx, off));
  float p = expf(s - mx), sum = p;
  #pragma unroll
  for (int off = 32; off; off >>= 1) sum += __shfl_xor(sum, off);
  msgP[(long)e*256 + t] = (p / sum) * valP[(long)e*256 + t];
}

__global__ __launch_bounds__(256) void agg_k(const int* __restrict__ start,
    const int* __restrict__ eids, const float* __restrict__ msgP, float* __restrict__ aggf) {
  int n = blockIdx.x, t = threadIdx.x;
  int b = start[n], e_ = start[n+1];
  float mx = -1e30f;
  for (int i = b; i < e_; ++i) {
    int e = eids[i];
    mx = fmaxf(mx, msgP[(long)e*256 + t]);
  }
  int c = (t & 63) * 4 + (t >> 6);
  aggf[(long)n*256 + c] = (e_ > b) ? mx : 0.f;
}

// ---------------- host side ------------------------------------------------------
static GB gb(const u16* A, const int* idx, long ld, long aoffz) {
  GB g; g.A = A; g.idx = idx; g.ld = ld; g.aoffz = aoffz; return g;
}

extern "C" void kernel_launch(void* const* d_in, const int* in_sizes, int n_in,
                              void* d_out, int out_size, void* d_ws, size_t ws_size,
                              hipStream_t stream) {
  (void)in_sizes; (void)n_in; (void)out_size; (void)ws_size;

  const float* node_f = (const float*)d_in[0];
  const float* edge_f = (const float*)d_in[1];
  const float* coords = (const float*)d_in[2];
  const int*   ei     = (const int*)d_in[3];
  const float* Wq = (const float*)d_in[5];  const float* bq = (const float*)d_in[6];
  const float* Wk = (const float*)d_in[7];  const float* bk = (const float*)d_in[8];
  const float* Wv = (const float*)d_in[9];  const float* bv = (const float*)d_in[10];
  const float* Wo = (const float*)d_in[11]; const float* bo = (const float*)d_in[12];
  const float* gd_W1 = (const float*)d_in[13]; const float* gd_b1 = (const float*)d_in[14];
  const float* gd_W2 = (const float*)d_in[15]; const float* gd_b2 = (const float*)d_in[16];
  const float* tw_W1 = (const float*)d_in[17]; const float* tw_b1 = (const float*)d_in[18];
  const float* tw_W2 = (const float*)d_in[19]; const float* tw_b2 = (const float*)d_in[20];
  const float* ne_W1 = (const float*)d_in[21]; const float* ne_b1 = (const float*)d_in[22];
  const float* ne_W2 = (const float*)d_in[23]; const float* ne_b2 = (const float*)d_in[24];
  const float* att_W1 = (const float*)d_in[25]; const float* att_b1 = (const float*)d_in[26];
  const float* att_W2 = (const float*)d_in[27]; const float* att_b2 = (const float*)d_in[28];
  const float* pe_W = (const float*)d_in[29]; const float* pe_b = (const float*)d_in[30];
  const float* pq_W = (const float*)d_in[31]; const float* pq_b = (const float*)d_in[32];
  const float* pv_W = (const float*)d_in[33]; const float* pv_b = (const float*)d_in[34];
  const float* pr_W1 = (const float*)d_in[35]; const float* pr_b1 = (const float*)d_in[36];
  const float* pr_W2 = (const float*)d_in[37]; const float* pr_b2 = (const float*)d_in[38];

  char* WB = (char*)d_ws;
  float* out = (float*)d_out;
  float* out_node = out;
  float* out_edge = out + (long)NN*DIM;
  float* out_xx   = out + (long)NN*DIM + (long)NE*DIM;

  // -------- workspace: big time-union'd regions --------
  const long sz_R1 = 4L*NN*NN*4;   // Opart f32 (8MB)+ml | later valP f32 (33.5 MB) + msgP f32
  const long sz_R2 = 4L*NN*NN*2;   // nehid bf16
  const long sz_R3 = 4L*NE*128*2;  // tbl int (16.8) + edge_bf (16.8); tbl -> h1 bf16
  const long sz_R4 = 4L*NE*128*2;  // qeA bf16 -> Sb f32
  const long R1 = 0, R2 = R1 + sz_R1, R3 = R2 + sz_R2, R4 = R3 + sz_R3;

  float*  Opart = (float*)(WB + R1);
  float2* mlbuf = (float2*)(WB + R1 + 4L*NN*256*4);
  float* valP   = (float*)(WB + R1);
  float* msgP   = (float*)(WB + R1 + sz_R1/2);
  u16*   nehid  = (u16*)(WB + R2);
  int*   tbl    = (int*)(WB + R3);
  u16*   h1     = (u16*)(WB + R3);
  u16*   edge_bf= (u16*)(WB + R3 + (long)NN*NN*4);
  u16*   qeA    = (u16*)(WB + R4);
  float* Sb     = (float*)(WB + R4);

  long cur = R4 + sz_R4;
  auto alloc = [&](long bytes) { long o = cur; cur += (bytes + 255) & ~255L; return o; };

  long o_sub = alloc(2L*NN*DIM*4);          // sub+obj -> later qkv_bf | vT,attn_bf
  float* sub = (float*)(WB + o_sub);
  float* obj = sub + (long)NN*DIM;
  u16* qkv_bf  = (u16*)sub;                 // [2048][768]
  u16* vT      = (u16*)obj;                 // [256][2048]
  u16* attn_bf = vT + (long)NN*DIM;

  long o_cs  = alloc(2L*NN*4);
  float* cs = (float*)(WB + o_cs); float* cd = cs + NN;
  long o_mh  = alloc((long)NN*DIM*4);  float* mhsa = (float*)(WB + o_mh);
  long o_ea  = alloc((long)NN*DIM*4);  float* eatt = (float*)(WB + o_ea);
  long o_ag  = alloc((long)NN*DIM*4);  float* aggf = (float*)(WB + o_ag);
  long o_rv  = alloc((long)NE*4);      int* rev = (int*)(WB + o_rv);
  long o_st  = alloc((NN+1)*4);        int* startp = (int*)(WB + o_st);
  long o_cu  = alloc(NN*4);            int* cursor = (int*)(WB + o_cu);
  long o_eid = alloc((long)NE*4);      int* eids = (int*)(WB + o_eid);
  long o_zb  = alloc(1024);            u16* zbuf = (u16*)(WB + o_zb);
  long o_geo = alloc((long)NN*8*4);    float* geo = (float*)(WB + o_geo);
  long o_nbf = alloc((long)NN*DIM*2);  u16* node_bf = (u16*)(WB + o_nbf);
  long o_twA = alloc((long)NN*512*2);  u16* twA = (u16*)(WB + o_twA);
  long o_twh = alloc((long)NN*DIM*2);  u16* twh = (u16*)(WB + o_twh);
  long o_prA = alloc((long)NN*512*2);  u16* prA = (u16*)(WB + o_prA);
  long o_prh = alloc((long)NN*512*2);  u16* prh = (u16*)(WB + o_prh);

  u16* qkv_t = (u16*)(WB + alloc(3L*DIM*DIM*2));   // Wq_t | Wk_t | Wv_t contiguous
  u16* Wo_t  = (u16*)(WB + alloc(DIM*DIM*2));
  u16* tw1_t = (u16*)(WB + alloc(DIM*512*2));
  u16* tw2_t = (u16*)(WB + alloc(DIM*DIM*2));
  u16* ne1_t = (u16*)(WB + alloc(512L*1024*2));
  u16* ne2_t = (u16*)(WB + alloc(DIM*512*2));
  u16* pe_t  = (u16*)(WB + alloc(DIM*DIM*2));
  u16* pq_t  = (u16*)(WB + alloc(DIM*DIM*2));
  u16* pv_t  = (u16*)(WB + alloc(DIM*DIM*2));
  u16* pr1_t = (u16*)(WB + alloc(512L*512*2));
  u16* pr2_t = (u16*)(WB + alloc(DIM*512*2));
  u16* a1_bf = (u16*)(WB + alloc(128*128*2));
  u16* a2_bf = (u16*)(WB + alloc(64*128*2));
  float* qkvb = (float*)(WB + alloc(768*4));

  // -------- init --------
  hipMemsetAsync(sub, 0, 2L*NN*DIM*4, stream);
  hipMemsetAsync(cs, 0, 2L*NN*4, stream);
  hipMemsetAsync(tbl, 0, (long)NN*NN*4, stream);
  hipMemsetAsync(zbuf, 0, 1024, stream);

  // -------- merged weight prep (one launch) --------
  PrepDesc pd{}; int ne_ = 0; int tot = 0;
  auto addT = [&](const float* s, u16* d, int K, int N) {
    pd.e[ne_] = { s, d, K, N, (K/32)*(N/32), 0 }; tot += pd.e[ne_].ntiles; ++ne_;
  };
  auto addC = [&](const float* s, u16* d, long elems) {
    int nt = (int)((elems/4 + 255) / 256);
    pd.e[ne_] = { s, d, 1, (int)elems, nt, 1 }; tot += nt; ++ne_;
  };
  auto addB = [&](const float* s, float* d, int n) {
    pd.e[ne_] = { s, d, 1, n, (n + 255)/256, 2 }; tot += pd.e[ne_].ntiles; ++ne_;
  };
  addT(Wq, qkv_t,               DIM, DIM);
  addT(Wk, qkv_t + DIM*DIM,     DIM, DIM);
  addT(Wv, qkv_t + 2*DIM*DIM,   DIM, DIM);
  addT(Wo, Wo_t, DIM, DIM);
  addT(tw_W1, tw1_t, 512, DIM);
  addT(tw_W2, tw2_t, DIM, DIM);
  addT(ne_W1, ne1_t, 1024, 512);
  addT(ne_W2, ne2_t, 512, DIM);
  addT(pe_W, pe_t, DIM, DIM);
  addT(pq_W, pq_t, DIM, DIM);
  addT(pv_W, pv_t, DIM, DIM);
  addT(pr_W1, pr1_t, 512, 512);
  addT(pr_W2, pr2_t, 512, DIM);
  addC(att_W1, a1_bf, 128*128);
  addC(att_W2, a2_bf, 64*128);
  addC(node_f, node_bf, (long)NN*DIM);
  addC(edge_f, edge_bf, (long)NE*DIM);
  addB(bq, qkvb, 256); addB(bk, qkvb + 256, 256); addB(bv, qkvb + 512, 256);
  pd.n = ne_;
  wprep_k<<<tot, 256, 0, stream>>>(pd);
  geo_k<<<NN/256, 256, 0, stream>>>(coords, gd_W1, geo);

  // -------- twin edge-mean gate + CSR --------
  seg_sum_k<<<NE/4, 256, 0, stream>>>(edge_f, ei, sub, obj, cs, cd);
  scan_k<<<1, 256, 0, stream>>>(cs, startp, cursor);
  scatter_k<<<NE/256, 256, 0, stream>>>(ei, cursor, eids);
  pack_tw_k<<<NN, 128, 0, stream>>>(sub, obj, cs, cd, twA);
  gemm_bf<4,1><<<dim3(2,16,1), 256, 0, stream>>>(gb(twA, nullptr, 512, 0), tw1_t, 512, 0,
      tw_b1, twh, DIM, 0, 512, 1.f);
  gemm_bf<4,2><<<dim3(2,16,1), 256, 0, stream>>>(gb(twh, nullptr, DIM, 0), tw2_t, DIM, 0,
      tw_b2, eatt, DIM, 0, DIM, 1.f);

  // -------- MHSA (flash-fused, KV-split x4) --------
  gemm_bf<4,5><<<dim3(6,16,1), 256, 0, stream>>>(gb(node_bf, nullptr, DIM, 0), qkv_t, DIM, 0,
      qkvb, qkv_bf, 768, 0, DIM, 1.f);
  transb_k<<<dim3(64,8), 256, 0, stream>>>(qkv_bf, vT);
  flash_k<<<dim3(128,4), 256, 0, stream>>>(qkv_bf, vT, (const float4*)geo,
      gd_W1, gd_b1, gd_W2, gd_b2, Opart, mlbuf);
  comb_k<<<NN, 256, 0, stream>>>(Opart, mlbuf, attn_bf);
  gemm_bf<4,0><<<dim3(2,16,1), 256, 0, stream>>>(gb(attn_bf, nullptr, DIM, 0), Wo_t, DIM, 0,
      bo, mhsa, DIM, 0, DIM, 1.f);
  node_out_k<<<NN, 256, 0, stream>>>(mhsa, eatt, out_node);

  // -------- reverse-edge lookup + edge MLP (fused gather) --------
  scat_k<<<NE/256, 256, 0, stream>>>(ei, tbl);
  rev_k<<<NE/256, 256, 0, stream>>>(ei, tbl, rev);
  gemm_ne<<<dim3(4,256,1), 256, 0, stream>>>(node_bf, edge_bf, zbuf, ei, rev,
      ne1_t, ne_b1, nehid);
  gemm_bf<4,0><<<dim3(2,256,1), 256, 0, stream>>>(gb(nehid, nullptr, 512, 0), ne2_t, 512, 0,
      ne_b2, out_edge, DIM, 0, 512, 1.f);

  // -------- per-edge attention --------
  gemm_bf<4,6><<<dim3(2,256,1), 256, 0, stream>>>(gb(node_bf, ei + NE, DIM, 0), pv_t, DIM, 0,
      pv_b, valP, DIM, 0, DIM, 1.f);
  gemm_bf<4,4><<<dim3(2,256,1), 256, 0, stream>>>(gb(node_bf, ei, DIM, 0), pq_t, DIM, 0,
      pq_b, qeA, 128, 0, DIM, 1.f);
  gemm_bf<4,4><<<dim3(2,256,1), 256, 0, stream>>>(gb(edge_bf, nullptr, DIM, 0), pe_t, DIM, 0,
      pe_b, qeA, 128, 64, DIM, 1.f);
  gemm_bf<4,1><<<dim3(1,1024,1), 256, 0, stream>>>(gb(qeA, nullptr, 128, 0), a1_bf, 128, 0,
      att_b1, h1, 128, 0, 128, 1.f);
  gemm_bf<2,0><<<dim3(1,1024,1), 256, 0, stream>>>(gb(h1, nullptr, 128, 0), a2_bf, 128, 0,
      att_b2, Sb, 64, 0, 128, 1.f);

  msg2_k<<<NE, 256, 0, stream>>>(Sb, valP, msgP);
  agg_k<<<NN, 256, 0, stream>>>(startp, eids, msgP, aggf);

  // -------- final node MLP --------
  pack_pr_k<<<NN, 128, 0, stream>>>(node_f, aggf, prA);
  gemm_bf<4,1><<<dim3(4,16,1), 256, 0, stream>>>(gb(prA, nullptr, 512, 0), pr1_t, 512, 0,
      pr_b1, prh, 512, 0, 512, 1.f);
  gemm_bf<4,0><<<dim3(2,16,1), 256, 0, stream>>>(gb(prh, nullptr, 512, 0), pr2_t, 512, 0,
      pr_b2, out_xx, DIM, 0, 512, 1.f);
}

// Round 7
// 447.240 us; speedup vs baseline: 1.4456x; 1.0931x over previous
//
#include <hip/hip_runtime.h>

#define NN 2048
#define NE 32768
#define DIM 256
#define NH 4

typedef unsigned short u16;
typedef __attribute__((ext_vector_type(4))) unsigned short u16x4;
typedef __attribute__((ext_vector_type(8))) short bf16x8;
typedef __attribute__((ext_vector_type(4))) float f32x4;

typedef __attribute__((address_space(1))) const unsigned int g_as1;
typedef __attribute__((address_space(3))) unsigned int l_as3;

__device__ __forceinline__ void gload16(const u16* g, u16* l) {
  __builtin_amdgcn_global_load_lds((g_as1*)g, (l_as3*)l, 16, 0, 0);
}

__device__ __forceinline__ u16 f2bf(float f) {
  unsigned u = __float_as_uint(f);
  unsigned r = u + 0x7FFFu + ((u >> 16) & 1u);
  return (u16)(r >> 16);
}
__device__ __forceinline__ float bf2f(u16 b) {
  return __uint_as_float(((unsigned)b) << 16);
}

// ---------------- bf16 MFMA GEMM ------------------------------------------------
// C[m][n] = epi(scale * sum_k A[m][k]*Bt[n][k] + bias[n])
struct GB { const u16* A; const int* idx; long ld; long aoffz; };

// EPI: 0 = f32 out; 1 = relu -> bf16; 2 = sigmoid -> f32;
//      4 = headsplit bf16 (rows=NE); 5 = bf16 out; 7 = headsplit bf16 (rows=NN)
template<int BNF, int EPI>
__global__ __launch_bounds__(256) void gemm_bf(
    GB ga, const u16* __restrict__ Bt, long bld, long boffz,
    const float* __restrict__ bias, void* __restrict__ Cp, long ldc, long coffz,
    int K, float scale)
{
  __shared__ u16 As[128 * 64];
  __shared__ u16 Bs[32 * BNF * 64];

  const int tid = threadIdx.x;
  const int wid = tid >> 6, lane = tid & 63;
  const int bz = blockIdx.z;
  const int m0 = blockIdx.y * 128;
  const int n0 = blockIdx.x * (32 * BNF);
  const int wr = wid >> 1, wc = wid & 1;
  const int l15 = lane & 15, l4 = lane >> 4;

  const u16* asrc[4];
  #pragma unroll
  for (int c = 0; c < 4; ++c) {
    int rl = c*32 + wid*8 + (lane >> 3);
    int row = ga.idx ? ga.idx[m0 + rl] : (m0 + rl);
    int c16s = (lane & 7) ^ (rl & 7);
    asrc[c] = ga.A + ga.aoffz * bz + (long)row * ga.ld + c16s * 8;
  }
  const u16* bsrc[BNF];
  #pragma unroll
  for (int c = 0; c < BNF; ++c) {
    int rl = c*32 + wid*8 + (lane >> 3);
    int c16s = (lane & 7) ^ (rl & 7);
    bsrc[c] = Bt + boffz * bz + (long)(n0 + rl) * bld + c16s * 8;
  }

  f32x4 acc[4][BNF] = {};

  for (int k0 = 0; k0 < K; k0 += 64) {
    #pragma unroll
    for (int c = 0; c < 4; ++c)
      gload16(asrc[c] + k0, &As[(c*32 + wid*8) * 64]);
    #pragma unroll
    for (int c = 0; c < BNF; ++c)
      gload16(bsrc[c] + k0, &Bs[(c*32 + wid*8) * 64]);
    __syncthreads();

    #pragma unroll
    for (int kk = 0; kk < 2; ++kk) {
      bf16x8 af[4], bfr[BNF];
      #pragma unroll
      for (int i = 0; i < 4; ++i) {
        int r = wr*64 + i*16 + l15;
        af[i] = *(const bf16x8*)&As[r*64 + (((kk*4 + l4) ^ (r & 7)) * 8)];
      }
      #pragma unroll
      for (int j = 0; j < BNF; ++j) {
        int r = wc*(16*BNF) + j*16 + l15;
        bfr[j] = *(const bf16x8*)&Bs[r*64 + (((kk*4 + l4) ^ (r & 7)) * 8)];
      }
      #pragma unroll
      for (int i = 0; i < 4; ++i)
        #pragma unroll
        for (int j = 0; j < BNF; ++j)
          acc[i][j] = __builtin_amdgcn_mfma_f32_16x16x32_bf16(af[i], bfr[j], acc[i][j], 0, 0, 0);
    }
    __syncthreads();
  }

  #pragma unroll
  for (int j = 0; j < BNF; ++j) {
    const int col = n0 + wc*(16*BNF) + j*16 + l15;
    const float bb = bias ? bias[col] : 0.f;
    #pragma unroll
    for (int i = 0; i < 4; ++i) {
      #pragma unroll
      for (int r = 0; r < 4; ++r) {
        const int m = m0 + wr*64 + i*16 + l4*4 + r;
        float v = acc[i][j][r] * scale + bb;
        if constexpr (EPI == 1) v = fmaxf(v, 0.f);
        if constexpr (EPI == 2) v = 1.f / (1.f + expf(-v));
        if constexpr (EPI == 0 || EPI == 2)
          ((float*)Cp)[coffz*bz + (long)m*ldc + col] = v;
        else if constexpr (EPI == 4)
          ((u16*)Cp)[((long)(col & 3) * NE + m) * ldc + (col >> 2) + coffz] = f2bf(v);
        else if constexpr (EPI == 7)
          ((u16*)Cp)[((long)(col & 3) * NN + m) * ldc + (col >> 2) + coffz] = f2bf(v);
        else
          ((u16*)Cp)[coffz*bz + (long)m*ldc + col] = f2bf(v);
      }
    }
  }
}

// ---------------- fused flash MHSA with KV-split ---------------------------------
__global__ __launch_bounds__(256) void flash_k(
    const u16* __restrict__ qkv,   // [NN][768] bf16  (q|k|v)
    const u16* __restrict__ vT,    // [256][NN] bf16  (v transposed)
    const float4* __restrict__ pk, // geo pack
    const float* __restrict__ gW1, const float* __restrict__ gb1,
    const float* __restrict__ gW2, const float* __restrict__ gb2,
    float* __restrict__ Op,        // [4][NN][256] f32 partial O
    float2* __restrict__ ml)       // [4][NN][4] (m,l)
{
  __shared__ u16 Qls[64*64];
  __shared__ u16 Kls[128*64];
  __shared__ u16 Vls[2][64*64];
  __shared__ u16 Pls[4][16*128];

  const int tid = threadIdx.x, wid = tid >> 6, lane = tid & 63;
  const int h  = blockIdx.x & 3;
  const int m0 = (blockIdx.x >> 2) * 64;
  const int part = blockIdx.y;
  const int l15 = lane & 15, l4 = lane >> 4;
  const int rl8 = wid*8 + (lane >> 3);
  const int c8  = lane & 7;

  #pragma unroll
  for (int c = 0; c < 2; ++c) {
    int r = c*32 + rl8;
    gload16(qkv + (long)(m0 + r)*768 + h*64 + ((c8 ^ (r & 7))*8), &Qls[(c*32 + wid*8)*64]);
  }
  __syncthreads();
  bf16x8 qf[2];
  {
    int r = wid*16 + l15;
    qf[0] = *(const bf16x8*)&Qls[r*64 + (((0*4 + l4) ^ (r & 7))*8)];
    qf[1] = *(const bf16x8*)&Qls[r*64 + (((1*4 + l4) ^ (r & 7))*8)];
  }

  const float b10 = gb1[0], b11 = gb1[1], b12 = gb1[2];
  const float w30 = gW1[9], w31 = gW1[10], w32 = gW1[11];
  const float w20 = gW2[0*4+h], w21 = gW2[1*4+h], w22 = gW2[2*4+h];
  const float b2h = gb2[h];
  float4 rp0[4], rp1[4];
  #pragma unroll
  for (int r = 0; r < 4; ++r) {
    int qrow = m0 + wid*16 + l4*4 + r;
    rp0[r] = pk[qrow*2]; rp1[r] = pk[qrow*2 + 1];
  }

  float mrun[4] = {-1e30f, -1e30f, -1e30f, -1e30f};
  float lrun[4] = {};
  f32x4 pa[4] = {};

  for (int t = 0; t < 4; ++t) {
    const int n0 = part*512 + t*128;
    #pragma unroll
    for (int c = 0; c < 4; ++c) {
      int r = c*32 + rl8;
      gload16(qkv + (long)(n0 + r)*768 + 256 + h*64 + ((c8 ^ (r & 7))*8),
              &Kls[(c*32 + wid*8)*64]);
    }
    #pragma unroll
    for (int hh = 0; hh < 2; ++hh)
      #pragma unroll
      for (int c = 0; c < 2; ++c) {
        int r = c*32 + rl8;
        gload16(vT + (long)(h*64 + r)*NN + n0 + hh*64 + ((c8 ^ (r & 7))*8),
                &Vls[hh][(c*32 + wid*8)*64]);
      }
    __syncthreads();

    f32x4 sa[8] = {};
    #pragma unroll
    for (int kk = 0; kk < 2; ++kk) {
      #pragma unroll
      for (int j = 0; j < 8; ++j) {
        int r = j*16 + l15;
        bf16x8 bf = *(const bf16x8*)&Kls[r*64 + (((kk*4 + l4) ^ (r & 7))*8)];
        sa[j] = __builtin_amdgcn_mfma_f32_16x16x32_bf16(qf[kk], bf, sa[j], 0, 0, 0);
      }
    }

    float rowmx[4] = {-1e30f, -1e30f, -1e30f, -1e30f};
    #pragma unroll
    for (int j = 0; j < 8; ++j) {
      int n = n0 + j*16 + l15;
      float4 cp0 = pk[n*2], cp1 = pk[n*2 + 1];
      #pragma unroll
      for (int r = 0; r < 4; ++r) {
        float dot = rp0[r].x*cp0.x + rp0[r].y*cp0.y + rp0[r].z*cp0.z;
        float sq = rp0[r].w + cp0.w - 2.f*dot;
        float dist = sq > 0.f ? sq * __frsqrt_rn(sq) : 0.f;
        float h0 = fmaxf(b10 + rp1[r].x - cp1.x + dist*w30, 0.f);
        float h1 = fmaxf(b11 + rp1[r].y - cp1.y + dist*w31, 0.f);
        float h2 = fmaxf(b12 + rp1[r].z - cp1.z + dist*w32, 0.f);
        float s = sa[j][r]*0.125f + b2h + h0*w20 + h1*w21 + h2*w22;
        sa[j][r] = s;
        rowmx[r] = fmaxf(rowmx[r], s);
      }
    }
    #pragma unroll
    for (int w = 1; w < 16; w <<= 1)
      #pragma unroll
      for (int r = 0; r < 4; ++r)
        rowmx[r] = fmaxf(rowmx[r], __shfl_xor(rowmx[r], w));

    float fac[4], rs[4] = {};
    #pragma unroll
    for (int r = 0; r < 4; ++r) {
      float mnew = fmaxf(mrun[r], rowmx[r]);
      fac[r] = __expf(mrun[r] - mnew);
      mrun[r] = mnew;
    }
    #pragma unroll
    for (int j = 0; j < 8; ++j)
      #pragma unroll
      for (int r = 0; r < 4; ++r) {
        float p = __expf(sa[j][r] - mrun[r]);
        sa[j][r] = p;
        rs[r] += p;
      }
    #pragma unroll
    for (int w = 1; w < 16; w <<= 1)
      #pragma unroll
      for (int r = 0; r < 4; ++r)
        rs[r] += __shfl_xor(rs[r], w);
    #pragma unroll
    for (int r = 0; r < 4; ++r) lrun[r] = lrun[r]*fac[r] + rs[r];
    #pragma unroll
    for (int j2 = 0; j2 < 4; ++j2)
      #pragma unroll
      for (int r = 0; r < 4; ++r)
        pa[j2][r] *= fac[r];

    #pragma unroll
    for (int j = 0; j < 8; ++j)
      #pragma unroll
      for (int r = 0; r < 4; ++r) {
        int qr = l4*4 + r, n = j*16 + l15;
        Pls[wid][qr*128 + (((n >> 3) ^ (qr & 7))*8) + (n & 7)] = f2bf(sa[j][r]);
      }
    #pragma unroll
    for (int ks = 0; ks < 4; ++ks) {
      bf16x8 paf = *(const bf16x8*)&Pls[wid][l15*128 + (((ks*4 + l4) ^ (l15 & 7))*8)];
      #pragma unroll
      for (int j2 = 0; j2 < 4; ++j2) {
        int r = j2*16 + l15;
        bf16x8 vf = *(const bf16x8*)&Vls[ks >> 1][r*64 + ((((ks & 1)*4 + l4) ^ (r & 7))*8)];
        pa[j2] = __builtin_amdgcn_mfma_f32_16x16x32_bf16(paf, vf, pa[j2], 0, 0, 0);
      }
    }
    __syncthreads();
  }

  #pragma unroll
  for (int j2 = 0; j2 < 4; ++j2)
    #pragma unroll
    for (int r = 0; r < 4; ++r) {
      int m = m0 + wid*16 + l4*4 + r;
      Op[((long)part*NN + m)*256 + h*64 + j2*16 + l15] = pa[j2][r];
    }
  if (l15 == 0) {
    #pragma unroll
    for (int r = 0; r < 4; ++r) {
      int m = m0 + wid*16 + l4*4 + r;
      ml[((long)part*NN + m)*4 + h] = make_float2(mrun[r], lrun[r]);
    }
  }
}

__global__ __launch_bounds__(256) void comb_k(const float* __restrict__ Op,
    const float2* __restrict__ ml, u16* __restrict__ attn) {
  int n = blockIdx.x, t = threadIdx.x, h = t >> 6;
  float m[4], l[4];
  #pragma unroll
  for (int p = 0; p < 4; ++p) { float2 v = ml[((long)p*NN + n)*4 + h]; m[p] = v.x; l[p] = v.y; }
  float M = fmaxf(fmaxf(m[0], m[1]), fmaxf(m[2], m[3]));
  float L = 0.f, o = 0.f;
  #pragma unroll
  for (int p = 0; p < 4; ++p) {
    float w = __expf(m[p] - M);
    L += w * l[p];
    o += w * Op[((long)p*NN + n)*256 + t];
  }
  attn[(long)n*256 + t] = f2bf(o / L);
}

// ---------------- fused per-edge conv1d attention -------------------------------
// grid (NE/128, NH). Per block: 128 (edge,head) rows.
// A row = [qN[h][src[e]] (64) | ep[h][e] (64)]; h1 = relu(A@W1^T+b1) -> P (LDS);
// s = P@W2^T+b2; softmax over 64; msgP[e][h*64+o] = prob * valN[dst[e]][o*4+h]
__global__ __launch_bounds__(256) void attedge_k(
    const u16* __restrict__ qN, const u16* __restrict__ ep,
    const float* __restrict__ valN, const int* __restrict__ ei,
    const u16* __restrict__ W1, const float* __restrict__ b1,
    const u16* __restrict__ W2, const float* __restrict__ b2,
    float* __restrict__ msgP)
{
  __shared__ u16 As[128*128];   // 32 KB; reused as P after GEMM-1
  const int tid = threadIdx.x, wid = tid >> 6, lane = tid & 63;
  const int h = blockIdx.y;
  const int e0 = blockIdx.x * 128;
  const int l15 = lane & 15, l4 = lane >> 4;

  // stage A (each wave stages its own 32 rows; swizzled within 64-ch halves)
  #pragma unroll
  for (int p = 0; p < 8; ++p) {
    int R0 = wid*32 + p*4;
    int r  = R0 + (lane >> 4);
    int cd = lane & 15;
    int cs = ((cd & 7) ^ (r & 7)) | (cd & 8);
    const u16* src = (cs < 8)
        ? qN + ((long)h*NN + ei[e0 + r])*64 + cs*8
        : ep + ((long)h*NE + e0 + r)*64 + (cs & 7)*8;
    gload16(src, &As[R0*128]);
  }
  __syncthreads();

  // GEMM-1: h1 (128 cols), wave owns rows wid*32..+32
  f32x4 acc1[2][8] = {};
  #pragma unroll
  for (int kk = 0; kk < 4; ++kk) {
    bf16x8 af[2], bfr[8];
    #pragma unroll
    for (int i = 0; i < 2; ++i) {
      int rA = wid*32 + i*16 + l15;
      int cg = kk*4 + l4;
      int cd = ((cg & 7) ^ (rA & 7)) | (cg & 8);
      af[i] = *(const bf16x8*)&As[rA*128 + cd*8];
    }
    #pragma unroll
    for (int j = 0; j < 8; ++j)
      bfr[j] = *(const bf16x8*)&W1[(long)(j*16 + l15)*128 + kk*32 + l4*8];
    #pragma unroll
    for (int i = 0; i < 2; ++i)
      #pragma unroll
      for (int j = 0; j < 8; ++j)
        acc1[i][j] = __builtin_amdgcn_mfma_f32_16x16x32_bf16(af[i], bfr[j], acc1[i][j], 0, 0, 0);
  }
  // relu+bias -> P in LDS (own rows only; no cross-wave hazard)
  #pragma unroll
  for (int i = 0; i < 2; ++i)
    #pragma unroll
    for (int j = 0; j < 8; ++j) {
      int n = j*16 + l15;
      float bb = b1[n];
      #pragma unroll
      for (int r = 0; r < 4; ++r) {
        int m = wid*32 + i*16 + l4*4 + r;
        int cg = n >> 3;
        int cd = ((cg & 7) ^ (m & 7)) | (cg & 8);
        As[m*128 + cd*8 + (n & 7)] = f2bf(fmaxf(acc1[i][j][r] + bb, 0.f));
      }
    }

  // GEMM-2: s (64 cols)
  f32x4 acc2[2][4] = {};
  #pragma unroll
  for (int kk = 0; kk < 4; ++kk) {
    bf16x8 af[2], bfr[4];
    #pragma unroll
    for (int i = 0; i < 2; ++i) {
      int rA = wid*32 + i*16 + l15;
      int cg = kk*4 + l4;
      int cd = ((cg & 7) ^ (rA & 7)) | (cg & 8);
      af[i] = *(const bf16x8*)&As[rA*128 + cd*8];
    }
    #pragma unroll
    for (int j = 0; j < 4; ++j)
      bfr[j] = *(const bf16x8*)&W2[(long)(j*16 + l15)*128 + kk*32 + l4*8];
    #pragma unroll
    for (int i = 0; i < 2; ++i)
      #pragma unroll
      for (int j = 0; j < 4; ++j)
        acc2[i][j] = __builtin_amdgcn_mfma_f32_16x16x32_bf16(af[i], bfr[j], acc2[i][j], 0, 0, 0);
  }

  // bias + softmax over the 64 outputs per row + msg write
  #pragma unroll
  for (int i = 0; i < 2; ++i) {
    float mx[4] = {-1e30f,-1e30f,-1e30f,-1e30f};
    #pragma unroll
    for (int j = 0; j < 4; ++j) {
      float bb = b2[j*16 + l15];
      #pragma unroll
      for (int r = 0; r < 4; ++r) {
        acc2[i][j][r] += bb;
        mx[r] = fmaxf(mx[r], acc2[i][j][r]);
      }
    }
    #pragma unroll
    for (int w = 1; w < 16; w <<= 1)
      #pragma unroll
      for (int r = 0; r < 4; ++r) mx[r] = fmaxf(mx[r], __shfl_xor(mx[r], w));
    float sum[4] = {};
    #pragma unroll
    for (int j = 0; j < 4; ++j)
      #pragma unroll
      for (int r = 0; r < 4; ++r) {
        float p = __expf(acc2[i][j][r] - mx[r]);
        acc2[i][j][r] = p; sum[r] += p;
      }
    #pragma unroll
    for (int w = 1; w < 16; w <<= 1)
      #pragma unroll
      for (int r = 0; r < 4; ++r) sum[r] += __shfl_xor(sum[r], w);
    #pragma unroll
    for (int r = 0; r < 4; ++r) {
      int m = wid*32 + i*16 + l4*4 + r;
      int e = e0 + m;
      int dst = ei[NE + e];
      float inv = 1.f / sum[r];
      #pragma unroll
      for (int j = 0; j < 4; ++j) {
        int o = j*16 + l15;
        float v = valN[(long)dst*256 + o*4 + h];
        msgP[(long)e*256 + h*64 + o] = acc2[i][j][r] * inv * v;
      }
    }
  }
}

// ---------------- dedicated ne-MLP layer-1 GEMM: fused 4-segment gather ---------
__global__ __launch_bounds__(256) void gemm_ne(
    const u16* __restrict__ nbf, const u16* __restrict__ ebf, const u16* __restrict__ zbuf,
    const int* __restrict__ ei, const int* __restrict__ rev,
    const u16* __restrict__ Bt, const float* __restrict__ bias, u16* __restrict__ C)
{
  __shared__ u16 As[128 * 64];
  __shared__ u16 Bs[128 * 64];
  const int tid = threadIdx.x, wid = tid >> 6, lane = tid & 63;
  // XCD-chunked swizzle: all 4 N-tiles of an M-panel land on the same XCD
  const int lin = blockIdx.y * 4 + blockIdx.x;
  const int xcd = lin & 7, seq = lin >> 3;
  const int m0 = (xcd*32 + (seq >> 2)) * 128;
  const int n0 = (seq & 3) * 128;
  const int wr = wid >> 1, wc = wid & 1, l15 = lane & 15, l4 = lane >> 4;

  const u16* bsrc[4];
  #pragma unroll
  for (int c = 0; c < 4; ++c) {
    int rl = c*32 + wid*8 + (lane >> 3);
    int c16s = (lane & 7) ^ (rl & 7);
    bsrc[c] = Bt + (long)(n0 + rl) * 1024 + c16s * 8;
  }

  f32x4 acc[4][4] = {};

  #pragma unroll
  for (int seg = 0; seg < 4; ++seg) {
    const u16* asrc[4];
    #pragma unroll
    for (int c = 0; c < 4; ++c) {
      int rl = c*32 + wid*8 + (lane >> 3);
      int m = m0 + rl;
      int c16s = (lane & 7) ^ (rl & 7);
      const u16* base; long row;
      if (seg == 0)      { base = nbf; row = ei[m]; }
      else if (seg == 1) { base = ebf; row = m; }
      else if (seg == 2) { int r = rev[m]; base = (r >= 0) ? ebf : zbuf; row = (r >= 0) ? r : 0; }
      else               { base = nbf; row = ei[NE + m]; }
      asrc[c] = base + row * 256 + c16s * 8;
    }
    #pragma unroll
    for (int kt = 0; kt < 4; ++kt) {
      #pragma unroll
      for (int c = 0; c < 4; ++c)
        gload16(asrc[c] + kt*64, &As[(c*32 + wid*8) * 64]);
      #pragma unroll
      for (int c = 0; c < 4; ++c)
        gload16(bsrc[c] + seg*256 + kt*64, &Bs[(c*32 + wid*8) * 64]);
      __syncthreads();
      #pragma unroll
      for (int kk = 0; kk < 2; ++kk) {
        bf16x8 af[4], bfr[4];
        #pragma unroll
        for (int i = 0; i < 4; ++i) {
          int r = wr*64 + i*16 + l15;
          af[i] = *(const bf16x8*)&As[r*64 + (((kk*4 + l4) ^ (r & 7)) * 8)];
        }
        #pragma unroll
        for (int j = 0; j < 4; ++j) {
          int r = wc*64 + j*16 + l15;
          bfr[j] = *(const bf16x8*)&Bs[r*64 + (((kk*4 + l4) ^ (r & 7)) * 8)];
        }
        #pragma unroll
        for (int i = 0; i < 4; ++i)
          #pragma unroll
          for (int j = 0; j < 4; ++j)
            acc[i][j] = __builtin_amdgcn_mfma_f32_16x16x32_bf16(af[i], bfr[j], acc[i][j], 0, 0, 0);
      }
      __syncthreads();
    }
  }

  #pragma unroll
  for (int j = 0; j < 4; ++j) {
    const int col = n0 + wc*64 + j*16 + l15;
    const float bb = bias[col];
    #pragma unroll
    for (int i = 0; i < 4; ++i) {
      #pragma unroll
      for (int r = 0; r < 4; ++r) {
        const int m = m0 + wr*64 + i*16 + l4*4 + r;
        C[(long)m*512 + col] = f2bf(fmaxf(acc[i][j][r] + bb, 0.f));
      }
    }
  }
}

// ---------------- merged weight-prep mega-kernel --------------------------------
struct PrepEnt { const float* src; void* dst; int K; int N; int ntiles; int op; };
struct PrepDesc { PrepEnt e[24]; int n; };

__global__ __launch_bounds__(256) void wprep_k(PrepDesc d) {
  __shared__ float t[32][33];
  int b = blockIdx.x;
  int ei = 0;
  while (ei < d.n && b >= d.e[ei].ntiles) { b -= d.e[ei].ntiles; ++ei; }
  if (ei >= d.n) return;
  PrepEnt E = d.e[ei];
  int tid = threadIdx.x;
  if (E.op == 0) {
    int kt = E.K >> 5;
    int bk = (b % kt) * 32, bn = (b / kt) * 32;
    int tx = tid & 31, ty = tid >> 5;
    #pragma unroll
    for (int i = ty; i < 32; i += 8) t[i][tx] = E.src[(long)(bk + i) * E.N + bn + tx];
    __syncthreads();
    u16* dst = (u16*)E.dst;
    #pragma unroll
    for (int i = ty; i < 32; i += 8) dst[(long)(bn + i) * E.K + bk + tx] = f2bf(t[tx][i]);
  } else if (E.op == 1) {
    long i = (long)b * 256 + tid;
    long n4 = ((long)E.K * E.N) >> 2;
    if (i < n4) {
      float4 v = ((const float4*)E.src)[i];
      u16x4 o = { f2bf(v.x), f2bf(v.y), f2bf(v.z), f2bf(v.w) };
      ((u16x4*)E.dst)[i] = o;
    }
  } else {
    int i = b * 256 + tid;
    if (i < E.N) ((float*)E.dst)[i] = E.src[i];
  }
}

__global__ void geo_k(const float* __restrict__ C3, const float* __restrict__ gW1,
                      float* __restrict__ geo) {
  int n = blockIdx.x * 256 + threadIdx.x;
  if (n >= NN) return;
  float cx = C3[3*n], cy = C3[3*n+1], cz = C3[3*n+2];
  float s = cx*cx + cy*cy + cz*cz;
  float a0 = cx*gW1[0] + cy*gW1[3] + cz*gW1[6];
  float a1 = cx*gW1[1] + cy*gW1[4] + cz*gW1[7];
  float a2 = cx*gW1[2] + cy*gW1[5] + cz*gW1[8];
  float4* g = (float4*)(geo + (long)n*8);
  g[0] = make_float4(cx, cy, cz, s);
  g[1] = make_float4(a0, a1, a2, 0.f);
}

__global__ __launch_bounds__(256) void transb_k(const u16* __restrict__ src,
                                                u16* __restrict__ dst) {
  __shared__ u16 t[32][34];
  int bm = blockIdx.x * 32, bc = blockIdx.y * 32;
  int tx = threadIdx.x & 31, ty = threadIdx.x >> 5;
  #pragma unroll
  for (int i = ty; i < 32; i += 8) t[i][tx] = src[(long)(bm+i)*768 + 512 + bc + tx];
  __syncthreads();
  #pragma unroll
  for (int i = ty; i < 32; i += 8) dst[(long)(bc+i)*NN + bm + tx] = t[tx][i];
}

__global__ __launch_bounds__(256) void seg_sum_k(const float* __restrict__ ef,
    const int* __restrict__ ei, float* sub, float* obj, float* cs, float* cd) {
  int e = blockIdx.x * 4 + (threadIdx.x >> 6);
  int lane = threadIdx.x & 63;
  int s = ei[e], d = ei[NE + e];
  const float* row = ef + (long)e * DIM;
  #pragma unroll
  for (int c = 0; c < 4; ++c) {
    float v = row[lane + c*64];
    atomicAdd(&sub[(long)s*DIM + lane + c*64], v);
    atomicAdd(&obj[(long)d*DIM + lane + c*64], v);
  }
  if (lane == 0) { atomicAdd(&cs[s], 1.f); atomicAdd(&cd[d], 1.f); }
}

__global__ void pack_tw_k(const float* __restrict__ sub, const float* __restrict__ obj,
    const float* __restrict__ cs, const float* __restrict__ cd, u16* __restrict__ twA) {
  int n = blockIdx.x, t = threadIdx.x;
  int seg = t >> 6, c = (t & 63) * 4;
  float sc = seg ? 1.f / fmaxf(cd[n], 1.f) : 1.f / fmaxf(cs[n], 1.f);
  float4 v = *(const float4*)((seg ? obj : sub) + (long)n * DIM + c);
  u16x4 o = { f2bf(v.x*sc), f2bf(v.y*sc), f2bf(v.z*sc), f2bf(v.w*sc) };
  *(u16x4*)&twA[(long)n*512 + seg*256 + c] = o;
}

__global__ void pack_pr_k(const float* __restrict__ nf, const float* __restrict__ agg,
                          u16* __restrict__ prA) {
  int n = blockIdx.x, t = threadIdx.x;
  int seg = t >> 6, c = (t & 63) * 4;
  float4 v = *(const float4*)((seg ? agg : nf) + (long)n * DIM + c);
  u16x4 o = { f2bf(v.x), f2bf(v.y), f2bf(v.z), f2bf(v.w) };
  *(u16x4*)&prA[(long)n*512 + seg*256 + c] = o;
}

__global__ void node_out_k(const float* mh, const float* ea, float* out) {
  long i = (long)blockIdx.x * 256 + threadIdx.x;
  out[i] = fmaxf(mh[i], 0.f) * ea[i];
}

__global__ void scat_k(const int* ei, int* tbl) {
  int e = blockIdx.x * 256 + threadIdx.x;
  atomicMax(&tbl[(long)ei[e] * NN + ei[NE + e]], e + 1);
}

__global__ void rev_k(const int* ei, const int* tbl, int* rev) {
  int e = blockIdx.x * 256 + threadIdx.x;
  rev[e] = tbl[(long)ei[NE + e] * NN + ei[e]] - 1;
}

// ---------------- CSR build + agg (atomic-free segment max) ---------------------
__global__ __launch_bounds__(256) void scan_k(const float* __restrict__ cs,
    int* __restrict__ start, int* __restrict__ cursor) {
  __shared__ int part[256];
  int t = threadIdx.x;
  int loc[8]; int s = 0;
  #pragma unroll
  for (int i = 0; i < 8; ++i) { int v = (int)cs[t*8 + i]; loc[i] = s; s += v; }
  part[t] = s;
  __syncthreads();
  if (t == 0) { int a = 0; for (int i = 0; i < 256; ++i) { int v = part[i]; part[i] = a; a += v; } }
  __syncthreads();
  int base = part[t];
  #pragma unroll
  for (int i = 0; i < 8; ++i) { start[t*8+i] = base + loc[i]; cursor[t*8+i] = base + loc[i]; }
  if (t == 255) start[2048] = base + s;
}

__global__ void scatter_k(const int* __restrict__ ei, int* __restrict__ cursor,
                          int* __restrict__ eids) {
  int e = blockIdx.x * 256 + threadIdx.x;
  int pos = atomicAdd(&cursor[ei[e]], 1);
  eids[pos] = e;
}

__global__ __launch_bounds__(256) void agg_k(const int* __restrict__ start,
    const int* __restrict__ eids, const float* __restrict__ msgP, float* __restrict__ aggf) {
  int n = blockIdx.x, t = threadIdx.x;
  int b = start[n], e_ = start[n+1];
  float mx = -1e30f;
  for (int i = b; i < e_; ++i) {
    int e = eids[i];
    mx = fmaxf(mx, msgP[(long)e*256 + t]);
  }
  int c = (t & 63) * 4 + (t >> 6);
  aggf[(long)n*256 + c] = (e_ > b) ? mx : 0.f;
}

// ---------------- host side ------------------------------------------------------
static GB gb(const u16* A, const int* idx, long ld, long aoffz) {
  GB g; g.A = A; g.idx = idx; g.ld = ld; g.aoffz = aoffz; return g;
}

extern "C" void kernel_launch(void* const* d_in, const int* in_sizes, int n_in,
                              void* d_out, int out_size, void* d_ws, size_t ws_size,
                              hipStream_t stream) {
  (void)in_sizes; (void)n_in; (void)out_size; (void)ws_size;

  const float* node_f = (const float*)d_in[0];
  const float* edge_f = (const float*)d_in[1];
  const float* coords = (const float*)d_in[2];
  const int*   ei     = (const int*)d_in[3];
  const float* Wq = (const float*)d_in[5];  const float* bq = (const float*)d_in[6];
  const float* Wk = (const float*)d_in[7];  const float* bk = (const float*)d_in[8];
  const float* Wv = (const float*)d_in[9];  const float* bv = (const float*)d_in[10];
  const float* Wo = (const float*)d_in[11]; const float* bo = (const float*)d_in[12];
  const float* gd_W1 = (const float*)d_in[13]; const float* gd_b1 = (const float*)d_in[14];
  const float* gd_W2 = (const float*)d_in[15]; const float* gd_b2 = (const float*)d_in[16];
  const float* tw_W1 = (const float*)d_in[17]; const float* tw_b1 = (const float*)d_in[18];
  const float* tw_W2 = (const float*)d_in[19]; const float* tw_b2 = (const float*)d_in[20];
  const float* ne_W1 = (const float*)d_in[21]; const float* ne_b1 = (const float*)d_in[22];
  const float* ne_W2 = (const float*)d_in[23]; const float* ne_b2 = (const float*)d_in[24];
  const float* att_W1 = (const float*)d_in[25]; const float* att_b1 = (const float*)d_in[26];
  const float* att_W2 = (const float*)d_in[27]; const float* att_b2 = (const float*)d_in[28];
  const float* pe_W = (const float*)d_in[29]; const float* pe_b = (const float*)d_in[30];
  const float* pq_W = (const float*)d_in[31]; const float* pq_b = (const float*)d_in[32];
  const float* pv_W = (const float*)d_in[33]; const float* pv_b = (const float*)d_in[34];
  const float* pr_W1 = (const float*)d_in[35]; const float* pr_b1 = (const float*)d_in[36];
  const float* pr_W2 = (const float*)d_in[37]; const float* pr_b2 = (const float*)d_in[38];

  char* WB = (char*)d_ws;
  float* out = (float*)d_out;
  float* out_node = out;
  float* out_edge = out + (long)NN*DIM;
  float* out_xx   = out + (long)NN*DIM + (long)NE*DIM;

  // -------- workspace --------
  const long sz_R1 = 4L*NN*NN*4;   // Opart+ml -> msgP f32 (33.5 MB)
  const long sz_R2 = 4L*NN*NN*2;   // nehid bf16
  const long sz_R3 = 4L*NE*128*2;  // tbl int (16.8) + edge_bf (16.8); tbl -> ep bf16
  const long R1 = 0, R2 = R1 + sz_R1, R3 = R2 + sz_R2;

  float*  Opart = (float*)(WB + R1);
  float2* mlbuf = (float2*)(WB + R1 + 4L*NN*256*4);
  float*  msgP  = (float*)(WB + R1);
  u16*   nehid  = (u16*)(WB + R2);
  int*   tbl    = (int*)(WB + R3);
  u16*   ep     = (u16*)(WB + R3);                      // [4][NE][64] bf16 (16.8 MB)
  u16*   edge_bf= (u16*)(WB + R3 + (long)NN*NN*4);

  long cur = R3 + sz_R3;
  auto alloc = [&](long bytes) { long o = cur; cur += (bytes + 255) & ~255L; return o; };

  long o_sub = alloc(2L*NN*DIM*4);          // sub+obj -> later qkv_bf | vT,attn_bf
  float* sub = (float*)(WB + o_sub);
  float* obj = sub + (long)NN*DIM;
  u16* qkv_bf  = (u16*)sub;                 // [2048][768]
  u16* vT      = (u16*)obj;                 // [256][2048]
  u16* attn_bf = vT + (long)NN*DIM;

  long o_cs  = alloc(2L*NN*4);
  float* cs = (float*)(WB + o_cs); float* cd = cs + NN;
  long o_mh  = alloc((long)NN*DIM*4);  float* mhsa = (float*)(WB + o_mh);
  long o_ea  = alloc((long)NN*DIM*4);  float* eatt = (float*)(WB + o_ea);
  long o_ag  = alloc((long)NN*DIM*4);  float* aggf = (float*)(WB + o_ag);
  long o_rv  = alloc((long)NE*4);      int* rev = (int*)(WB + o_rv);
  long o_st  = alloc((NN+1)*4);        int* startp = (int*)(WB + o_st);
  long o_cu  = alloc(NN*4);            int* cursor = (int*)(WB + o_cu);
  long o_eid = alloc((long)NE*4);      int* eids = (int*)(WB + o_eid);
  long o_zb  = alloc(1024);            u16* zbuf = (u16*)(WB + o_zb);
  long o_geo = alloc((long)NN*8*4);    float* geo = (float*)(WB + o_geo);
  long o_nbf = alloc((long)NN*DIM*2);  u16* node_bf = (u16*)(WB + o_nbf);
  long o_twA = alloc((long)NN*512*2);  u16* twA = (u16*)(WB + o_twA);
  long o_twh = alloc((long)NN*DIM*2);  u16* twh = (u16*)(WB + o_twh);
  long o_prA = alloc((long)NN*512*2);  u16* prA = (u16*)(WB + o_prA);
  long o_prh = alloc((long)NN*512*2);  u16* prh = (u16*)(WB + o_prh);
  long o_qN  = alloc(4L*NN*64*2);      u16* qN = (u16*)(WB + o_qN);     // [4][NN][64]
  long o_vN  = alloc((long)NN*DIM*4);  float* valN = (float*)(WB + o_vN);

  u16* qkv_t = (u16*)(WB + alloc(3L*DIM*DIM*2));
  u16* Wo_t  = (u16*)(WB + alloc(DIM*DIM*2));
  u16* tw1_t = (u16*)(WB + alloc(DIM*512*2));
  u16* tw2_t = (u16*)(WB + alloc(DIM*DIM*2));
  u16* ne1_t = (u16*)(WB + alloc(512L*1024*2));
  u16* ne2_t = (u16*)(WB + alloc(DIM*512*2));
  u16* pe_t  = (u16*)(WB + alloc(DIM*DIM*2));
  u16* pq_t  = (u16*)(WB + alloc(DIM*DIM*2));
  u16* pv_t  = (u16*)(WB + alloc(DIM*DIM*2));
  u16* pr1_t = (u16*)(WB + alloc(512L*512*2));
  u16* pr2_t = (u16*)(WB + alloc(DIM*512*2));
  u16* a1_bf = (u16*)(WB + alloc(128*128*2));
  u16* a2_bf = (u16*)(WB + alloc(64*128*2));
  float* qkvb = (float*)(WB + alloc(768*4));

  // -------- init --------
  hipMemsetAsync(sub, 0, 2L*NN*DIM*4, stream);
  hipMemsetAsync(cs, 0, 2L*NN*4, stream);
  hipMemsetAsync(tbl, 0, (long)NN*NN*4, stream);
  hipMemsetAsync(zbuf, 0, 1024, stream);

  // -------- merged weight prep --------
  PrepDesc pd{}; int ne_ = 0; int tot = 0;
  auto addT = [&](const float* s, u16* d, int K, int N) {
    pd.e[ne_] = { s, d, K, N, (K/32)*(N/32), 0 }; tot += pd.e[ne_].ntiles; ++ne_;
  };
  auto addC = [&](const float* s, u16* d, long elems) {
    int nt = (int)((elems/4 + 255) / 256);
    pd.e[ne_] = { s, d, 1, (int)elems, nt, 1 }; tot += nt; ++ne_;
  };
  auto addB = [&](const float* s, float* d, int n) {
    pd.e[ne_] = { s, d, 1, n, (n + 255)/256, 2 }; tot += pd.e[ne_].ntiles; ++ne_;
  };
  addT(Wq, qkv_t,               DIM, DIM);
  addT(Wk, qkv_t + DIM*DIM,     DIM, DIM);
  addT(Wv, qkv_t + 2*DIM*DIM,   DIM, DIM);
  addT(Wo, Wo_t, DIM, DIM);
  addT(tw_W1, tw1_t, 512, DIM);
  addT(tw_W2, tw2_t, DIM, DIM);
  addT(ne_W1, ne1_t, 1024, 512);
  addT(ne_W2, ne2_t, 512, DIM);
  addT(pe_W, pe_t, DIM, DIM);
  addT(pq_W, pq_t, DIM, DIM);
  addT(pv_W, pv_t, DIM, DIM);
  addT(pr_W1, pr1_t, 512, 512);
  addT(pr_W2, pr2_t, 512, DIM);
  addC(att_W1, a1_bf, 128*128);
  addC(att_W2, a2_bf, 64*128);
  addC(node_f, node_bf, (long)NN*DIM);
  addC(edge_f, edge_bf, (long)NE*DIM);
  addB(bq, qkvb, 256); addB(bk, qkvb + 256, 256); addB(bv, qkvb + 512, 256);
  pd.n = ne_;
  wprep_k<<<tot, 256, 0, stream>>>(pd);
  geo_k<<<NN/256, 256, 0, stream>>>(coords, gd_W1, geo);

  // -------- twin edge-mean gate + CSR --------
  seg_sum_k<<<NE/4, 256, 0, stream>>>(edge_f, ei, sub, obj, cs, cd);
  scan_k<<<1, 256, 0, stream>>>(cs, startp, cursor);
  scatter_k<<<NE/256, 256, 0, stream>>>(ei, cursor, eids);
  pack_tw_k<<<NN, 128, 0, stream>>>(sub, obj, cs, cd, twA);
  gemm_bf<4,1><<<dim3(2,16,1), 256, 0, stream>>>(gb(twA, nullptr, 512, 0), tw1_t, 512, 0,
      tw_b1, twh, DIM, 0, 512, 1.f);
  gemm_bf<4,2><<<dim3(2,16,1), 256, 0, stream>>>(gb(twh, nullptr, DIM, 0), tw2_t, DIM, 0,
      tw_b2, eatt, DIM, 0, DIM, 1.f);

  // -------- MHSA (flash-fused, KV-split x4) --------
  gemm_bf<4,5><<<dim3(6,16,1), 256, 0, stream>>>(gb(node_bf, nullptr, DIM, 0), qkv_t, DIM, 0,
      qkvb, qkv_bf, 768, 0, DIM, 1.f);
  transb_k<<<dim3(64,8), 256, 0, stream>>>(qkv_bf, vT);
  flash_k<<<dim3(128,4), 256, 0, stream>>>(qkv_bf, vT, (const float4*)geo,
      gd_W1, gd_b1, gd_W2, gd_b2, Opart, mlbuf);
  comb_k<<<NN, 256, 0, stream>>>(Opart, mlbuf, attn_bf);
  gemm_bf<4,0><<<dim3(2,16,1), 256, 0, stream>>>(gb(attn_bf, nullptr, DIM, 0), Wo_t, DIM, 0,
      bo, mhsa, DIM, 0, DIM, 1.f);
  node_out_k<<<NN, 256, 0, stream>>>(mhsa, eatt, out_node);

  // -------- reverse-edge lookup + edge MLP (fused gather) --------
  scat_k<<<NE/256, 256, 0, stream>>>(ei, tbl);
  rev_k<<<NE/256, 256, 0, stream>>>(ei, tbl, rev);
  gemm_ne<<<dim3(4,256,1), 256, 0, stream>>>(node_bf, edge_bf, zbuf, ei, rev,
      ne1_t, ne_b1, nehid);
  gemm_bf<4,0><<<dim3(2,256,1), 256, 0, stream>>>(gb(nehid, nullptr, 512, 0), ne2_t, 512, 0,
      ne_b2, out_edge, DIM, 0, 512, 1.f);

  // -------- per-edge attention (node-level projections + fused conv-attn) -------
  gemm_bf<4,0><<<dim3(2,16,1), 256, 0, stream>>>(gb(node_bf, nullptr, DIM, 0), pv_t, DIM, 0,
      pv_b, valN, DIM, 0, DIM, 1.f);                                    // valN [NN][256] f32
  gemm_bf<4,7><<<dim3(2,16,1), 256, 0, stream>>>(gb(node_bf, nullptr, DIM, 0), pq_t, DIM, 0,
      pq_b, qN, 64, 0, DIM, 1.f);                                       // qN [4][NN][64] bf16
  gemm_bf<4,4><<<dim3(2,256,1), 256, 0, stream>>>(gb(edge_bf, nullptr, DIM, 0), pe_t, DIM, 0,
      pe_b, ep, 64, 0, DIM, 1.f);                                       // ep [4][NE][64] bf16
  attedge_k<<<dim3(NE/128, NH), 256, 0, stream>>>(qN, ep, valN, ei,
      a1_bf, att_b1, a2_bf, att_b2, msgP);
  agg_k<<<NN, 256, 0, stream>>>(startp, eids, msgP, aggf);

  // -------- final node MLP --------
  pack_pr_k<<<NN, 128, 0, stream>>>(node_f, aggf, prA);
  gemm_bf<4,1><<<dim3(4,16,1), 256, 0, stream>>>(gb(prA, nullptr, 512, 0), pr1_t, 512, 0,
      pr_b1, prh, 512, 0, 512, 1.f);
  gemm_bf<4,0><<<dim3(2,16,1), 256, 0, stream>>>(gb(prh, nullptr, 512, 0), pr2_t, 512, 0,
      pr_b2, out_xx, DIM, 0, 512, 1.f);
}

// Round 8
// 434.226 us; speedup vs baseline: 1.4889x; 1.0300x over previous
//
#include <hip/hip_runtime.h>

#define NN 2048
#define NE 32768
#define DIM 256
#define NH 4

typedef unsigned short u16;
typedef __attribute__((ext_vector_type(4))) unsigned short u16x4;
typedef __attribute__((ext_vector_type(8))) short bf16x8;
typedef __attribute__((ext_vector_type(4))) float f32x4;

typedef __attribute__((address_space(1))) const unsigned int g_as1;
typedef __attribute__((address_space(3))) unsigned int l_as3;

__device__ __forceinline__ void gload16(const u16* g, u16* l) {
  __builtin_amdgcn_global_load_lds((g_as1*)g, (l_as3*)l, 16, 0, 0);
}

__device__ __forceinline__ u16 f2bf(float f) {
  unsigned u = __float_as_uint(f);
  unsigned r = u + 0x7FFFu + ((u >> 16) & 1u);
  return (u16)(r >> 16);
}
__device__ __forceinline__ float bf2f(u16 b) {
  return __uint_as_float(((unsigned)b) << 16);
}

// ---------------- bf16 MFMA GEMM ------------------------------------------------
// C[m][n] = epi(scale * sum_k A[m][k]*Bt[n][k] + bias[n])
struct GB { const u16* A; const int* idx; long ld; long aoffz; };

// EPI: 0 = f32 out; 1 = relu -> bf16; 2 = sigmoid -> f32;
//      4 = headsplit bf16 (rows=NE); 5 = bf16 out; 6 = head-permuted f32;
//      7 = headsplit bf16 (rows=NN)
template<int BNF, int EPI>
__global__ __launch_bounds__(256) void gemm_bf(
    GB ga, const u16* __restrict__ Bt, long bld, long boffz,
    const float* __restrict__ bias, void* __restrict__ Cp, long ldc, long coffz,
    int K, float scale)
{
  __shared__ u16 As[128 * 64];
  __shared__ u16 Bs[32 * BNF * 64];

  const int tid = threadIdx.x;
  const int wid = tid >> 6, lane = tid & 63;
  const int bz = blockIdx.z;
  const int m0 = blockIdx.y * 128;
  const int n0 = blockIdx.x * (32 * BNF);
  const int wr = wid >> 1, wc = wid & 1;
  const int l15 = lane & 15, l4 = lane >> 4;

  const u16* asrc[4];
  #pragma unroll
  for (int c = 0; c < 4; ++c) {
    int rl = c*32 + wid*8 + (lane >> 3);
    int row = ga.idx ? ga.idx[m0 + rl] : (m0 + rl);
    int c16s = (lane & 7) ^ (rl & 7);
    asrc[c] = ga.A + ga.aoffz * bz + (long)row * ga.ld + c16s * 8;
  }
  const u16* bsrc[BNF];
  #pragma unroll
  for (int c = 0; c < BNF; ++c) {
    int rl = c*32 + wid*8 + (lane >> 3);
    int c16s = (lane & 7) ^ (rl & 7);
    bsrc[c] = Bt + boffz * bz + (long)(n0 + rl) * bld + c16s * 8;
  }

  f32x4 acc[4][BNF] = {};

  for (int k0 = 0; k0 < K; k0 += 64) {
    #pragma unroll
    for (int c = 0; c < 4; ++c)
      gload16(asrc[c] + k0, &As[(c*32 + wid*8) * 64]);
    #pragma unroll
    for (int c = 0; c < BNF; ++c)
      gload16(bsrc[c] + k0, &Bs[(c*32 + wid*8) * 64]);
    __syncthreads();

    #pragma unroll
    for (int kk = 0; kk < 2; ++kk) {
      bf16x8 af[4], bfr[BNF];
      #pragma unroll
      for (int i = 0; i < 4; ++i) {
        int r = wr*64 + i*16 + l15;
        af[i] = *(const bf16x8*)&As[r*64 + (((kk*4 + l4) ^ (r & 7)) * 8)];
      }
      #pragma unroll
      for (int j = 0; j < BNF; ++j) {
        int r = wc*(16*BNF) + j*16 + l15;
        bfr[j] = *(const bf16x8*)&Bs[r*64 + (((kk*4 + l4) ^ (r & 7)) * 8)];
      }
      #pragma unroll
      for (int i = 0; i < 4; ++i)
        #pragma unroll
        for (int j = 0; j < BNF; ++j)
          acc[i][j] = __builtin_amdgcn_mfma_f32_16x16x32_bf16(af[i], bfr[j], acc[i][j], 0, 0, 0);
    }
    __syncthreads();
  }

  #pragma unroll
  for (int j = 0; j < BNF; ++j) {
    const int col = n0 + wc*(16*BNF) + j*16 + l15;
    const float bb = bias ? bias[col] : 0.f;
    #pragma unroll
    for (int i = 0; i < 4; ++i) {
      #pragma unroll
      for (int r = 0; r < 4; ++r) {
        const int m = m0 + wr*64 + i*16 + l4*4 + r;
        float v = acc[i][j][r] * scale + bb;
        if constexpr (EPI == 1) v = fmaxf(v, 0.f);
        if constexpr (EPI == 2) v = 1.f / (1.f + expf(-v));
        if constexpr (EPI == 0 || EPI == 2)
          ((float*)Cp)[coffz*bz + (long)m*ldc + col] = v;
        else if constexpr (EPI == 4)
          ((u16*)Cp)[((long)(col & 3) * NE + m) * ldc + (col >> 2) + coffz] = f2bf(v);
        else if constexpr (EPI == 6)
          ((float*)Cp)[(long)m*256 + (col & 3)*64 + (col >> 2)] = v;
        else if constexpr (EPI == 7)
          ((u16*)Cp)[((long)(col & 3) * NN + m) * ldc + (col >> 2) + coffz] = f2bf(v);
        else
          ((u16*)Cp)[coffz*bz + (long)m*ldc + col] = f2bf(v);
      }
    }
  }
}

// ---------------- fused flash MHSA with KV-split ---------------------------------
__global__ __launch_bounds__(256) void flash_k(
    const u16* __restrict__ qkv,   // [NN][768] bf16  (q|k|v)
    const u16* __restrict__ vT,    // [256][NN] bf16  (v transposed)
    const float4* __restrict__ pk, // geo pack
    const float* __restrict__ gW1, const float* __restrict__ gb1,
    const float* __restrict__ gW2, const float* __restrict__ gb2,
    float* __restrict__ Op,        // [4][NN][256] f32 partial O
    float2* __restrict__ ml)       // [4][NN][4] (m,l)
{
  __shared__ u16 Qls[64*64];
  __shared__ u16 Kls[128*64];
  __shared__ u16 Vls[2][64*64];
  __shared__ u16 Pls[4][16*128];

  const int tid = threadIdx.x, wid = tid >> 6, lane = tid & 63;
  const int h  = blockIdx.x & 3;
  const int m0 = (blockIdx.x >> 2) * 64;
  const int part = blockIdx.y;
  const int l15 = lane & 15, l4 = lane >> 4;
  const int rl8 = wid*8 + (lane >> 3);
  const int c8  = lane & 7;

  #pragma unroll
  for (int c = 0; c < 2; ++c) {
    int r = c*32 + rl8;
    gload16(qkv + (long)(m0 + r)*768 + h*64 + ((c8 ^ (r & 7))*8), &Qls[(c*32 + wid*8)*64]);
  }
  __syncthreads();
  bf16x8 qf[2];
  {
    int r = wid*16 + l15;
    qf[0] = *(const bf16x8*)&Qls[r*64 + (((0*4 + l4) ^ (r & 7))*8)];
    qf[1] = *(const bf16x8*)&Qls[r*64 + (((1*4 + l4) ^ (r & 7))*8)];
  }

  const float b10 = gb1[0], b11 = gb1[1], b12 = gb1[2];
  const float w30 = gW1[9], w31 = gW1[10], w32 = gW1[11];
  const float w20 = gW2[0*4+h], w21 = gW2[1*4+h], w22 = gW2[2*4+h];
  const float b2h = gb2[h];
  float4 rp0[4], rp1[4];
  #pragma unroll
  for (int r = 0; r < 4; ++r) {
    int qrow = m0 + wid*16 + l4*4 + r;
    rp0[r] = pk[qrow*2]; rp1[r] = pk[qrow*2 + 1];
  }

  float mrun[4] = {-1e30f, -1e30f, -1e30f, -1e30f};
  float lrun[4] = {};
  f32x4 pa[4] = {};

  for (int t = 0; t < 4; ++t) {
    const int n0 = part*512 + t*128;
    #pragma unroll
    for (int c = 0; c < 4; ++c) {
      int r = c*32 + rl8;
      gload16(qkv + (long)(n0 + r)*768 + 256 + h*64 + ((c8 ^ (r & 7))*8),
              &Kls[(c*32 + wid*8)*64]);
    }
    #pragma unroll
    for (int hh = 0; hh < 2; ++hh)
      #pragma unroll
      for (int c = 0; c < 2; ++c) {
        int r = c*32 + rl8;
        gload16(vT + (long)(h*64 + r)*NN + n0 + hh*64 + ((c8 ^ (r & 7))*8),
                &Vls[hh][(c*32 + wid*8)*64]);
      }
    __syncthreads();

    f32x4 sa[8] = {};
    #pragma unroll
    for (int kk = 0; kk < 2; ++kk) {
      #pragma unroll
      for (int j = 0; j < 8; ++j) {
        int r = j*16 + l15;
        bf16x8 bf = *(const bf16x8*)&Kls[r*64 + (((kk*4 + l4) ^ (r & 7))*8)];
        sa[j] = __builtin_amdgcn_mfma_f32_16x16x32_bf16(qf[kk], bf, sa[j], 0, 0, 0);
      }
    }

    float rowmx[4] = {-1e30f, -1e30f, -1e30f, -1e30f};
    #pragma unroll
    for (int j = 0; j < 8; ++j) {
      int n = n0 + j*16 + l15;
      float4 cp0 = pk[n*2], cp1 = pk[n*2 + 1];
      #pragma unroll
      for (int r = 0; r < 4; ++r) {
        float dot = rp0[r].x*cp0.x + rp0[r].y*cp0.y + rp0[r].z*cp0.z;
        float sq = rp0[r].w + cp0.w - 2.f*dot;
        float dist = sq > 0.f ? sq * __frsqrt_rn(sq) : 0.f;
        float h0 = fmaxf(b10 + rp1[r].x - cp1.x + dist*w30, 0.f);
        float h1 = fmaxf(b11 + rp1[r].y - cp1.y + dist*w31, 0.f);
        float h2 = fmaxf(b12 + rp1[r].z - cp1.z + dist*w32, 0.f);
        float s = sa[j][r]*0.125f + b2h + h0*w20 + h1*w21 + h2*w22;
        sa[j][r] = s;
        rowmx[r] = fmaxf(rowmx[r], s);
      }
    }
    #pragma unroll
    for (int w = 1; w < 16; w <<= 1)
      #pragma unroll
      for (int r = 0; r < 4; ++r)
        rowmx[r] = fmaxf(rowmx[r], __shfl_xor(rowmx[r], w));

    float fac[4], rs[4] = {};
    #pragma unroll
    for (int r = 0; r < 4; ++r) {
      float mnew = fmaxf(mrun[r], rowmx[r]);
      fac[r] = __expf(mrun[r] - mnew);
      mrun[r] = mnew;
    }
    #pragma unroll
    for (int j = 0; j < 8; ++j)
      #pragma unroll
      for (int r = 0; r < 4; ++r) {
        float p = __expf(sa[j][r] - mrun[r]);
        sa[j][r] = p;
        rs[r] += p;
      }
    #pragma unroll
    for (int w = 1; w < 16; w <<= 1)
      #pragma unroll
      for (int r = 0; r < 4; ++r)
        rs[r] += __shfl_xor(rs[r], w);
    #pragma unroll
    for (int r = 0; r < 4; ++r) lrun[r] = lrun[r]*fac[r] + rs[r];
    #pragma unroll
    for (int j2 = 0; j2 < 4; ++j2)
      #pragma unroll
      for (int r = 0; r < 4; ++r)
        pa[j2][r] *= fac[r];

    #pragma unroll
    for (int j = 0; j < 8; ++j)
      #pragma unroll
      for (int r = 0; r < 4; ++r) {
        int qr = l4*4 + r, n = j*16 + l15;
        Pls[wid][qr*128 + (((n >> 3) ^ (qr & 7))*8) + (n & 7)] = f2bf(sa[j][r]);
      }
    #pragma unroll
    for (int ks = 0; ks < 4; ++ks) {
      bf16x8 paf = *(const bf16x8*)&Pls[wid][l15*128 + (((ks*4 + l4) ^ (l15 & 7))*8)];
      #pragma unroll
      for (int j2 = 0; j2 < 4; ++j2) {
        int r = j2*16 + l15;
        bf16x8 vf = *(const bf16x8*)&Vls[ks >> 1][r*64 + ((((ks & 1)*4 + l4) ^ (r & 7))*8)];
        pa[j2] = __builtin_amdgcn_mfma_f32_16x16x32_bf16(paf, vf, pa[j2], 0, 0, 0);
      }
    }
    __syncthreads();
  }

  #pragma unroll
  for (int j2 = 0; j2 < 4; ++j2)
    #pragma unroll
    for (int r = 0; r < 4; ++r) {
      int m = m0 + wid*16 + l4*4 + r;
      Op[((long)part*NN + m)*256 + h*64 + j2*16 + l15] = pa[j2][r];
    }
  if (l15 == 0) {
    #pragma unroll
    for (int r = 0; r < 4; ++r) {
      int m = m0 + wid*16 + l4*4 + r;
      ml[((long)part*NN + m)*4 + h] = make_float2(mrun[r], lrun[r]);
    }
  }
}

__global__ __launch_bounds__(256) void comb_k(const float* __restrict__ Op,
    const float2* __restrict__ ml, u16* __restrict__ attn) {
  int n = blockIdx.x, t = threadIdx.x, h = t >> 6;
  float m[4], l[4];
  #pragma unroll
  for (int p = 0; p < 4; ++p) { float2 v = ml[((long)p*NN + n)*4 + h]; m[p] = v.x; l[p] = v.y; }
  float M = fmaxf(fmaxf(m[0], m[1]), fmaxf(m[2], m[3]));
  float L = 0.f, o = 0.f;
  #pragma unroll
  for (int p = 0; p < 4; ++p) {
    float w = __expf(m[p] - M);
    L += w * l[p];
    o += w * Op[((long)p*NN + n)*256 + t];
  }
  attn[(long)n*256 + t] = f2bf(o / L);
}

// ---------------- fused per-edge conv1d attention (1-wave blocks) ---------------
// grid (NE/32, NH), 64 threads. Per block: 32 (edge,head) rows.
// A row = [qN[h][src[e]] (64) | ep[h][e] (64)]; h1 = relu(A@W1^T+b1) -> P (LDS);
// s = P@W2^T+b2; softmax over 64; msgP[e][h*64+o] = prob * valNp[dst[e]][h*64+o]
__global__ __launch_bounds__(64) void attedge_k(
    const u16* __restrict__ qN, const u16* __restrict__ ep,
    const float* __restrict__ valNp, const int* __restrict__ ei,
    const u16* __restrict__ W1, const float* __restrict__ b1,
    const u16* __restrict__ W2, const float* __restrict__ b2,
    float* __restrict__ msgP)
{
  __shared__ u16 As[32*128];   // 8 KB; reused as P after GEMM-1
  const int lane = threadIdx.x;
  const int h = blockIdx.y;
  const int e0 = blockIdx.x * 32;
  const int l15 = lane & 15, l4 = lane >> 4;

  // stage A (swizzled within 64-ch halves)
  #pragma unroll
  for (int p = 0; p < 8; ++p) {
    int R0 = p*4;
    int r  = R0 + (lane >> 4);
    int cd = lane & 15;
    int cs = ((cd & 7) ^ (r & 7)) | (cd & 8);
    const u16* src = (cs < 8)
        ? qN + ((long)h*NN + ei[e0 + r])*64 + cs*8
        : ep + ((long)h*NE + e0 + r)*64 + (cs & 7)*8;
    gload16(src, &As[R0*128]);
  }
  __syncthreads();

  // GEMM-1: h1 (128 cols), rows 0..31
  f32x4 acc1[2][8] = {};
  #pragma unroll
  for (int kk = 0; kk < 4; ++kk) {
    bf16x8 af[2], bfr[8];
    #pragma unroll
    for (int i = 0; i < 2; ++i) {
      int rA = i*16 + l15;
      int cg = kk*4 + l4;
      int cd = ((cg & 7) ^ (rA & 7)) | (cg & 8);
      af[i] = *(const bf16x8*)&As[rA*128 + cd*8];
    }
    #pragma unroll
    for (int j = 0; j < 8; ++j)
      bfr[j] = *(const bf16x8*)&W1[(long)(j*16 + l15)*128 + kk*32 + l4*8];
    #pragma unroll
    for (int i = 0; i < 2; ++i)
      #pragma unroll
      for (int j = 0; j < 8; ++j)
        acc1[i][j] = __builtin_amdgcn_mfma_f32_16x16x32_bf16(af[i], bfr[j], acc1[i][j], 0, 0, 0);
  }
  __syncthreads();
  // relu+bias -> P in LDS
  #pragma unroll
  for (int i = 0; i < 2; ++i)
    #pragma unroll
    for (int j = 0; j < 8; ++j) {
      int n = j*16 + l15;
      float bb = b1[n];
      #pragma unroll
      for (int r = 0; r < 4; ++r) {
        int m = i*16 + l4*4 + r;
        int cg = n >> 3;
        int cd = ((cg & 7) ^ (m & 7)) | (cg & 8);
        As[m*128 + cd*8 + (n & 7)] = f2bf(fmaxf(acc1[i][j][r] + bb, 0.f));
      }
    }
  __syncthreads();

  // GEMM-2: s (64 cols)
  f32x4 acc2[2][4] = {};
  #pragma unroll
  for (int kk = 0; kk < 4; ++kk) {
    bf16x8 af[2], bfr[4];
    #pragma unroll
    for (int i = 0; i < 2; ++i) {
      int rA = i*16 + l15;
      int cg = kk*4 + l4;
      int cd = ((cg & 7) ^ (rA & 7)) | (cg & 8);
      af[i] = *(const bf16x8*)&As[rA*128 + cd*8];
    }
    #pragma unroll
    for (int j = 0; j < 4; ++j)
      bfr[j] = *(const bf16x8*)&W2[(long)(j*16 + l15)*128 + kk*32 + l4*8];
    #pragma unroll
    for (int i = 0; i < 2; ++i)
      #pragma unroll
      for (int j = 0; j < 4; ++j)
        acc2[i][j] = __builtin_amdgcn_mfma_f32_16x16x32_bf16(af[i], bfr[j], acc2[i][j], 0, 0, 0);
  }

  // bias + softmax over the 64 outputs per row + msg write (coalesced valNp)
  #pragma unroll
  for (int i = 0; i < 2; ++i) {
    float mx[4] = {-1e30f,-1e30f,-1e30f,-1e30f};
    #pragma unroll
    for (int j = 0; j < 4; ++j) {
      float bb = b2[j*16 + l15];
      #pragma unroll
      for (int r = 0; r < 4; ++r) {
        acc2[i][j][r] += bb;
        mx[r] = fmaxf(mx[r], acc2[i][j][r]);
      }
    }
    #pragma unroll
    for (int w = 1; w < 16; w <<= 1)
      #pragma unroll
      for (int r = 0; r < 4; ++r) mx[r] = fmaxf(mx[r], __shfl_xor(mx[r], w));
    float sum[4] = {};
    #pragma unroll
    for (int j = 0; j < 4; ++j)
      #pragma unroll
      for (int r = 0; r < 4; ++r) {
        float p = __expf(acc2[i][j][r] - mx[r]);
        acc2[i][j][r] = p; sum[r] += p;
      }
    #pragma unroll
    for (int w = 1; w < 16; w <<= 1)
      #pragma unroll
      for (int r = 0; r < 4; ++r) sum[r] += __shfl_xor(sum[r], w);
    #pragma unroll
    for (int r = 0; r < 4; ++r) {
      int m = i*16 + l4*4 + r;
      int e = e0 + m;
      int dst = ei[NE + e];
      float inv = 1.f / sum[r];
      #pragma unroll
      for (int j = 0; j < 4; ++j) {
        int o = j*16 + l15;
        float v = valNp[(long)dst*256 + h*64 + o];
        msgP[(long)e*256 + h*64 + o] = acc2[i][j][r] * inv * v;
      }
    }
  }
}

// ---------------- dedicated ne-MLP layer-1 GEMM: fused 4-segment gather ---------
__global__ __launch_bounds__(256) void gemm_ne(
    const u16* __restrict__ nbf, const u16* __restrict__ ebf, const u16* __restrict__ zbuf,
    const int* __restrict__ ei, const int* __restrict__ rev,
    const u16* __restrict__ Bt, const float* __restrict__ bias, u16* __restrict__ C)
{
  __shared__ u16 As[128 * 64];
  __shared__ u16 Bs[128 * 64];
  const int tid = threadIdx.x, wid = tid >> 6, lane = tid & 63;
  // XCD-chunked swizzle: all 4 N-tiles of an M-panel land on the same XCD
  const int lin = blockIdx.y * 4 + blockIdx.x;
  const int xcd = lin & 7, seq = lin >> 3;
  const int m0 = (xcd*32 + (seq >> 2)) * 128;
  const int n0 = (seq & 3) * 128;
  const int wr = wid >> 1, wc = wid & 1, l15 = lane & 15, l4 = lane >> 4;

  const u16* bsrc[4];
  #pragma unroll
  for (int c = 0; c < 4; ++c) {
    int rl = c*32 + wid*8 + (lane >> 3);
    int c16s = (lane & 7) ^ (rl & 7);
    bsrc[c] = Bt + (long)(n0 + rl) * 1024 + c16s * 8;
  }

  f32x4 acc[4][4] = {};

  #pragma unroll
  for (int seg = 0; seg < 4; ++seg) {
    const u16* asrc[4];
    #pragma unroll
    for (int c = 0; c < 4; ++c) {
      int rl = c*32 + wid*8 + (lane >> 3);
      int m = m0 + rl;
      int c16s = (lane & 7) ^ (rl & 7);
      const u16* base; long row;
      if (seg == 0)      { base = nbf; row = ei[m]; }
      else if (seg == 1) { base = ebf; row = m; }
      else if (seg == 2) { int r = rev[m]; base = (r >= 0) ? ebf : zbuf; row = (r >= 0) ? r : 0; }
      else               { base = nbf; row = ei[NE + m]; }
      asrc[c] = base + row * 256 + c16s * 8;
    }
    #pragma unroll
    for (int kt = 0; kt < 4; ++kt) {
      #pragma unroll
      for (int c = 0; c < 4; ++c)
        gload16(asrc[c] + kt*64, &As[(c*32 + wid*8) * 64]);
      #pragma unroll
      for (int c = 0; c < 4; ++c)
        gload16(bsrc[c] + seg*256 + kt*64, &Bs[(c*32 + wid*8) * 64]);
      __syncthreads();
      #pragma unroll
      for (int kk = 0; kk < 2; ++kk) {
        bf16x8 af[4], bfr[4];
        #pragma unroll
        for (int i = 0; i < 4; ++i) {
          int r = wr*64 + i*16 + l15;
          af[i] = *(const bf16x8*)&As[r*64 + (((kk*4 + l4) ^ (r & 7)) * 8)];
        }
        #pragma unroll
        for (int j = 0; j < 4; ++j) {
          int r = wc*64 + j*16 + l15;
          bfr[j] = *(const bf16x8*)&Bs[r*64 + (((kk*4 + l4) ^ (r & 7)) * 8)];
        }
        #pragma unroll
        for (int i = 0; i < 4; ++i)
          #pragma unroll
          for (int j = 0; j < 4; ++j)
            acc[i][j] = __builtin_amdgcn_mfma_f32_16x16x32_bf16(af[i], bfr[j], acc[i][j], 0, 0, 0);
      }
      __syncthreads();
    }
  }

  #pragma unroll
  for (int j = 0; j < 4; ++j) {
    const int col = n0 + wc*64 + j*16 + l15;
    const float bb = bias[col];
    #pragma unroll
    for (int i = 0; i < 4; ++i) {
      #pragma unroll
      for (int r = 0; r < 4; ++r) {
        const int m = m0 + wr*64 + i*16 + l4*4 + r;
        C[(long)m*512 + col] = f2bf(fmaxf(acc[i][j][r] + bb, 0.f));
      }
    }
  }
}

// ---------------- merged weight-prep mega-kernel --------------------------------
struct PrepEnt { const float* src; void* dst; int K; int N; int ntiles; int op; };
struct PrepDesc { PrepEnt e[24]; int n; };

__global__ __launch_bounds__(256) void wprep_k(PrepDesc d) {
  __shared__ float t[32][33];
  int b = blockIdx.x;
  int ei = 0;
  while (ei < d.n && b >= d.e[ei].ntiles) { b -= d.e[ei].ntiles; ++ei; }
  if (ei >= d.n) return;
  PrepEnt E = d.e[ei];
  int tid = threadIdx.x;
  if (E.op == 0) {
    int kt = E.K >> 5;
    int bk = (b % kt) * 32, bn = (b / kt) * 32;
    int tx = tid & 31, ty = tid >> 5;
    #pragma unroll
    for (int i = ty; i < 32; i += 8) t[i][tx] = E.src[(long)(bk + i) * E.N + bn + tx];
    __syncthreads();
    u16* dst = (u16*)E.dst;
    #pragma unroll
    for (int i = ty; i < 32; i += 8) dst[(long)(bn + i) * E.K + bk + tx] = f2bf(t[tx][i]);
  } else if (E.op == 1) {
    long i = (long)b * 256 + tid;
    long n4 = ((long)E.K * E.N) >> 2;
    if (i < n4) {
      float4 v = ((const float4*)E.src)[i];
      u16x4 o = { f2bf(v.x), f2bf(v.y), f2bf(v.z), f2bf(v.w) };
      ((u16x4*)E.dst)[i] = o;
    }
  } else {
    int i = b * 256 + tid;
    if (i < E.N) ((float*)E.dst)[i] = E.src[i];
  }
}

__global__ void geo_k(const float* __restrict__ C3, const float* __restrict__ gW1,
                      float* __restrict__ geo) {
  int n = blockIdx.x * 256 + threadIdx.x;
  if (n >= NN) return;
  float cx = C3[3*n], cy = C3[3*n+1], cz = C3[3*n+2];
  float s = cx*cx + cy*cy + cz*cz;
  float a0 = cx*gW1[0] + cy*gW1[3] + cz*gW1[6];
  float a1 = cx*gW1[1] + cy*gW1[4] + cz*gW1[7];
  float a2 = cx*gW1[2] + cy*gW1[5] + cz*gW1[8];
  float4* g = (float4*)(geo + (long)n*8);
  g[0] = make_float4(cx, cy, cz, s);
  g[1] = make_float4(a0, a1, a2, 0.f);
}

__global__ __launch_bounds__(256) void transb_k(const u16* __restrict__ src,
                                                u16* __restrict__ dst) {
  __shared__ u16 t[32][34];
  int bm = blockIdx.x * 32, bc = blockIdx.y * 32;
  int tx = threadIdx.x & 31, ty = threadIdx.x >> 5;
  #pragma unroll
  for (int i = ty; i < 32; i += 8) t[i][tx] = src[(long)(bm+i)*768 + 512 + bc + tx];
  __syncthreads();
  #pragma unroll
  for (int i = ty; i < 32; i += 8) dst[(long)(bc+i)*NN + bm + tx] = t[tx][i];
}

__global__ __launch_bounds__(256) void seg_sum_k(const float* __restrict__ ef,
    const int* __restrict__ ei, float* sub, float* obj, float* cs, float* cd) {
  int e = blockIdx.x * 4 + (threadIdx.x >> 6);
  int lane = threadIdx.x & 63;
  int s = ei[e], d = ei[NE + e];
  const float* row = ef + (long)e * DIM;
  #pragma unroll
  for (int c = 0; c < 4; ++c) {
    float v = row[lane + c*64];
    atomicAdd(&sub[(long)s*DIM + lane + c*64], v);
    atomicAdd(&obj[(long)d*DIM + lane + c*64], v);
  }
  if (lane == 0) { atomicAdd(&cs[s], 1.f); atomicAdd(&cd[d], 1.f); }
}

__global__ void pack_tw_k(const float* __restrict__ sub, const float* __restrict__ obj,
    const float* __restrict__ cs, const float* __restrict__ cd, u16* __restrict__ twA) {
  int n = blockIdx.x, t = threadIdx.x;
  int seg = t >> 6, c = (t & 63) * 4;
  float sc = seg ? 1.f / fmaxf(cd[n], 1.f) : 1.f / fmaxf(cs[n], 1.f);
  float4 v = *(const float4*)((seg ? obj : sub) + (long)n * DIM + c);
  u16x4 o = { f2bf(v.x*sc), f2bf(v.y*sc), f2bf(v.z*sc), f2bf(v.w*sc) };
  *(u16x4*)&twA[(long)n*512 + seg*256 + c] = o;
}

__global__ void pack_pr_k(const float* __restrict__ nf, const float* __restrict__ agg,
                          u16* __restrict__ prA) {
  int n = blockIdx.x, t = threadIdx.x;
  int seg = t >> 6, c = (t & 63) * 4;
  float4 v = *(const float4*)((seg ? agg : nf) + (long)n * DIM + c);
  u16x4 o = { f2bf(v.x), f2bf(v.y), f2bf(v.z), f2bf(v.w) };
  *(u16x4*)&prA[(long)n*512 + seg*256 + c] = o;
}

__global__ void node_out_k(const float* mh, const float* ea, float* out) {
  long i = (long)blockIdx.x * 256 + threadIdx.x;
  out[i] = fmaxf(mh[i], 0.f) * ea[i];
}

__global__ void scat_k(const int* ei, int* tbl) {
  int e = blockIdx.x * 256 + threadIdx.x;
  atomicMax(&tbl[(long)ei[e] * NN + ei[NE + e]], e + 1);
}

__global__ void rev_k(const int* ei, const int* tbl, int* rev) {
  int e = blockIdx.x * 256 + threadIdx.x;
  rev[e] = tbl[(long)ei[NE + e] * NN + ei[e]] - 1;
}

// ---------------- CSR build + agg (atomic-free segment max) ---------------------
__global__ __launch_bounds__(256) void scan_k(const float* __restrict__ cs,
    int* __restrict__ start, int* __restrict__ cursor) {
  __shared__ int part[256];
  int t = threadIdx.x;
  int loc[8]; int s = 0;
  #pragma unroll
  for (int i = 0; i < 8; ++i) { int v = (int)cs[t*8 + i]; loc[i] = s; s += v; }
  part[t] = s;
  __syncthreads();
  if (t == 0) { int a = 0; for (int i = 0; i < 256; ++i) { int v = part[i]; part[i] = a; a += v; } }
  __syncthreads();
  int base = part[t];
  #pragma unroll
  for (int i = 0; i < 8; ++i) { start[t*8+i] = base + loc[i]; cursor[t*8+i] = base + loc[i]; }
  if (t == 255) start[2048] = base + s;
}

__global__ void scatter_k(const int* __restrict__ ei, int* __restrict__ cursor,
                          int* __restrict__ eids) {
  int e = blockIdx.x * 256 + threadIdx.x;
  int pos = atomicAdd(&cursor[ei[e]], 1);
  eids[pos] = e;
}

__global__ __launch_bounds__(256) void agg_k(const int* __restrict__ start,
    const int* __restrict__ eids, const float* __restrict__ msgP, float* __restrict__ aggf) {
  int n = blockIdx.x, t = threadIdx.x;
  int b = start[n], e_ = start[n+1];
  float mx = -1e30f;
  for (int i = b; i < e_; ++i) {
    int e = eids[i];
    mx = fmaxf(mx, msgP[(long)e*256 + t]);
  }
  int c = (t & 63) * 4 + (t >> 6);
  aggf[(long)n*256 + c] = (e_ > b) ? mx : 0.f;
}

// ---------------- host side ------------------------------------------------------
static GB gb(const u16* A, const int* idx, long ld, long aoffz) {
  GB g; g.A = A; g.idx = idx; g.ld = ld; g.aoffz = aoffz; return g;
}

extern "C" void kernel_launch(void* const* d_in, const int* in_sizes, int n_in,
                              void* d_out, int out_size, void* d_ws, size_t ws_size,
                              hipStream_t stream) {
  (void)in_sizes; (void)n_in; (void)out_size; (void)ws_size;

  const float* node_f = (const float*)d_in[0];
  const float* edge_f = (const float*)d_in[1];
  const float* coords = (const float*)d_in[2];
  const int*   ei     = (const int*)d_in[3];
  const float* Wq = (const float*)d_in[5];  const float* bq = (const float*)d_in[6];
  const float* Wk = (const float*)d_in[7];  const float* bk = (const float*)d_in[8];
  const float* Wv = (const float*)d_in[9];  const float* bv = (const float*)d_in[10];
  const float* Wo = (const float*)d_in[11]; const float* bo = (const float*)d_in[12];
  const float* gd_W1 = (const float*)d_in[13]; const float* gd_b1 = (const float*)d_in[14];
  const float* gd_W2 = (const float*)d_in[15]; const float* gd_b2 = (const float*)d_in[16];
  const float* tw_W1 = (const float*)d_in[17]; const float* tw_b1 = (const float*)d_in[18];
  const float* tw_W2 = (const float*)d_in[19]; const float* tw_b2 = (const float*)d_in[20];
  const float* ne_W1 = (const float*)d_in[21]; const float* ne_b1 = (const float*)d_in[22];
  const float* ne_W2 = (const float*)d_in[23]; const float* ne_b2 = (const float*)d_in[24];
  const float* att_W1 = (const float*)d_in[25]; const float* att_b1 = (const float*)d_in[26];
  const float* att_W2 = (const float*)d_in[27]; const float* att_b2 = (const float*)d_in[28];
  const float* pe_W = (const float*)d_in[29]; const float* pe_b = (const float*)d_in[30];
  const float* pq_W = (const float*)d_in[31]; const float* pq_b = (const float*)d_in[32];
  const float* pv_W = (const float*)d_in[33]; const float* pv_b = (const float*)d_in[34];
  const float* pr_W1 = (const float*)d_in[35]; const float* pr_b1 = (const float*)d_in[36];
  const float* pr_W2 = (const float*)d_in[37]; const float* pr_b2 = (const float*)d_in[38];

  char* WB = (char*)d_ws;
  float* out = (float*)d_out;
  float* out_node = out;
  float* out_edge = out + (long)NN*DIM;
  float* out_xx   = out + (long)NN*DIM + (long)NE*DIM;

  // -------- workspace --------
  const long sz_R1 = 4L*NN*NN*4;   // Opart+ml -> msgP f32 (33.5 MB)
  const long sz_R2 = 4L*NN*NN*2;   // nehid bf16
  const long sz_R3 = 4L*NE*128*2;  // tbl int (16.8) + edge_bf (16.8); tbl -> ep bf16
  const long R1 = 0, R2 = R1 + sz_R1, R3 = R2 + sz_R2;

  float*  Opart = (float*)(WB + R1);
  float2* mlbuf = (float2*)(WB + R1 + 4L*NN*256*4);
  float*  msgP  = (float*)(WB + R1);
  u16*   nehid  = (u16*)(WB + R2);
  int*   tbl    = (int*)(WB + R3);
  u16*   ep     = (u16*)(WB + R3);                      // [4][NE][64] bf16 (16.8 MB)
  u16*   edge_bf= (u16*)(WB + R3 + (long)NN*NN*4);

  long cur = R3 + sz_R3;
  auto alloc = [&](long bytes) { long o = cur; cur += (bytes + 255) & ~255L; return o; };

  long o_sub = alloc(2L*NN*DIM*4);          // sub+obj -> later qkv_bf | vT,attn_bf
  float* sub = (float*)(WB + o_sub);
  float* obj = sub + (long)NN*DIM;
  u16* qkv_bf  = (u16*)sub;                 // [2048][768]
  u16* vT      = (u16*)obj;                 // [256][2048]
  u16* attn_bf = vT + (long)NN*DIM;

  long o_cs  = alloc(2L*NN*4);
  float* cs = (float*)(WB + o_cs); float* cd = cs + NN;
  long o_mh  = alloc((long)NN*DIM*4);  float* mhsa = (float*)(WB + o_mh);
  long o_ea  = alloc((long)NN*DIM*4);  float* eatt = (float*)(WB + o_ea);
  long o_ag  = alloc((long)NN*DIM*4);  float* aggf = (float*)(WB + o_ag);
  long o_rv  = alloc((long)NE*4);      int* rev = (int*)(WB + o_rv);
  long o_st  = alloc((NN+1)*4);        int* startp = (int*)(WB + o_st);
  long o_cu  = alloc(NN*4);            int* cursor = (int*)(WB + o_cu);
  long o_eid = alloc((long)NE*4);      int* eids = (int*)(WB + o_eid);
  long o_zb  = alloc(1024);            u16* zbuf = (u16*)(WB + o_zb);
  long o_geo = alloc((long)NN*8*4);    float* geo = (float*)(WB + o_geo);
  long o_nbf = alloc((long)NN*DIM*2);  u16* node_bf = (u16*)(WB + o_nbf);
  long o_twA = alloc((long)NN*512*2);  u16* twA = (u16*)(WB + o_twA);
  long o_twh = alloc((long)NN*DIM*2);  u16* twh = (u16*)(WB + o_twh);
  long o_prA = alloc((long)NN*512*2);  u16* prA = (u16*)(WB + o_prA);
  long o_prh = alloc((long)NN*512*2);  u16* prh = (u16*)(WB + o_prh);
  long o_qN  = alloc(4L*NN*64*2);      u16* qN = (u16*)(WB + o_qN);     // [4][NN][64]
  long o_vN  = alloc((long)NN*DIM*4);  float* valN = (float*)(WB + o_vN);

  u16* qkv_t = (u16*)(WB + alloc(3L*DIM*DIM*2));
  u16* Wo_t  = (u16*)(WB + alloc(DIM*DIM*2));
  u16* tw1_t = (u16*)(WB + alloc(DIM*512*2));
  u16* tw2_t = (u16*)(WB + alloc(DIM*DIM*2));
  u16* ne1_t = (u16*)(WB + alloc(512L*1024*2));
  u16* ne2_t = (u16*)(WB + alloc(DIM*512*2));
  u16* pe_t  = (u16*)(WB + alloc(DIM*DIM*2));
  u16* pq_t  = (u16*)(WB + alloc(DIM*DIM*2));
  u16* pv_t  = (u16*)(WB + alloc(DIM*DIM*2));
  u16* pr1_t = (u16*)(WB + alloc(512L*512*2));
  u16* pr2_t = (u16*)(WB + alloc(DIM*512*2));
  u16* a1_bf = (u16*)(WB + alloc(128*128*2));
  u16* a2_bf = (u16*)(WB + alloc(64*128*2));
  float* qkvb = (float*)(WB + alloc(768*4));

  // -------- init --------
  hipMemsetAsync(sub, 0, 2L*NN*DIM*4, stream);
  hipMemsetAsync(cs, 0, 2L*NN*4, stream);
  hipMemsetAsync(tbl, 0, (long)NN*NN*4, stream);
  hipMemsetAsync(zbuf, 0, 1024, stream);

  // -------- merged weight prep --------
  PrepDesc pd{}; int ne_ = 0; int tot = 0;
  auto addT = [&](const float* s, u16* d, int K, int N) {
    pd.e[ne_] = { s, d, K, N, (K/32)*(N/32), 0 }; tot += pd.e[ne_].ntiles; ++ne_;
  };
  auto addC = [&](const float* s, u16* d, long elems) {
    int nt = (int)((elems/4 + 255) / 256);
    pd.e[ne_] = { s, d, 1, (int)elems, nt, 1 }; tot += nt; ++ne_;
  };
  auto addB = [&](const float* s, float* d, int n) {
    pd.e[ne_] = { s, d, 1, n, (n + 255)/256, 2 }; tot += pd.e[ne_].ntiles; ++ne_;
  };
  addT(Wq, qkv_t,               DIM, DIM);
  addT(Wk, qkv_t + DIM*DIM,     DIM, DIM);
  addT(Wv, qkv_t + 2*DIM*DIM,   DIM, DIM);
  addT(Wo, Wo_t, DIM, DIM);
  addT(tw_W1, tw1_t, 512, DIM);
  addT(tw_W2, tw2_t, DIM, DIM);
  addT(ne_W1, ne1_t, 1024, 512);
  addT(ne_W2, ne2_t, 512, DIM);
  addT(pe_W, pe_t, DIM, DIM);
  addT(pq_W, pq_t, DIM, DIM);
  addT(pv_W, pv_t, DIM, DIM);
  addT(pr_W1, pr1_t, 512, 512);
  addT(pr_W2, pr2_t, 512, DIM);
  addC(att_W1, a1_bf, 128*128);
  addC(att_W2, a2_bf, 64*128);
  addC(node_f, node_bf, (long)NN*DIM);
  addC(edge_f, edge_bf, (long)NE*DIM);
  addB(bq, qkvb, 256); addB(bk, qkvb + 256, 256); addB(bv, qkvb + 512, 256);
  pd.n = ne_;
  wprep_k<<<tot, 256, 0, stream>>>(pd);
  geo_k<<<NN/256, 256, 0, stream>>>(coords, gd_W1, geo);

  // -------- twin edge-mean gate + CSR --------
  seg_sum_k<<<NE/4, 256, 0, stream>>>(edge_f, ei, sub, obj, cs, cd);
  scan_k<<<1, 256, 0, stream>>>(cs, startp, cursor);
  scatter_k<<<NE/256, 256, 0, stream>>>(ei, cursor, eids);
  pack_tw_k<<<NN, 128, 0, stream>>>(sub, obj, cs, cd, twA);
  gemm_bf<4,1><<<dim3(2,16,1), 256, 0, stream>>>(gb(twA, nullptr, 512, 0), tw1_t, 512, 0,
      tw_b1, twh, DIM, 0, 512, 1.f);
  gemm_bf<4,2><<<dim3(2,16,1), 256, 0, stream>>>(gb(twh, nullptr, DIM, 0), tw2_t, DIM, 0,
      tw_b2, eatt, DIM, 0, DIM, 1.f);

  // -------- MHSA (flash-fused, KV-split x4) --------
  gemm_bf<4,5><<<dim3(6,16,1), 256, 0, stream>>>(gb(node_bf, nullptr, DIM, 0), qkv_t, DIM, 0,
      qkvb, qkv_bf, 768, 0, DIM, 1.f);
  transb_k<<<dim3(64,8), 256, 0, stream>>>(qkv_bf, vT);
  flash_k<<<dim3(128,4), 256, 0, stream>>>(qkv_bf, vT, (const float4*)geo,
      gd_W1, gd_b1, gd_W2, gd_b2, Opart, mlbuf);
  comb_k<<<NN, 256, 0, stream>>>(Opart, mlbuf, attn_bf);
  gemm_bf<4,0><<<dim3(2,16,1), 256, 0, stream>>>(gb(attn_bf, nullptr, DIM, 0), Wo_t, DIM, 0,
      bo, mhsa, DIM, 0, DIM, 1.f);
  node_out_k<<<NN, 256, 0, stream>>>(mhsa, eatt, out_node);

  // -------- reverse-edge lookup + edge MLP (fused gather) --------
  scat_k<<<NE/256, 256, 0, stream>>>(ei, tbl);
  rev_k<<<NE/256, 256, 0, stream>>>(ei, tbl, rev);
  gemm_ne<<<dim3(4,256,1), 256, 0, stream>>>(node_bf, edge_bf, zbuf, ei, rev,
      ne1_t, ne_b1, nehid);
  gemm_bf<4,0><<<dim3(2,256,1), 256, 0, stream>>>(gb(nehid, nullptr, 512, 0), ne2_t, 512, 0,
      ne_b2, out_edge, DIM, 0, 512, 1.f);

  // -------- per-edge attention (node-level projections + fused conv-attn) -------
  gemm_bf<4,6><<<dim3(2,16,1), 256, 0, stream>>>(gb(node_bf, nullptr, DIM, 0), pv_t, DIM, 0,
      pv_b, valN, DIM, 0, DIM, 1.f);                                    // valN [NN][h*64+o] f32
  gemm_bf<4,7><<<dim3(2,16,1), 256, 0, stream>>>(gb(node_bf, nullptr, DIM, 0), pq_t, DIM, 0,
      pq_b, qN, 64, 0, DIM, 1.f);                                       // qN [4][NN][64] bf16
  gemm_bf<4,4><<<dim3(2,256,1), 256, 0, stream>>>(gb(edge_bf, nullptr, DIM, 0), pe_t, DIM, 0,
      pe_b, ep, 64, 0, DIM, 1.f);                                       // ep [4][NE][64] bf16
  attedge_k<<<dim3(NE/32, NH), 64, 0, stream>>>(qN, ep, valN, ei,
      a1_bf, att_b1, a2_bf, att_b2, msgP);
  agg_k<<<NN, 256, 0, stream>>>(startp, eids, msgP, aggf);

  // -------- final node MLP --------
  pack_pr_k<<<NN, 128, 0, stream>>>(node_f, aggf, prA);
  gemm_bf<4,1><<<dim3(4,16,1), 256, 0, stream>>>(gb(prA, nullptr, 512, 0), pr1_t, 512, 0,
      pr_b1, prh, 512, 0, 512, 1.f);
  gemm_bf<4,0><<<dim3(2,16,1), 256, 0, stream>>>(gb(prh, nullptr, 512, 0), pr2_t, 512, 0,
      pr_b2, out_xx, DIM, 0, 512, 1.f);
}